// Round 1
// baseline (1743.225 us; speedup 1.0000x reference)
//
#include <hip/hip_runtime.h>
#include <hip/hip_bf16.h>
#include <math.h>

namespace {

constexpr int B_ = 8, C_ = 384, H_ = 32, W_ = 32, HW_ = 1024;
constexpr int HEADS_ = 12, G_ = 6, HC_ = 32, CG_ = 64, NS_ = 256, D2_ = 1536;
constexpr float SCALE_ = 0.17677669529663687f;  // 32^-0.5

__device__ __forceinline__ float gelu_exact(float x) {
  return 0.5f * x * (1.f + erff(x * 0.70710678118654752f));
}

// y = x + dwconv3x3(x, w, b)   (optionally GELU on the sum) — pad 1, stride 1
template <bool GELU>
__global__ __launch_bounds__(256) void dw3x3_kernel(
    const float* __restrict__ x, const float* __restrict__ w,
    const float* __restrict__ bias, float* __restrict__ y, int Cn) {
  int idx = blockIdx.x * 256 + threadIdx.x;  // grid sized exactly B*Cn*HW
  int wp = idx & 31, hp = (idx >> 5) & 31;
  int bc = idx >> 10;
  int c = bc % Cn;
  const float* img = x + (size_t)bc * HW_;
  const float* wc = w + c * 9;
  float acc = bias[c];
#pragma unroll
  for (int ky = 0; ky < 3; ky++) {
    int ih = hp + ky - 1;
    if ((unsigned)ih >= 32u) continue;
#pragma unroll
    for (int kx = 0; kx < 3; kx++) {
      int iw = wp + kx - 1;
      if ((unsigned)iw >= 32u) continue;
      acc = fmaf(wc[ky * 3 + kx], img[ih * 32 + iw], acc);
    }
  }
  float t = img[hp * 32 + wp] + acc;
  y[idx] = GELU ? gelu_exact(t) : t;
}

// Y[b,o,n] = sum_k W[o,k] * X[b,k,n] + bias[o] (+ resid[b,o,n])
// O,K multiples of 64/16; N multiple of 64. 64x64 tile, BK=16, 4x4/thread.
__global__ __launch_bounds__(256) void gemm_kernel(
    const float* __restrict__ Wm, const float* __restrict__ X,
    const float* __restrict__ bias, const float* __restrict__ resid,
    float* __restrict__ Y, int O, int K, int N) {
  __shared__ float sW[16][68];
  __shared__ float sX[16][68];
  int b = blockIdx.z;
  int o0 = blockIdx.y * 64, n0 = blockIdx.x * 64;
  const float* Xb = X + (size_t)b * K * N + n0;
  const float* Wb = Wm + (size_t)o0 * K;
  float acc[4][4] = {{0.f}};
  int tx = threadIdx.x & 15, ty = threadIdx.x >> 4;
  int wo_ = threadIdx.x >> 2, wk_ = threadIdx.x & 3;   // W-tile load map
  int xk_ = threadIdx.x >> 4, xn_ = threadIdx.x & 15;  // X-tile load map
  for (int k0 = 0; k0 < K; k0 += 16) {
    float4 w4 = *reinterpret_cast<const float4*>(&Wb[(size_t)wo_ * K + k0 + wk_ * 4]);
    sW[wk_ * 4 + 0][wo_] = w4.x;
    sW[wk_ * 4 + 1][wo_] = w4.y;
    sW[wk_ * 4 + 2][wo_] = w4.z;
    sW[wk_ * 4 + 3][wo_] = w4.w;
    float4 x4 = *reinterpret_cast<const float4*>(&Xb[(size_t)(k0 + xk_) * N + xn_ * 4]);
    *reinterpret_cast<float4*>(&sX[xk_][xn_ * 4]) = x4;
    __syncthreads();
#pragma unroll
    for (int k = 0; k < 16; k++) {
      float4 a4 = *reinterpret_cast<const float4*>(&sW[k][ty * 4]);
      float4 b4 = *reinterpret_cast<const float4*>(&sX[k][tx * 4]);
      float a[4] = {a4.x, a4.y, a4.z, a4.w};
      float bb[4] = {b4.x, b4.y, b4.z, b4.w};
#pragma unroll
      for (int i = 0; i < 4; i++)
#pragma unroll
        for (int j = 0; j < 4; j++) acc[i][j] = fmaf(a[i], bb[j], acc[i][j]);
    }
    __syncthreads();
  }
#pragma unroll
  for (int i = 0; i < 4; i++) {
    int o = o0 + ty * 4 + i;
    float bi = bias ? bias[o] : 0.f;
    size_t rowoff = (size_t)b * O * N + (size_t)o * N + n0;
#pragma unroll
    for (int j = 0; j < 4; j++) {
      int n = tx * 4 + j;
      float v = acc[i][j] + bi;
      if (resid) v += resid[rowoff + n];
      Y[rowoff + n] = v;
    }
  }
}

// Fused offset branch: dwconv3x3 stride2 -> LN(channel) -> GELU -> 64->2 proj
// -> +ref grid -> clip -> pos (BG, 256, 2) as (y,x).  One block per bg.
__global__ __launch_bounds__(256) void offset_kernel(
    const float* __restrict__ q, const float* __restrict__ odw,
    const float* __restrict__ odb, const float* __restrict__ olw,
    const float* __restrict__ olb, const float* __restrict__ opw,
    float* __restrict__ pos) {
  __shared__ float s[CG_][256];  // [channel][position] = 64 KB
  int bg = blockIdx.x;
  int b = bg / G_, g = bg % G_;
  int t = threadIdx.x;
  int hk = t >> 4, wk = t & 15;
  const float* qb = q + ((size_t)b * C_ + g * CG_) * HW_;
  for (int c = 0; c < CG_; c++) {
    float acc = odb[c];
    const float* wc = odw + c * 9;
    const float* img = qb + (size_t)c * HW_;
#pragma unroll
    for (int ky = 0; ky < 3; ky++) {
      int ih = 2 * hk + ky - 1;
      if ((unsigned)ih >= 32u) continue;
#pragma unroll
      for (int kx = 0; kx < 3; kx++) {
        int iw = 2 * wk + kx - 1;
        if ((unsigned)iw >= 32u) continue;
        acc = fmaf(wc[ky * 3 + kx], img[ih * 32 + iw], acc);
      }
    }
    s[c][t] = acc;
  }
  __syncthreads();
  float mu = 0.f;
  for (int c = 0; c < CG_; c++) mu += s[c][t];
  mu *= (1.f / CG_);
  float var = 0.f;
  for (int c = 0; c < CG_; c++) {
    float d = s[c][t] - mu;
    var = fmaf(d, d, var);
  }
  var *= (1.f / CG_);
  float rs = rsqrtf(var + 1e-5f);
  float dy = 0.f, dx = 0.f;
  for (int c = 0; c < CG_; c++) {
    float tv = (s[c][t] - mu) * rs * olw[c] + olb[c];
    float ge = gelu_exact(tv);
    dy = fmaf(opw[c], ge, dy);
    dx = fmaf(opw[CG_ + c], ge, dx);
  }
  float ry = (hk + 0.5f) * (2.f / 15.f) - 1.f;
  float rx = (wk + 0.5f) * (2.f / 15.f) - 1.f;
  float py = fminf(fmaxf(dy + ry, -1.f), 1.f);
  float px = fminf(fmaxf(dx + rx, -1.f), 1.f);
  pos[(size_t)bg * 512 + t * 2 + 0] = py;
  pos[(size_t)bg * 512 + t * 2 + 1] = px;
}

// xs[b, g*64+cg, n] = bilinear(y1[b, g*64+cg], pos[bg,n]), align_corners=True
__global__ __launch_bounds__(256) void sample_xs(
    const float* __restrict__ y1, const float* __restrict__ pos,
    float* __restrict__ xs) {
  int idx = blockIdx.x * 256 + threadIdx.x;  // 48*64*256 threads
  int n = idx & 255;
  int cg = (idx >> 8) & 63;
  int bg = idx >> 14;
  int b = bg / G_, g = bg % G_;
  float py = pos[(size_t)bg * 512 + n * 2];
  float px = pos[(size_t)bg * 512 + n * 2 + 1];
  float gx = (px + 1.f) * 15.5f, gy = (py + 1.f) * 15.5f;
  float fx = floorf(gx), fy = floorf(gy);
  float wx = gx - fx, wy = gy - fy;
  int x0 = min(max((int)fx, 0), 31), y0 = min(max((int)fy, 0), 31);
  int x1 = min(x0 + 1, 31), y1i = min(y0 + 1, 31);
  const float* img = y1 + ((size_t)b * C_ + g * CG_ + cg) * HW_;
  float v00 = img[y0 * 32 + x0], v01 = img[y0 * 32 + x1];
  float v10 = img[y1i * 32 + x0], v11 = img[y1i * 32 + x1];
  float v = v00 * (1.f - wx) * (1.f - wy) + v01 * wx * (1.f - wy) +
            v10 * (1.f - wx) * wy + v11 * wx * wy;
  xs[((size_t)b * C_ + g * CG_ + cg) * NS_ + n] = v;
}

// Fused attention: logits = scale*q.k + bilinear(rpe, disp); online softmax; PV.
// grid (HW/256, HEADS, B), 256 threads, thread = one query position m.
__global__ __launch_bounds__(256) void attn_kernel(
    const float* __restrict__ q, const float* __restrict__ k,
    const float* __restrict__ v, const float* __restrict__ pos,
    const float* __restrict__ rpe, float* __restrict__ out) {
  __shared__ float ks[NS_][36];  // n-major, padded: float4-aligned rows
  __shared__ float vs[NS_][36];
  __shared__ float rp[63 * 63];
  __shared__ float ps[NS_ * 2];
  int mc = blockIdx.x, h = blockIdx.y, b = blockIdx.z;
  int t = threadIdx.x;
  int bg = b * G_ + (h >> 1);
  const float* kb = k + ((size_t)b * C_ + h * HC_) * NS_;
  const float* vb = v + ((size_t)b * C_ + h * HC_) * NS_;
  for (int i = t; i < HC_ * NS_; i += 256) {
    int c = i >> 8, n = i & 255;
    ks[n][c] = kb[i];
    vs[n][c] = vb[i];
  }
  for (int i = t; i < 63 * 63; i += 256) rp[i] = rpe[i];
  for (int i = t; i < NS_ * 2; i += 256) ps[i] = pos[(size_t)bg * 512 + i];
  __syncthreads();
  int m = mc * 256 + t;
  const float* qp = q + ((size_t)b * C_ + h * HC_) * HW_ + m;
  float qr[HC_];
#pragma unroll
  for (int c = 0; c < HC_; c++) qr[c] = qp[(size_t)c * HW_] * SCALE_;
  float qy = (float)(m >> 5) * (2.f / 31.f) - 1.f;
  float qx = (float)(m & 31) * (2.f / 31.f) - 1.f;
  float mx = -3e30f, sum = 0.f;
  float acc[HC_];
#pragma unroll
  for (int c = 0; c < HC_; c++) acc[c] = 0.f;
  for (int n = 0; n < NS_; n++) {
    const float4* kp = reinterpret_cast<const float4*>(&ks[n][0]);
    float s = 0.f;
#pragma unroll
    for (int c4 = 0; c4 < 8; c4++) {
      float4 kk = kp[c4];
      s += qr[4 * c4] * kk.x + qr[4 * c4 + 1] * kk.y + qr[4 * c4 + 2] * kk.z +
           qr[4 * c4 + 3] * kk.w;
    }
    float py = ps[2 * n], px = ps[2 * n + 1];
    float dy = (qy - py) * 0.5f, dx = (qx - px) * 0.5f;
    float gx = (dx + 1.f) * 31.f, gy = (dy + 1.f) * 31.f;
    float fx = floorf(gx), fy = floorf(gy);
    float wx = gx - fx, wy = gy - fy;
    int x0 = min(max((int)fx, 0), 62), y0 = min(max((int)fy, 0), 62);
    int x1 = min(x0 + 1, 62), y1 = min(y0 + 1, 62);
    float b00 = rp[y0 * 63 + x0], b01 = rp[y0 * 63 + x1];
    float b10 = rp[y1 * 63 + x0], b11 = rp[y1 * 63 + x1];
    s += b00 * (1.f - wx) * (1.f - wy) + b01 * wx * (1.f - wy) +
         b10 * (1.f - wx) * wy + b11 * wx * wy;
    if (s > mx) {
      float f = __expf(mx - s);
      sum *= f;
#pragma unroll
      for (int c = 0; c < HC_; c++) acc[c] *= f;
      mx = s;
    }
    float p = __expf(s - mx);
    sum += p;
    const float4* vp = reinterpret_cast<const float4*>(&vs[n][0]);
#pragma unroll
    for (int c4 = 0; c4 < 8; c4++) {
      float4 vv = vp[c4];
      acc[4 * c4 + 0] = fmaf(p, vv.x, acc[4 * c4 + 0]);
      acc[4 * c4 + 1] = fmaf(p, vv.y, acc[4 * c4 + 1]);
      acc[4 * c4 + 2] = fmaf(p, vv.z, acc[4 * c4 + 2]);
      acc[4 * c4 + 3] = fmaf(p, vv.w, acc[4 * c4 + 3]);
    }
  }
  float inv = 1.f / sum;
  float* ob = out + ((size_t)b * C_ + h * HC_) * HW_ + m;
#pragma unroll
  for (int c = 0; c < HC_; c++) ob[(size_t)c * HW_] = acc[c] * inv;
}

}  // namespace

extern "C" void kernel_launch(void* const* d_in, const int* in_sizes, int n_in,
                              void* d_out, int out_size, void* d_ws,
                              size_t ws_size, hipStream_t stream) {
  const float* x_in = (const float*)d_in[0];
  const float* lpu_w = (const float*)d_in[1];
  const float* lpu_b = (const float*)d_in[2];
  const float* wq = (const float*)d_in[3];
  const float* bq = (const float*)d_in[4];
  const float* wk = (const float*)d_in[5];
  const float* bk = (const float*)d_in[6];
  const float* wv = (const float*)d_in[7];
  const float* bv = (const float*)d_in[8];
  const float* wo = (const float*)d_in[9];
  const float* bo = (const float*)d_in[10];
  const float* odw = (const float*)d_in[11];
  const float* odb = (const float*)d_in[12];
  const float* olw = (const float*)d_in[13];
  const float* olb = (const float*)d_in[14];
  const float* opw = (const float*)d_in[15];
  const float* rpe = (const float*)d_in[16];
  const float* w1 = (const float*)d_in[17];
  const float* b1 = (const float*)d_in[18];
  const float* mdw = (const float*)d_in[19];
  const float* mdb = (const float*)d_in[20];
  const float* w2 = (const float*)d_in[21];
  const float* b2 = (const float*)d_in[22];
  float* out = (float*)d_out;

  constexpr size_t XSZ = (size_t)B_ * C_ * HW_;   // 3,145,728
  constexpr size_t HSZ = (size_t)B_ * D2_ * HW_;  // 12,582,912
  constexpr size_t SSZ = (size_t)B_ * C_ * NS_;   // 786,432

  // Workspace layout (phase-overlapped, ~113 MB):
  //   x2    : [0, XSZ)
  //   bufB  : [XSZ, XSZ + 4*XSZ + HSZ)
  //     xin/xnext at bufB+0; y1/q/ao at +1/2/3*XSZ; xs/k/v/pos at +4*XSZ
  //     h1 at bufB+0 (over dead xin,y1,q,ao); h3 at +4*XSZ (over dead xs..pos)
  float* ws = (float*)d_ws;
  float* x2 = ws;
  float* bufB = ws + XSZ;
  float* y1 = bufB + XSZ;
  float* qbuf = bufB + 2 * XSZ;
  float* ao = bufB + 3 * XSZ;
  float* xs = bufB + 4 * XSZ;
  float* kb = xs + SSZ;
  float* vb = kb + SSZ;
  float* pos = vb + SSZ;
  float* h1 = bufB;
  float* h3 = bufB + 4 * XSZ;

  for (int d = 0; d < 2; ++d) {
    const float* xin = (d == 0) ? x_in : bufB;
    float* xnext = (d == 1) ? out : bufB;
    // LPU: y1 = xin + dwconv(xin)
    dw3x3_kernel<false><<<(int)(XSZ / 256), 256, 0, stream>>>(
        xin, lpu_w + d * C_ * 9, lpu_b + d * C_, y1, C_);
    // q = Wq @ y1 + bq
    gemm_kernel<<<dim3(HW_ / 64, C_ / 64, B_), 256, 0, stream>>>(
        wq + (size_t)d * C_ * C_, y1, bq + d * C_, nullptr, qbuf, C_, C_, HW_);
    // offsets -> pos
    offset_kernel<<<B_ * G_, 256, 0, stream>>>(
        qbuf, odw + d * CG_ * 9, odb + d * CG_, olw + d * CG_, olb + d * CG_,
        opw + d * 2 * CG_, pos);
    // deformable sampling
    sample_xs<<<(B_ * G_ * CG_ * NS_) / 256, 256, 0, stream>>>(y1, pos, xs);
    // k, v projections
    gemm_kernel<<<dim3(NS_ / 64, C_ / 64, B_), 256, 0, stream>>>(
        wk + (size_t)d * C_ * C_, xs, bk + d * C_, nullptr, kb, C_, C_, NS_);
    gemm_kernel<<<dim3(NS_ / 64, C_ / 64, B_), 256, 0, stream>>>(
        wv + (size_t)d * C_ * C_, xs, bv + d * C_, nullptr, vb, C_, C_, NS_);
    // fused attention (logits + rpe bias + softmax + PV)
    attn_kernel<<<dim3(HW_ / 256, HEADS_, B_), 256, 0, stream>>>(
        qbuf, kb, vb, pos, rpe + (size_t)d * HEADS_ * 63 * 63, ao);
    // x2 = y1 + Wo @ ao + bo
    gemm_kernel<<<dim3(HW_ / 64, C_ / 64, B_), 256, 0, stream>>>(
        wo + (size_t)d * C_ * C_, ao, bo + d * C_, y1, x2, C_, C_, HW_);
    // MLP
    gemm_kernel<<<dim3(HW_ / 64, D2_ / 64, B_), 256, 0, stream>>>(
        w1 + (size_t)d * D2_ * C_, x2, b1 + d * D2_, nullptr, h1, D2_, C_, HW_);
    dw3x3_kernel<true><<<(int)(HSZ / 256), 256, 0, stream>>>(
        h1, mdw + d * D2_ * 9, mdb + d * D2_, h3, D2_);
    gemm_kernel<<<dim3(HW_ / 64, C_ / 64, B_), 256, 0, stream>>>(
        w2 + (size_t)d * C_ * D2_, h3, b2 + d * C_, x2, xnext, C_, D2_, HW_);
  }
}

// Round 2
// 991.423 us; speedup vs baseline: 1.7583x; 1.7583x over previous
//
#include <hip/hip_runtime.h>
#include <hip/hip_bf16.h>
#include <math.h>

namespace {

constexpr int B_ = 8, C_ = 384, H_ = 32, W_ = 32, HW_ = 1024;
constexpr int HEADS_ = 12, G_ = 6, HC_ = 32, CG_ = 64, NS_ = 256, D2_ = 1536;
constexpr float SCALE_ = 0.17677669529663687f;  // 32^-0.5

using short8 = __attribute__((ext_vector_type(8))) short;
using f32x4 = __attribute__((ext_vector_type(4))) float;
typedef unsigned short ushort_t;

__device__ __forceinline__ float gelu_exact(float x) {
  return 0.5f * x * (1.f + erff(x * 0.70710678118654752f));
}
__device__ __forceinline__ ushort_t f2bf(float f) {
  unsigned u = __float_as_uint(f);
  u = (u + 0x7FFFu + ((u >> 16) & 1u)) >> 16;
  return (ushort_t)u;
}
__device__ __forceinline__ float bf2f(ushort_t s) {
  return __uint_as_float(((unsigned)s) << 16);
}
__device__ __forceinline__ float bflo(unsigned u) { return __uint_as_float(u << 16); }
__device__ __forceinline__ float bfhi(unsigned u) { return __uint_as_float(u & 0xFFFF0000u); }
__device__ __forceinline__ unsigned pack2(float a, float b) {
  return (unsigned)f2bf(a) | ((unsigned)f2bf(b) << 16);
}

// ---- weight fp32 -> bf16 (all 6 weight tensors, both depths, contiguous dst)
__global__ __launch_bounds__(256) void wcvt_kernel(
    const float* __restrict__ s0, const float* __restrict__ s1,
    const float* __restrict__ s2, const float* __restrict__ s3,
    const float* __restrict__ s4, const float* __restrict__ s5,
    ushort_t* __restrict__ dst) {
  long idx = (long)blockIdx.x * 256 + threadIdx.x;
  long off = idx;
  const float* s;
  if (off < 294912) s = s0;
  else if ((off -= 294912) < 294912) s = s1;
  else if ((off -= 294912) < 294912) s = s2;
  else if ((off -= 294912) < 294912) s = s3;
  else if ((off -= 294912) < 1179648) s = s4;
  else { off -= 1179648; s = s5; }
  dst[idx] = f2bf(s[off]);
}

// ---- LPU: y = x + dwconv3x3(x) ; writes y fp32 [b][c][hw] and yt bf16 [b][hw][c]
__global__ __launch_bounds__(256) void dwconv_lpu(
    const float* __restrict__ x, const float* __restrict__ w,
    const float* __restrict__ bias, float* __restrict__ y,
    ushort_t* __restrict__ yt) {
  __shared__ __align__(16) float tile[32][33];
  int hp = blockIdx.x;       // image row
  int c0 = blockIdx.y * 32;  // channel tile
  int b = blockIdx.z;
  int t = threadIdx.x;
#pragma unroll
  for (int it = 0; it < 4; ++it) {
    int idx = it * 256 + t;
    int cl = idx >> 5, wp = idx & 31;
    int c = c0 + cl;
    const float* img = x + ((size_t)b * C_ + c) * HW_;
    float acc = bias[c];
    const float* wc = w + c * 9;
#pragma unroll
    for (int ky = 0; ky < 3; ky++) {
      int ih = hp + ky - 1;
      if ((unsigned)ih >= 32u) continue;
#pragma unroll
      for (int kx = 0; kx < 3; kx++) {
        int iw = wp + kx - 1;
        if ((unsigned)iw >= 32u) continue;
        acc = fmaf(wc[ky * 3 + kx], img[ih * 32 + iw], acc);
      }
    }
    float v = img[hp * 32 + wp] + acc;
    y[((size_t)b * C_ + c) * HW_ + hp * 32 + wp] = v;
    tile[cl][wp] = v;
  }
  __syncthreads();
  int wl = t >> 3, cg = t & 7;
  unsigned p0 = pack2(tile[cg * 4 + 0][wl], tile[cg * 4 + 1][wl]);
  unsigned p1 = pack2(tile[cg * 4 + 2][wl], tile[cg * 4 + 3][wl]);
  unsigned* dst = (unsigned*)(yt + ((size_t)b * HW_ + hp * 32 + wl) * C_ + c0 + cg * 4);
  dst[0] = p0;
  dst[1] = p1;
}

// ---- MLP dw: h3t[b][hw][c] = bf16( gelu(h + dwconv(h)+bias) ), input h bf16 [b][c][hw]
__global__ __launch_bounds__(256) void dwgelu_t(
    const ushort_t* __restrict__ hin, const float* __restrict__ w,
    const float* __restrict__ bias, ushort_t* __restrict__ ht) {
  __shared__ __align__(16) float tile[32][33];
  int hp = blockIdx.x;
  int c0 = blockIdx.y * 32;
  int b = blockIdx.z;
  int t = threadIdx.x;
#pragma unroll
  for (int it = 0; it < 4; ++it) {
    int idx = it * 256 + t;
    int cl = idx >> 5, wp = idx & 31;
    int c = c0 + cl;
    const ushort_t* img = hin + ((size_t)b * D2_ + c) * HW_;
    float acc = bias[c];
    const float* wc = w + c * 9;
#pragma unroll
    for (int ky = 0; ky < 3; ky++) {
      int ih = hp + ky - 1;
      if ((unsigned)ih >= 32u) continue;
#pragma unroll
      for (int kx = 0; kx < 3; kx++) {
        int iw = wp + kx - 1;
        if ((unsigned)iw >= 32u) continue;
        acc = fmaf(wc[ky * 3 + kx], bf2f(img[ih * 32 + iw]), acc);
      }
    }
    float v = bf2f(img[hp * 32 + wp]) + acc;
    tile[cl][wp] = gelu_exact(v);
  }
  __syncthreads();
  int wl = t >> 3, cg = t & 7;
  unsigned p0 = pack2(tile[cg * 4 + 0][wl], tile[cg * 4 + 1][wl]);
  unsigned p1 = pack2(tile[cg * 4 + 2][wl], tile[cg * 4 + 3][wl]);
  unsigned* dst = (unsigned*)(ht + ((size_t)b * HW_ + hp * 32 + wl) * D2_ + c0 + cg * 4);
  dst[0] = p0;
  dst[1] = p1;
}

// ---- bf16 MFMA GEMM: Y[b,o,n] = sum_k W[o,k]*X[b,n,k] + bias[o] (+resid fp32)
// W bf16 [O][K]; Xt bf16 [b][N][K] (K-major!).  Outputs:
//  F32:  Y fp32 [b][O][N];  B16N: Yb bf16 [b][O][N];  B16T: Yb bf16 [b][N][O]
template <bool F32, bool B16N, bool B16T, bool RES>
__global__ __launch_bounds__(256) void gemm_bf16(
    const ushort_t* __restrict__ Wb, const ushort_t* __restrict__ Xt,
    const float* __restrict__ bias, const float* __restrict__ resid,
    float* __restrict__ Y, ushort_t* __restrict__ Yb, int O, int K, int N) {
  struct __align__(16) SMem {
    union {
      struct { char a[8192]; char b[8192]; } st;
      float shuf[64 * 68];
    };
  };
  __shared__ SMem sm;
  int t = threadIdx.x;
  int lane = t & 63, wave = t >> 6;
  int wm = (wave >> 1) * 32, wn = (wave & 1) * 32;
  int bz = blockIdx.z;
  int o0 = blockIdx.y * 64, n0 = blockIdx.x * 64;
  const ushort_t* Ag = Wb + (size_t)o0 * K;
  const ushort_t* Bg = Xt + ((size_t)bz * N + n0) * K;
  int sr = t >> 3, sc = t & 7;
  int swz = ((sc ^ (sr & 7)) << 4);
  f32x4 acc[2][2];
#pragma unroll
  for (int fi = 0; fi < 2; ++fi)
#pragma unroll
    for (int fj = 0; fj < 2; ++fj) acc[fi][fj] = f32x4{0.f, 0.f, 0.f, 0.f};
  int lrow = lane & 15, lk = lane >> 4;
  for (int k0 = 0; k0 < K; k0 += 64) {
    short8 a0 = *(const short8*)(Ag + (size_t)sr * K + k0 + sc * 8);
    short8 a1 = *(const short8*)(Ag + (size_t)(sr + 32) * K + k0 + sc * 8);
    short8 b0 = *(const short8*)(Bg + (size_t)sr * K + k0 + sc * 8);
    short8 b1 = *(const short8*)(Bg + (size_t)(sr + 32) * K + k0 + sc * 8);
    __syncthreads();
    *(short8*)(sm.st.a + sr * 128 + swz) = a0;
    *(short8*)(sm.st.a + (sr + 32) * 128 + swz) = a1;
    *(short8*)(sm.st.b + sr * 128 + swz) = b0;
    *(short8*)(sm.st.b + (sr + 32) * 128 + swz) = b1;
    __syncthreads();
#pragma unroll
    for (int kk = 0; kk < 2; ++kk) {
      short8 af[2], bfr[2];
#pragma unroll
      for (int fi = 0; fi < 2; ++fi) {
        int row = wm + fi * 16 + lrow;
        af[fi] = *(const short8*)(sm.st.a + row * 128 + (((kk * 4 + lk) ^ (row & 7)) << 4));
      }
#pragma unroll
      for (int fj = 0; fj < 2; ++fj) {
        int row = wn + fj * 16 + lrow;
        bfr[fj] = *(const short8*)(sm.st.b + row * 128 + (((kk * 4 + lk) ^ (row & 7)) << 4));
      }
#pragma unroll
      for (int fi = 0; fi < 2; ++fi)
#pragma unroll
        for (int fj = 0; fj < 2; ++fj)
          acc[fi][fj] = __builtin_amdgcn_mfma_f32_16x16x32_bf16(af[fi], bfr[fj], acc[fi][fj], 0, 0, 0);
    }
  }
  if (B16N || B16T) __syncthreads();  // st -> shuf reuse
#pragma unroll
  for (int fi = 0; fi < 2; ++fi) {
#pragma unroll
    for (int r = 0; r < 4; ++r) {
      int ol = wm + fi * 16 + lk * 4 + r;
      float bi = bias[o0 + ol];
#pragma unroll
      for (int fj = 0; fj < 2; ++fj) {
        int nl = wn + fj * 16 + lrow;
        float v = acc[fi][fj][r] + bi;
        if (RES) v += resid[((size_t)bz * O + (o0 + ol)) * N + n0 + nl];
        if (F32) Y[((size_t)bz * O + (o0 + ol)) * N + n0 + nl] = v;
        if (B16N || B16T) sm.shuf[ol * 68 + nl] = v;
      }
    }
  }
  if (B16N || B16T) {
    __syncthreads();
    if (B16T) {
      int nl = t >> 2, og = (t & 3) * 16;
      unsigned pk[8];
#pragma unroll
      for (int i = 0; i < 8; ++i)
        pk[i] = pack2(sm.shuf[(og + 2 * i) * 68 + nl], sm.shuf[(og + 2 * i + 1) * 68 + nl]);
      unsigned* dst = (unsigned*)(Yb + ((size_t)bz * N + (n0 + nl)) * O + o0 + og);
      *(uint4*)(dst) = make_uint4(pk[0], pk[1], pk[2], pk[3]);
      *(uint4*)(dst + 4) = make_uint4(pk[4], pk[5], pk[6], pk[7]);
    } else {
      int ol = t >> 2, ng = (t & 3) * 16;
      unsigned pk[8];
#pragma unroll
      for (int i = 0; i < 8; ++i)
        pk[i] = pack2(sm.shuf[ol * 68 + ng + 2 * i], sm.shuf[ol * 68 + ng + 2 * i + 1]);
      unsigned* dst = (unsigned*)(Yb + ((size_t)bz * O + (o0 + ol)) * N + n0 + ng);
      *(uint4*)(dst) = make_uint4(pk[0], pk[1], pk[2], pk[3]);
      *(uint4*)(dst + 4) = make_uint4(pk[4], pk[5], pk[6], pk[7]);
    }
  }
}

// ---- offset branch: reads qt bf16 [b][hw][c]
__global__ __launch_bounds__(256) void offset_kernel(
    const ushort_t* __restrict__ qt, const float* __restrict__ odw,
    const float* __restrict__ odb, const float* __restrict__ olw,
    const float* __restrict__ olb, const float* __restrict__ opw,
    float* __restrict__ pos) {
  __shared__ float s[CG_][256];
  int bg = blockIdx.x;
  int b = bg / G_, g = bg % G_;
  int t = threadIdx.x;
  int hk = t >> 4, wk = t & 15;
  const ushort_t* qb = qt + (size_t)b * HW_ * C_ + g * CG_;
  for (int c = 0; c < CG_; c++) {
    float acc = odb[c];
    const float* wc = odw + c * 9;
#pragma unroll
    for (int ky = 0; ky < 3; ky++) {
      int ih = 2 * hk + ky - 1;
      if ((unsigned)ih >= 32u) continue;
#pragma unroll
      for (int kx = 0; kx < 3; kx++) {
        int iw = 2 * wk + kx - 1;
        if ((unsigned)iw >= 32u) continue;
        acc = fmaf(wc[ky * 3 + kx], bf2f(qb[(size_t)(ih * 32 + iw) * C_ + c]), acc);
      }
    }
    s[c][t] = acc;
  }
  __syncthreads();
  float mu = 0.f;
  for (int c = 0; c < CG_; c++) mu += s[c][t];
  mu *= (1.f / CG_);
  float var = 0.f;
  for (int c = 0; c < CG_; c++) {
    float d = s[c][t] - mu;
    var = fmaf(d, d, var);
  }
  var *= (1.f / CG_);
  float rs = rsqrtf(var + 1e-5f);
  float dy = 0.f, dx = 0.f;
  for (int c = 0; c < CG_; c++) {
    float tv = (s[c][t] - mu) * rs * olw[c] + olb[c];
    float ge = gelu_exact(tv);
    dy = fmaf(opw[c], ge, dy);
    dx = fmaf(opw[CG_ + c], ge, dx);
  }
  float ry = (hk + 0.5f) * (2.f / 15.f) - 1.f;
  float rx = (wk + 0.5f) * (2.f / 15.f) - 1.f;
  pos[(size_t)bg * 512 + t * 2 + 0] = fminf(fmaxf(dy + ry, -1.f), 1.f);
  pos[(size_t)bg * 512 + t * 2 + 1] = fminf(fmaxf(dx + rx, -1.f), 1.f);
}

// ---- deformable sampling (fp32 y1 -> fp32 xs [bg][cg][n])
__global__ __launch_bounds__(256) void sample_xs(
    const float* __restrict__ y1, const float* __restrict__ pos,
    float* __restrict__ xs) {
  int idx = blockIdx.x * 256 + threadIdx.x;
  int n = idx & 255;
  int cg = (idx >> 8) & 63;
  int bg = idx >> 14;
  int b = bg / G_, g = bg % G_;
  float py = pos[(size_t)bg * 512 + n * 2];
  float px = pos[(size_t)bg * 512 + n * 2 + 1];
  float gx = (px + 1.f) * 15.5f, gy = (py + 1.f) * 15.5f;
  float fx = floorf(gx), fy = floorf(gy);
  float wx = gx - fx, wy = gy - fy;
  int x0 = min(max((int)fx, 0), 31), y0 = min(max((int)fy, 0), 31);
  int x1 = min(x0 + 1, 31), y1i = min(y0 + 1, 31);
  const float* img = y1 + ((size_t)b * C_ + g * CG_ + cg) * HW_;
  float v00 = img[y0 * 32 + x0], v01 = img[y0 * 32 + x1];
  float v10 = img[y1i * 32 + x0], v11 = img[y1i * 32 + x1];
  xs[((size_t)bg * CG_ + cg) * NS_ + n] =
      v00 * (1.f - wx) * (1.f - wy) + v01 * wx * (1.f - wy) +
      v10 * (1.f - wx) * wy + v11 * wx * wy;
}

// ---- xs fp32 [bg][cg][n] -> xst bf16 [b][n][C] (c = g*64+cg)
__global__ __launch_bounds__(256) void t_xs(const float* __restrict__ xs,
                                            ushort_t* __restrict__ xst) {
  __shared__ __align__(16) float tile[32][33];
  int n0 = blockIdx.x * 32, c0 = blockIdx.y * 32, bg = blockIdx.z;
  int b = bg / G_, g = bg % G_;
  int t = threadIdx.x;
#pragma unroll
  for (int it = 0; it < 4; ++it) {
    int idx = it * 256 + t;
    int cl = idx >> 5, nl = idx & 31;
    tile[cl][nl] = xs[((size_t)bg * CG_ + c0 + cl) * NS_ + n0 + nl];
  }
  __syncthreads();
  int nl = t >> 3, cg = t & 7;
  unsigned p0 = pack2(tile[cg * 4 + 0][nl], tile[cg * 4 + 1][nl]);
  unsigned p1 = pack2(tile[cg * 4 + 2][nl], tile[cg * 4 + 3][nl]);
  unsigned* dst = (unsigned*)(xst + ((size_t)b * NS_ + n0 + nl) * C_ + g * CG_ + c0 + cg * 4);
  dst[0] = p0;
  dst[1] = p1;
}

// ---- fused attention; all activations bf16 K-major; out aot bf16 [b][m][c]
__global__ __launch_bounds__(256) void attn_kernel(
    const ushort_t* __restrict__ qt, const ushort_t* __restrict__ kt,
    const ushort_t* __restrict__ vt, const float* __restrict__ pos,
    const float* __restrict__ rpe, ushort_t* __restrict__ aot) {
  __shared__ __align__(16) float ks[NS_][HC_];
  __shared__ __align__(16) float vs[NS_][HC_];
  __shared__ ushort_t rp[63 * 63];
  __shared__ float ps[NS_ * 2];
  int mc = blockIdx.x, h = blockIdx.y, b = blockIdx.z;
  int t = threadIdx.x;
  int bg = b * G_ + (h >> 1);
  {
    const uint4* kr = (const uint4*)(kt + ((size_t)b * NS_ + t) * C_ + h * HC_);
    const uint4* vr = (const uint4*)(vt + ((size_t)b * NS_ + t) * C_ + h * HC_);
    int sw = t & 7;
#pragma unroll
    for (int q4 = 0; q4 < 4; ++q4) {
      uint4 u = kr[q4];
      *(float4*)&ks[t][((2 * q4) ^ sw) * 4] = make_float4(bflo(u.x), bfhi(u.x), bflo(u.y), bfhi(u.y));
      *(float4*)&ks[t][((2 * q4 + 1) ^ sw) * 4] = make_float4(bflo(u.z), bfhi(u.z), bflo(u.w), bfhi(u.w));
      u = vr[q4];
      *(float4*)&vs[t][((2 * q4) ^ sw) * 4] = make_float4(bflo(u.x), bfhi(u.x), bflo(u.y), bfhi(u.y));
      *(float4*)&vs[t][((2 * q4 + 1) ^ sw) * 4] = make_float4(bflo(u.z), bfhi(u.z), bflo(u.w), bfhi(u.w));
    }
  }
  const float* rph = rpe + (size_t)h * 3969;
  for (int i = t; i < 3969; i += 256) rp[i] = f2bf(rph[i]);
  for (int i = t; i < 512; i += 256) ps[i] = pos[(size_t)bg * 512 + i];
  __syncthreads();
  int m = mc * 256 + t;
  float qr[HC_];
  {
    const uint4* qp = (const uint4*)(qt + ((size_t)b * HW_ + m) * C_ + h * HC_);
#pragma unroll
    for (int q4 = 0; q4 < 4; ++q4) {
      uint4 u = qp[q4];
      qr[8 * q4 + 0] = bflo(u.x) * SCALE_;
      qr[8 * q4 + 1] = bfhi(u.x) * SCALE_;
      qr[8 * q4 + 2] = bflo(u.y) * SCALE_;
      qr[8 * q4 + 3] = bfhi(u.y) * SCALE_;
      qr[8 * q4 + 4] = bflo(u.z) * SCALE_;
      qr[8 * q4 + 5] = bfhi(u.z) * SCALE_;
      qr[8 * q4 + 6] = bflo(u.w) * SCALE_;
      qr[8 * q4 + 7] = bfhi(u.w) * SCALE_;
    }
  }
  float qy = (float)(m >> 5) * (2.f / 31.f) - 1.f;
  float qx = (float)(m & 31) * (2.f / 31.f) - 1.f;
  float mx = -3e30f, sum = 0.f;
  float acc[HC_];
#pragma unroll
  for (int c = 0; c < HC_; c++) acc[c] = 0.f;
  for (int n0 = 0; n0 < NS_; n0 += 8) {
    float s[8];
#pragma unroll
    for (int j = 0; j < 8; ++j) {
      int n = n0 + j;
      int sw = n & 7;
      const float4* kp = (const float4*)&ks[n][0];
      float a0 = 0.f, a1 = 0.f;
#pragma unroll
      for (int c4 = 0; c4 < 8; c4 += 2) {
        float4 k0 = kp[c4 ^ sw];
        float4 k1 = kp[(c4 + 1) ^ sw];
        a0 += qr[4 * c4 + 0] * k0.x + qr[4 * c4 + 1] * k0.y + qr[4 * c4 + 2] * k0.z + qr[4 * c4 + 3] * k0.w;
        a1 += qr[4 * c4 + 4] * k1.x + qr[4 * c4 + 5] * k1.y + qr[4 * c4 + 6] * k1.z + qr[4 * c4 + 7] * k1.w;
      }
      float py = ps[2 * n], px = ps[2 * n + 1];
      float gy = ((qy - py) * 0.5f + 1.f) * 31.f;
      float gx = ((qx - px) * 0.5f + 1.f) * 31.f;
      float fy = floorf(gy), fx = floorf(gx);
      float wy = gy - fy, wx = gx - fx;
      int y0 = min(max((int)fy, 0), 62), x0 = min(max((int)fx, 0), 62);
      int y1 = min(y0 + 1, 62), x1 = min(x0 + 1, 62);
      float b00 = bf2f(rp[y0 * 63 + x0]), b01 = bf2f(rp[y0 * 63 + x1]);
      float b10 = bf2f(rp[y1 * 63 + x0]), b11 = bf2f(rp[y1 * 63 + x1]);
      s[j] = a0 + a1 + b00 * (1.f - wx) * (1.f - wy) + b01 * wx * (1.f - wy) +
             b10 * (1.f - wx) * wy + b11 * wx * wy;
    }
    float m8 = fmaxf(fmaxf(fmaxf(s[0], s[1]), fmaxf(s[2], s[3])),
                     fmaxf(fmaxf(s[4], s[5]), fmaxf(s[6], s[7])));
    float newm = fmaxf(mx, m8);
    float f = __expf(mx - newm);
    mx = newm;
    float p[8];
    float psum = 0.f;
#pragma unroll
    for (int j = 0; j < 8; ++j) {
      p[j] = __expf(s[j] - newm);
      psum += p[j];
    }
    sum = sum * f + psum;
#pragma unroll
    for (int c = 0; c < HC_; ++c) acc[c] *= f;
#pragma unroll
    for (int j = 0; j < 8; ++j) {
      int n = n0 + j;
      int sw = n & 7;
      const float4* vp = (const float4*)&vs[n][0];
#pragma unroll
      for (int c4 = 0; c4 < 8; ++c4) {
        float4 vv = vp[c4 ^ sw];
        acc[4 * c4 + 0] = fmaf(p[j], vv.x, acc[4 * c4 + 0]);
        acc[4 * c4 + 1] = fmaf(p[j], vv.y, acc[4 * c4 + 1]);
        acc[4 * c4 + 2] = fmaf(p[j], vv.z, acc[4 * c4 + 2]);
        acc[4 * c4 + 3] = fmaf(p[j], vv.w, acc[4 * c4 + 3]);
      }
    }
  }
  float inv = 1.f / sum;
  unsigned* dst = (unsigned*)(aot + ((size_t)b * HW_ + m) * C_ + h * HC_);
#pragma unroll
  for (int gq = 0; gq < 4; ++gq) {
    uint4 o4;
    o4.x = pack2(acc[8 * gq + 0] * inv, acc[8 * gq + 1] * inv);
    o4.y = pack2(acc[8 * gq + 2] * inv, acc[8 * gq + 3] * inv);
    o4.z = pack2(acc[8 * gq + 4] * inv, acc[8 * gq + 5] * inv);
    o4.w = pack2(acc[8 * gq + 6] * inv, acc[8 * gq + 7] * inv);
    ((uint4*)dst)[gq] = o4;
  }
}

}  // namespace

extern "C" void kernel_launch(void* const* d_in, const int* in_sizes, int n_in,
                              void* d_out, int out_size, void* d_ws,
                              size_t ws_size, hipStream_t stream) {
  const float* x_in = (const float*)d_in[0];
  const float* lpu_w = (const float*)d_in[1];
  const float* lpu_b = (const float*)d_in[2];
  const float* wq = (const float*)d_in[3];
  const float* bq = (const float*)d_in[4];
  const float* wk = (const float*)d_in[5];
  const float* bk = (const float*)d_in[6];
  const float* wv = (const float*)d_in[7];
  const float* bv = (const float*)d_in[8];
  const float* wo = (const float*)d_in[9];
  const float* bo = (const float*)d_in[10];
  const float* odw = (const float*)d_in[11];
  const float* odb = (const float*)d_in[12];
  const float* olw = (const float*)d_in[13];
  const float* olb = (const float*)d_in[14];
  const float* opw = (const float*)d_in[15];
  const float* rpe = (const float*)d_in[16];
  const float* w1 = (const float*)d_in[17];
  const float* b1 = (const float*)d_in[18];
  const float* mdw = (const float*)d_in[19];
  const float* mdb = (const float*)d_in[20];
  const float* w2 = (const float*)d_in[21];
  const float* b2 = (const float*)d_in[22];
  float* out = (float*)d_out;

  constexpr size_t XSZ = (size_t)B_ * C_ * HW_;   // 3,145,728
  constexpr size_t SSZ = (size_t)B_ * C_ * NS_;   // 786,432
  constexpr size_t HSZ = (size_t)B_ * D2_ * HW_;  // 12,582,912

  char* base = (char*)d_ws;
  auto alloc = [&](size_t bytes) {
    char* p = base;
    base += (bytes + 255) & ~(size_t)255;
    return p;
  };
  float* bufX = (float*)alloc(XSZ * 4);
  float* y1 = (float*)alloc(XSZ * 4);
  float* x2 = (float*)alloc(XSZ * 4);
  float* xs = (float*)alloc(SSZ * 4);
  float* pos = (float*)alloc(48 * 512 * 4);
  ushort_t* qt = (ushort_t*)alloc(XSZ * 2);
  ushort_t* tb1 = (ushort_t*)alloc(XSZ * 2);  // y1t, later x2t
  ushort_t* aot = (ushort_t*)alloc(XSZ * 2);
  ushort_t* xst = (ushort_t*)alloc(SSZ * 2);
  ushort_t* ktb = (ushort_t*)alloc(SSZ * 2);
  ushort_t* vtb = (ushort_t*)alloc(SSZ * 2);
  ushort_t* h1b = (ushort_t*)alloc(HSZ * 2);
  ushort_t* h3t = (ushort_t*)alloc(HSZ * 2);
  ushort_t* wb = (ushort_t*)alloc((size_t)3538944 * 2);

  ushort_t* wqb = wb;
  ushort_t* wkb = wb + 294912;
  ushort_t* wvb = wb + 589824;
  ushort_t* wob = wb + 884736;
  ushort_t* w1b = wb + 1179648;
  ushort_t* w2b = wb + 2359296;

  wcvt_kernel<<<3538944 / 256, 256, 0, stream>>>(wq, wk, wv, wo, w1, w2, wb);

  for (int d = 0; d < 2; ++d) {
    const float* xin = (d == 0) ? x_in : bufX;
    float* xnext = (d == 1) ? out : bufX;
    const ushort_t* wqd = wqb + (size_t)d * 147456;
    const ushort_t* wkd = wkb + (size_t)d * 147456;
    const ushort_t* wvd = wvb + (size_t)d * 147456;
    const ushort_t* wod = wob + (size_t)d * 147456;
    const ushort_t* w1d = w1b + (size_t)d * 589824;
    const ushort_t* w2d = w2b + (size_t)d * 589824;

    // LPU: y1 = xin + dw(xin) ; y1t = bf16T(y1)
    dwconv_lpu<<<dim3(32, 12, 8), 256, 0, stream>>>(xin, lpu_w + d * C_ * 9,
                                                    lpu_b + d * C_, y1, tb1);
    // q (bf16T only)
    gemm_bf16<false, false, true, false><<<dim3(16, 6, 8), 256, 0, stream>>>(
        wqd, tb1, bq + d * C_, nullptr, nullptr, qt, C_, C_, HW_);
    // offsets
    offset_kernel<<<48, 256, 0, stream>>>(qt, odw + d * CG_ * 9, odb + d * CG_,
                                          olw + d * CG_, olb + d * CG_,
                                          opw + d * 2 * CG_, pos);
    // sampling + transpose
    sample_xs<<<(int)(SSZ / 256), 256, 0, stream>>>(y1, pos, xs);
    t_xs<<<dim3(8, 2, 48), 256, 0, stream>>>(xs, xst);
    // k, v (bf16T only)
    gemm_bf16<false, false, true, false><<<dim3(4, 6, 8), 256, 0, stream>>>(
        wkd, xst, bk + d * C_, nullptr, nullptr, ktb, C_, C_, NS_);
    gemm_bf16<false, false, true, false><<<dim3(4, 6, 8), 256, 0, stream>>>(
        wvd, xst, bv + d * C_, nullptr, nullptr, vtb, C_, C_, NS_);
    // attention
    attn_kernel<<<dim3(4, 12, 8), 256, 0, stream>>>(
        qt, ktb, vtb, pos, rpe + (size_t)d * HEADS_ * 63 * 63, aot);
    // out proj: x2 = y1 + Wo@ao (fp32) ; x2t = bf16T
    gemm_bf16<true, false, true, true><<<dim3(16, 6, 8), 256, 0, stream>>>(
        wod, aot, bo + d * C_, y1, x2, tb1, C_, C_, HW_);
    // mlp1: h1b = bf16N(W1@x2 + b1)
    gemm_bf16<false, true, false, false><<<dim3(16, 24, 8), 256, 0, stream>>>(
        w1d, tb1, b1 + d * D2_, nullptr, nullptr, h1b, D2_, C_, HW_);
    // mlp dwconv + gelu -> h3t bf16T
    dwgelu_t<<<dim3(32, 48, 8), 256, 0, stream>>>(h1b, mdw + d * D2_ * 9,
                                                  mdb + d * D2_, h3t);
    // mlp2: xnext = x2 + W2@h3 (fp32)
    gemm_bf16<true, false, false, true><<<dim3(16, 6, 8), 256, 0, stream>>>(
        w2d, h3t, b2 + d * C_, x2, xnext, nullptr, C_, D2_, HW_);
  }
}

// Round 4
// 883.414 us; speedup vs baseline: 1.9733x; 1.1223x over previous
//
#include <hip/hip_runtime.h>
#include <hip/hip_bf16.h>
#include <math.h>

namespace {

constexpr int B_ = 8, C_ = 384, H_ = 32, W_ = 32, HW_ = 1024;
constexpr int HEADS_ = 12, G_ = 6, HC_ = 32, CG_ = 64, NS_ = 256, D2_ = 1536;
constexpr float SCALE_ = 0.17677669529663687f;  // 32^-0.5

using short8 = __attribute__((ext_vector_type(8))) short;
using f32x4 = __attribute__((ext_vector_type(4))) float;
using u32x4 = __attribute__((ext_vector_type(4))) unsigned;
typedef unsigned short ushort_t;

__device__ __forceinline__ float gelu_exact(float x) {
  return 0.5f * x * (1.f + erff(x * 0.70710678118654752f));
}
__device__ __forceinline__ ushort_t f2bf(float f) {
  unsigned u = __float_as_uint(f);
  u = (u + 0x7FFFu + ((u >> 16) & 1u)) >> 16;
  return (ushort_t)u;
}
__device__ __forceinline__ float bf2f(ushort_t s) {
  return __uint_as_float(((unsigned)s) << 16);
}
__device__ __forceinline__ float bflo(unsigned u) { return __uint_as_float(u << 16); }
__device__ __forceinline__ float bfhi(unsigned u) { return __uint_as_float(u & 0xFFFF0000u); }
__device__ __forceinline__ unsigned pack2(float a, float b) {
  return (unsigned)f2bf(a) | ((unsigned)f2bf(b) << 16);
}

typedef __attribute__((address_space(1))) const unsigned int gq_u32;
typedef __attribute__((address_space(3))) unsigned int lq_u32;
__device__ __forceinline__ void gload16(const ushort_t* g, ushort_t* l) {
  __builtin_amdgcn_global_load_lds((gq_u32*)g, (lq_u32*)l, 16, 0, 0);
}

// ---- weight fp32 -> bf16
__global__ __launch_bounds__(256) void wcvt_kernel(
    const float* __restrict__ s0, const float* __restrict__ s1,
    const float* __restrict__ s2, const float* __restrict__ s3,
    const float* __restrict__ s4, const float* __restrict__ s5,
    ushort_t* __restrict__ dst) {
  long idx = (long)blockIdx.x * 256 + threadIdx.x;
  long off = idx;
  const float* s;
  if (off < 294912) s = s0;
  else if ((off -= 294912) < 294912) s = s1;
  else if ((off -= 294912) < 294912) s = s2;
  else if ((off -= 294912) < 294912) s = s3;
  else if ((off -= 294912) < 1179648) s = s4;
  else { off -= 1179648; s = s5; }
  dst[idx] = f2bf(s[off]);
}

// ---- LPU: y = x + dwconv3x3(x) ; writes y fp32 [b][c][hw] and yt bf16 [b][hw][c]
__global__ __launch_bounds__(256) void dwconv_lpu(
    const float* __restrict__ x, const float* __restrict__ w,
    const float* __restrict__ bias, float* __restrict__ y,
    ushort_t* __restrict__ yt) {
  __shared__ __align__(16) float tile[32][33];
  int hp = blockIdx.x;
  int c0 = blockIdx.y * 32;
  int b = blockIdx.z;
  int t = threadIdx.x;
#pragma unroll
  for (int it = 0; it < 4; ++it) {
    int idx = it * 256 + t;
    int cl = idx >> 5, wp = idx & 31;
    int c = c0 + cl;
    const float* img = x + ((size_t)b * C_ + c) * HW_;
    float acc = bias[c];
    const float* wc = w + c * 9;
#pragma unroll
    for (int ky = 0; ky < 3; ky++) {
      int ih = hp + ky - 1;
      if ((unsigned)ih >= 32u) continue;
#pragma unroll
      for (int kx = 0; kx < 3; kx++) {
        int iw = wp + kx - 1;
        if ((unsigned)iw >= 32u) continue;
        acc = fmaf(wc[ky * 3 + kx], img[ih * 32 + iw], acc);
      }
    }
    float v = img[hp * 32 + wp] + acc;
    y[((size_t)b * C_ + c) * HW_ + hp * 32 + wp] = v;
    tile[cl][wp] = v;
  }
  __syncthreads();
  int wl = t >> 3, cg = t & 7;
  unsigned p0 = pack2(tile[cg * 4 + 0][wl], tile[cg * 4 + 1][wl]);
  unsigned p1 = pack2(tile[cg * 4 + 2][wl], tile[cg * 4 + 3][wl]);
  unsigned* dst = (unsigned*)(yt + ((size_t)b * HW_ + hp * 32 + wl) * C_ + c0 + cg * 4);
  dst[0] = p0;
  dst[1] = p1;
}

// ---- MLP dw: h3t[b][hw][c] = bf16( gelu(h + dwconv(h)+bias) )
__global__ __launch_bounds__(256) void dwgelu_t(
    const ushort_t* __restrict__ hin, const float* __restrict__ w,
    const float* __restrict__ bias, ushort_t* __restrict__ ht) {
  __shared__ __align__(16) float tile[32][33];
  int hp = blockIdx.x;
  int c0 = blockIdx.y * 32;
  int b = blockIdx.z;
  int t = threadIdx.x;
#pragma unroll
  for (int it = 0; it < 4; ++it) {
    int idx = it * 256 + t;
    int cl = idx >> 5, wp = idx & 31;
    int c = c0 + cl;
    const ushort_t* img = hin + ((size_t)b * D2_ + c) * HW_;
    float acc = bias[c];
    const float* wc = w + c * 9;
#pragma unroll
    for (int ky = 0; ky < 3; ky++) {
      int ih = hp + ky - 1;
      if ((unsigned)ih >= 32u) continue;
#pragma unroll
      for (int kx = 0; kx < 3; kx++) {
        int iw = wp + kx - 1;
        if ((unsigned)iw >= 32u) continue;
        acc = fmaf(wc[ky * 3 + kx], bf2f(img[ih * 32 + iw]), acc);
      }
    }
    float v = bf2f(img[hp * 32 + wp]) + acc;
    tile[cl][wp] = gelu_exact(v);
  }
  __syncthreads();
  int wl = t >> 3, cg = t & 7;
  unsigned p0 = pack2(tile[cg * 4 + 0][wl], tile[cg * 4 + 1][wl]);
  unsigned p1 = pack2(tile[cg * 4 + 2][wl], tile[cg * 4 + 3][wl]);
  unsigned* dst = (unsigned*)(ht + ((size_t)b * HW_ + hp * 32 + wl) * D2_ + c0 + cg * 4);
  dst[0] = p0;
  dst[1] = p1;
}

// ---- 64-tile bf16 MFMA GEMM (kept for N=256 K/V projections)
template <bool F32, bool B16N, bool B16T, bool RES>
__global__ __launch_bounds__(256) void gemm_bf16(
    const ushort_t* __restrict__ Wb, const ushort_t* __restrict__ Xt,
    const float* __restrict__ bias, const float* __restrict__ resid,
    float* __restrict__ Y, ushort_t* __restrict__ Yb, int O, int K, int N) {
  struct __align__(16) SMem {
    union {
      struct { char a[8192]; char b[8192]; } st;
      float shuf[64 * 68];
    };
  };
  __shared__ SMem sm;
  int t = threadIdx.x;
  int lane = t & 63, wave = t >> 6;
  int wm = (wave >> 1) * 32, wn = (wave & 1) * 32;
  int bz = blockIdx.z;
  int o0 = blockIdx.y * 64, n0 = blockIdx.x * 64;
  const ushort_t* Ag = Wb + (size_t)o0 * K;
  const ushort_t* Bg = Xt + ((size_t)bz * N + n0) * K;
  int sr = t >> 3, sc = t & 7;
  int swz = ((sc ^ (sr & 7)) << 4);
  f32x4 acc[2][2];
#pragma unroll
  for (int fi = 0; fi < 2; ++fi)
#pragma unroll
    for (int fj = 0; fj < 2; ++fj) acc[fi][fj] = f32x4{0.f, 0.f, 0.f, 0.f};
  int lrow = lane & 15, lk = lane >> 4;
  for (int k0 = 0; k0 < K; k0 += 64) {
    short8 a0 = *(const short8*)(Ag + (size_t)sr * K + k0 + sc * 8);
    short8 a1 = *(const short8*)(Ag + (size_t)(sr + 32) * K + k0 + sc * 8);
    short8 b0 = *(const short8*)(Bg + (size_t)sr * K + k0 + sc * 8);
    short8 b1 = *(const short8*)(Bg + (size_t)(sr + 32) * K + k0 + sc * 8);
    __syncthreads();
    *(short8*)(sm.st.a + sr * 128 + swz) = a0;
    *(short8*)(sm.st.a + (sr + 32) * 128 + swz) = a1;
    *(short8*)(sm.st.b + sr * 128 + swz) = b0;
    *(short8*)(sm.st.b + (sr + 32) * 128 + swz) = b1;
    __syncthreads();
#pragma unroll
    for (int kk = 0; kk < 2; ++kk) {
      short8 af[2], bfr[2];
#pragma unroll
      for (int fi = 0; fi < 2; ++fi) {
        int row = wm + fi * 16 + lrow;
        af[fi] = *(const short8*)(sm.st.a + row * 128 + (((kk * 4 + lk) ^ (row & 7)) << 4));
      }
#pragma unroll
      for (int fj = 0; fj < 2; ++fj) {
        int row = wn + fj * 16 + lrow;
        bfr[fj] = *(const short8*)(sm.st.b + row * 128 + (((kk * 4 + lk) ^ (row & 7)) << 4));
      }
#pragma unroll
      for (int fi = 0; fi < 2; ++fi)
#pragma unroll
        for (int fj = 0; fj < 2; ++fj)
          acc[fi][fj] = __builtin_amdgcn_mfma_f32_16x16x32_bf16(af[fi], bfr[fj], acc[fi][fj], 0, 0, 0);
    }
  }
  if (B16N || B16T) __syncthreads();
#pragma unroll
  for (int fi = 0; fi < 2; ++fi) {
#pragma unroll
    for (int r = 0; r < 4; ++r) {
      int ol = wm + fi * 16 + lk * 4 + r;
      float bi = bias[o0 + ol];
#pragma unroll
      for (int fj = 0; fj < 2; ++fj) {
        int nl = wn + fj * 16 + lrow;
        float v = acc[fi][fj][r] + bi;
        if (RES) v += resid[((size_t)bz * O + (o0 + ol)) * N + n0 + nl];
        if (F32) Y[((size_t)bz * O + (o0 + ol)) * N + n0 + nl] = v;
        if (B16N || B16T) sm.shuf[ol * 68 + nl] = v;
      }
    }
  }
  if (B16N || B16T) {
    __syncthreads();
    if (B16T) {
      int nl = t >> 2, og = (t & 3) * 16;
      unsigned pk[8];
#pragma unroll
      for (int i = 0; i < 8; ++i)
        pk[i] = pack2(sm.shuf[(og + 2 * i) * 68 + nl], sm.shuf[(og + 2 * i + 1) * 68 + nl]);
      unsigned* dst = (unsigned*)(Yb + ((size_t)bz * N + (n0 + nl)) * O + o0 + og);
      *(uint4*)(dst) = make_uint4(pk[0], pk[1], pk[2], pk[3]);
      *(uint4*)(dst + 4) = make_uint4(pk[4], pk[5], pk[6], pk[7]);
    } else {
      int ol = t >> 2, ng = (t & 3) * 16;
      unsigned pk[8];
#pragma unroll
      for (int i = 0; i < 8; ++i)
        pk[i] = pack2(sm.shuf[ol * 68 + ng + 2 * i], sm.shuf[ol * 68 + ng + 2 * i + 1]);
      unsigned* dst = (unsigned*)(Yb + ((size_t)bz * O + (o0 + ol)) * N + n0 + ng);
      *(uint4*)(dst) = make_uint4(pk[0], pk[1], pk[2], pk[3]);
      *(uint4*)(dst + 4) = make_uint4(pk[4], pk[5], pk[6], pk[7]);
    }
  }
}

// ---- m97-style 128x128x64 bf16 GEMM with global_load_lds staging.
// W bf16 [O][K]; Xt bf16 [b][N][K].  Epilogues as gemm_bf16.
template <bool F32, bool B16N, bool B16T, bool RES>
__global__ __launch_bounds__(256) void gemm128(
    const ushort_t* __restrict__ Wb, const ushort_t* __restrict__ Xt,
    const float* __restrict__ bias, const float* __restrict__ resid,
    float* __restrict__ Y, ushort_t* __restrict__ Yb, int O, int K, int N) {
  __shared__ __align__(16) ushort_t sA[128 * 64];
  __shared__ __align__(16) ushort_t sB[128 * 64];
  int t = threadIdx.x;
  int l = t & 63, w = t >> 6;
  int o0 = blockIdx.y * 128, n0 = blockIdx.x * 128, bz = blockIdx.z;
  const ushort_t* Ag = Wb + (size_t)o0 * K;
  const ushort_t* Bg = Xt + ((size_t)bz * N + n0) * K;
  int srow = w * 32 + (l >> 3);  // global row within tile for this lane's 16B
  int scol = (l & 7) * 8;        // k-offset (elements)
  int lrow = l & 15, lg = l >> 4;
  int wm = (w >> 1) * 64, wn = (w & 1) * 64;
  f32x4 acc[4][4];
#pragma unroll
  for (int fi = 0; fi < 4; ++fi)
#pragma unroll
    for (int fj = 0; fj < 4; ++fj) acc[fi][fj] = f32x4{0.f, 0.f, 0.f, 0.f};
  for (int k0 = 0; k0 < K; k0 += 64) {
#pragma unroll
    for (int i = 0; i < 4; ++i) {
      gload16(Ag + (size_t)(srow + i * 8) * K + k0 + scol, sA + (w * 32 + i * 8) * 64);
      gload16(Bg + (size_t)(srow + i * 8) * K + k0 + scol, sB + (w * 32 + i * 8) * 64);
    }
    __syncthreads();
#pragma unroll
    for (int kk = 0; kk < 2; ++kk) {
      short8 af[4], bfr[4];
#pragma unroll
      for (int fi = 0; fi < 4; ++fi)
        af[fi] = *(const short8*)(sA + (wm + fi * 16 + lrow) * 64 + kk * 32 + lg * 8);
#pragma unroll
      for (int fj = 0; fj < 4; ++fj)
        bfr[fj] = *(const short8*)(sB + (wn + fj * 16 + lrow) * 64 + kk * 32 + lg * 8);
#pragma unroll
      for (int fi = 0; fi < 4; ++fi)
#pragma unroll
        for (int fj = 0; fj < 4; ++fj)
          acc[fi][fj] = __builtin_amdgcn_mfma_f32_16x16x32_bf16(af[fi], bfr[fj], acc[fi][fj], 0, 0, 0);
    }
    __syncthreads();
  }
#pragma unroll
  for (int fi = 0; fi < 4; ++fi) {
    int ob = wm + fi * 16 + lg * 4;
    float bi[4];
#pragma unroll
    for (int r = 0; r < 4; ++r) bi[r] = bias[o0 + ob + r];
#pragma unroll
    for (int fj = 0; fj < 4; ++fj) {
      int n = n0 + wn + fj * 16 + lrow;
      float v[4];
#pragma unroll
      for (int r = 0; r < 4; ++r) {
        v[r] = acc[fi][fj][r] + bi[r];
        if (RES) v[r] += resid[((size_t)bz * O + ob + r + o0) * N + n];
        if (F32) Y[((size_t)bz * O + ob + r + o0) * N + n] = v[r];
        if (B16N) Yb[((size_t)bz * O + ob + r + o0) * N + n] = f2bf(v[r]);
      }
      if (B16T) {
        uint2 u;
        u.x = pack2(v[0], v[1]);
        u.y = pack2(v[2], v[3]);
        *(uint2*)&Yb[((size_t)bz * N + n) * O + o0 + ob] = u;
      }
    }
  }
}

// ---- offset branch
__global__ __launch_bounds__(256) void offset_kernel(
    const ushort_t* __restrict__ qt, const float* __restrict__ odw,
    const float* __restrict__ odb, const float* __restrict__ olw,
    const float* __restrict__ olb, const float* __restrict__ opw,
    float* __restrict__ pos) {
  __shared__ float s[CG_][256];
  int bg = blockIdx.x;
  int b = bg / G_, g = bg % G_;
  int t = threadIdx.x;
  int hk = t >> 4, wk = t & 15;
  const ushort_t* qb = qt + (size_t)b * HW_ * C_ + g * CG_;
  for (int c = 0; c < CG_; c++) {
    float acc = odb[c];
    const float* wc = odw + c * 9;
#pragma unroll
    for (int ky = 0; ky < 3; ky++) {
      int ih = 2 * hk + ky - 1;
      if ((unsigned)ih >= 32u) continue;
#pragma unroll
      for (int kx = 0; kx < 3; kx++) {
        int iw = 2 * wk + kx - 1;
        if ((unsigned)iw >= 32u) continue;
        acc = fmaf(wc[ky * 3 + kx], bf2f(qb[(size_t)(ih * 32 + iw) * C_ + c]), acc);
      }
    }
    s[c][t] = acc;
  }
  __syncthreads();
  float mu = 0.f;
  for (int c = 0; c < CG_; c++) mu += s[c][t];
  mu *= (1.f / CG_);
  float var = 0.f;
  for (int c = 0; c < CG_; c++) {
    float d = s[c][t] - mu;
    var = fmaf(d, d, var);
  }
  var *= (1.f / CG_);
  float rs = rsqrtf(var + 1e-5f);
  float dy = 0.f, dx = 0.f;
  for (int c = 0; c < CG_; c++) {
    float tv = (s[c][t] - mu) * rs * olw[c] + olb[c];
    float ge = gelu_exact(tv);
    dy = fmaf(opw[c], ge, dy);
    dx = fmaf(opw[CG_ + c], ge, dx);
  }
  float ry = (hk + 0.5f) * (2.f / 15.f) - 1.f;
  float rx = (wk + 0.5f) * (2.f / 15.f) - 1.f;
  pos[(size_t)bg * 512 + t * 2 + 0] = fminf(fmaxf(dy + ry, -1.f), 1.f);
  pos[(size_t)bg * 512 + t * 2 + 1] = fminf(fmaxf(dx + rx, -1.f), 1.f);
}

// ---- deformable sampling (fp32 y1 -> fp32 xs [bg][cg][n])
__global__ __launch_bounds__(256) void sample_xs(
    const float* __restrict__ y1, const float* __restrict__ pos,
    float* __restrict__ xs) {
  int idx = blockIdx.x * 256 + threadIdx.x;
  int n = idx & 255;
  int cg = (idx >> 8) & 63;
  int bg = idx >> 14;
  int b = bg / G_, g = bg % G_;
  float py = pos[(size_t)bg * 512 + n * 2];
  float px = pos[(size_t)bg * 512 + n * 2 + 1];
  float gx = (px + 1.f) * 15.5f, gy = (py + 1.f) * 15.5f;
  float fx = floorf(gx), fy = floorf(gy);
  float wx = gx - fx, wy = gy - fy;
  int x0 = min(max((int)fx, 0), 31), y0 = min(max((int)fy, 0), 31);
  int x1 = min(x0 + 1, 31), y1i = min(y0 + 1, 31);
  const float* img = y1 + ((size_t)b * C_ + g * CG_ + cg) * HW_;
  float v00 = img[y0 * 32 + x0], v01 = img[y0 * 32 + x1];
  float v10 = img[y1i * 32 + x0], v11 = img[y1i * 32 + x1];
  xs[((size_t)bg * CG_ + cg) * NS_ + n] =
      v00 * (1.f - wx) * (1.f - wy) + v01 * wx * (1.f - wy) +
      v10 * (1.f - wx) * wy + v11 * wx * wy;
}

// ---- xs fp32 [bg][cg][n] -> xst bf16 [b][n][C]
__global__ __launch_bounds__(256) void t_xs(const float* __restrict__ xs,
                                            ushort_t* __restrict__ xst) {
  __shared__ __align__(16) float tile[32][33];
  int n0 = blockIdx.x * 32, c0 = blockIdx.y * 32, bg = blockIdx.z;
  int b = bg / G_, g = bg % G_;
  int t = threadIdx.x;
#pragma unroll
  for (int it = 0; it < 4; ++it) {
    int idx = it * 256 + t;
    int cl = idx >> 5, nl = idx & 31;
    tile[cl][nl] = xs[((size_t)bg * CG_ + c0 + cl) * NS_ + n0 + nl];
  }
  __syncthreads();
  int nl = t >> 3, cg = t & 7;
  unsigned p0 = pack2(tile[cg * 4 + 0][nl], tile[cg * 4 + 1][nl]);
  unsigned p1 = pack2(tile[cg * 4 + 2][nl], tile[cg * 4 + 3][nl]);
  unsigned* dst = (unsigned*)(xst + ((size_t)b * NS_ + n0 + nl) * C_ + g * CG_ + c0 + cg * 4);
  dst[0] = p0;
  dst[1] = p1;
}

// ---- MFMA flash attention.
// grid (HW/128, HEADS, B), 256 thr = 4 waves, wave handles 32 q-rows.
// qt [b][m][C] bf16, kt [b][n][C] bf16, vbn [b][C][n] bf16 -> aot [b][m][C] bf16
__global__ __launch_bounds__(256) void attn_kernel(
    const ushort_t* __restrict__ qt, const ushort_t* __restrict__ kt,
    const ushort_t* __restrict__ vbn, const float* __restrict__ pos,
    const float* __restrict__ rpe, ushort_t* __restrict__ aot) {
  __shared__ __align__(16) ushort_t sK[256 * 40];   // [key][c 0..31], stride 40
  __shared__ __align__(16) ushort_t sV[32 * 264];   // [c][key 0..255], stride 264
  __shared__ __align__(16) ushort_t sRP[64 * 64];   // padded rpe, zeros at edges
  __shared__ __align__(16) unsigned sIB[256];       // iy*64+ix per key
  __shared__ __align__(16) float sW2[512];          // (wy,wx) per key
  __shared__ __align__(16) ushort_t sP[4 * 32 * 40];  // per-wave P bounce
  int qb = blockIdx.x, h = blockIdx.y, b = blockIdx.z;
  int t = threadIdx.x;
  int l = t & 63, wv = t >> 6;
  int lrow = l & 15, lg = l >> 4;
  int bg = b * G_ + (h >> 1);
  // --- stage K (thread t = key row t)
  {
    const uint4* kr = (const uint4*)(kt + ((size_t)b * NS_ + t) * C_ + h * HC_);
#pragma unroll
    for (int i = 0; i < 4; ++i) *(uint4*)&sK[t * 40 + i * 8] = kr[i];
  }
  // --- stage V (thread t: channel t&31, key chunk t>>5)
  {
    int c = t & 31, ch = t >> 5;
    const uint4* vr = (const uint4*)(vbn + ((size_t)b * C_ + h * HC_ + c) * NS_ + ch * 32);
#pragma unroll
    for (int i = 0; i < 4; ++i) *(uint4*)&sV[c * 264 + ch * 32 + i * 8] = vr[i];
  }
  // --- stage rpe (zero-padded 64x64)
  {
    const float* rph = rpe + (size_t)h * 3969;
    for (int i = t; i < 4096; i += 256) {
      int y = i >> 6, x = i & 63;
      sRP[i] = (y < 63 && x < 63) ? f2bf(rph[y * 63 + x]) : (ushort_t)0;
    }
  }
  // --- per-key bilinear params
  {
    float py = pos[(size_t)bg * 512 + 2 * t];
    float px = pos[(size_t)bg * 512 + 2 * t + 1];
    float cy = 15.5f - 15.5f * py;
    float cx = 15.5f - 15.5f * px;
    float fy = floorf(cy), fx = floorf(cx);
    sIB[t] = (unsigned)((int)fy * 64 + (int)fx);
    sW2[2 * t] = cy - fy;
    sW2[2 * t + 1] = cx - fx;
  }
  __syncthreads();

  int m0 = qb * 128 + wv * 32;
  short8 qf[2];
  int aq[2];
#pragma unroll
  for (int f = 0; f < 2; ++f) {
    int m = m0 + f * 16 + lrow;
    qf[f] = *(const short8*)(qt + ((size_t)b * HW_ + m) * C_ + h * HC_ + lg * 8);
    aq[f] = (m >> 5) * 64 + (m & 31);
  }
  f32x4 oc[2][2];
#pragma unroll
  for (int f = 0; f < 2; ++f)
#pragma unroll
    for (int ct = 0; ct < 2; ++ct) oc[f][ct] = f32x4{0.f, 0.f, 0.f, 0.f};
  float mrun[2] = {-1e30f, -1e30f}, lrun[2] = {0.f, 0.f};
  ushort_t* sPw = sP + wv * 32 * 40;

  for (int c = 0; c < 8; ++c) {
    // QK^T (swapped: A = K-tile -> rows=keys, cols=q)
    f32x4 s[2][2];  // [f][T]
#pragma unroll
    for (int T = 0; T < 2; ++T) {
      int k16 = c * 2 + T;
      short8 kf = *(const short8*)(sK + (k16 * 16 + lrow) * 40 + lg * 8);
#pragma unroll
      for (int f = 0; f < 2; ++f)
        s[f][T] = __builtin_amdgcn_mfma_f32_16x16x32_bf16(kf, qf[f], f32x4{0.f, 0.f, 0.f, 0.f}, 0, 0, 0);
    }
    // per-key params for this lane's 8 keys
    u32x4 ibT[2];
    f32x4 wA[2], wB[2];
#pragma unroll
    for (int T = 0; T < 2; ++T) {
      int kbase = c * 32 + T * 16 + lg * 4;
      ibT[T] = *(const u32x4*)&sIB[kbase];
      wA[T] = *(const f32x4*)&sW2[2 * kbase];
      wB[T] = *(const f32x4*)&sW2[2 * kbase + 4];
    }
    // bias + scale
#pragma unroll
    for (int f = 0; f < 2; ++f)
#pragma unroll
      for (int T = 0; T < 2; ++T)
#pragma unroll
        for (int r = 0; r < 4; ++r) {
          int a = aq[f] + (int)ibT[T][r];
          float wy = (r < 2) ? wA[T][(r & 1) * 2] : wB[T][(r & 1) * 2];
          float wx = (r < 2) ? wA[T][(r & 1) * 2 + 1] : wB[T][(r & 1) * 2 + 1];
          float b00 = bf2f(sRP[a]), b01 = bf2f(sRP[a + 1]);
          float b10 = bf2f(sRP[a + 64]), b11 = bf2f(sRP[a + 65]);
          float r0 = b00 + wx * (b01 - b00);
          float r1 = b10 + wx * (b11 - b10);
          s[f][T][r] = s[f][T][r] * SCALE_ + r0 + wy * (r1 - r0);
        }
    // online softmax + P pack
#pragma unroll
    for (int f = 0; f < 2; ++f) {
      float mx = s[f][0][0];
#pragma unroll
      for (int T = 0; T < 2; ++T)
#pragma unroll
        for (int r = 0; r < 4; ++r) mx = fmaxf(mx, s[f][T][r]);
      mx = fmaxf(mx, __shfl_xor(mx, 16));
      mx = fmaxf(mx, __shfl_xor(mx, 32));
      float newm = fmaxf(mrun[f], mx);
      float fac = __expf(mrun[f] - newm);
      mrun[f] = newm;
      float ps = 0.f;
#pragma unroll
      for (int T = 0; T < 2; ++T)
#pragma unroll
        for (int r = 0; r < 4; ++r) {
          float p = __expf(s[f][T][r] - newm);
          s[f][T][r] = p;
          ps += p;
        }
      ps += __shfl_xor(ps, 16);
      ps += __shfl_xor(ps, 32);
      lrun[f] = lrun[f] * fac + ps;
#pragma unroll
      for (int ct = 0; ct < 2; ++ct)
#pragma unroll
        for (int r = 0; r < 4; ++r) oc[f][ct][r] *= fac;
#pragma unroll
      for (int T = 0; T < 2; ++T) {
        uint2 u;
        u.x = pack2(s[f][T][0], s[f][T][1]);
        u.y = pack2(s[f][T][2], s[f][T][3]);
        *(uint2*)&sPw[(f * 16 + lrow) * 40 + T * 16 + lg * 4] = u;
      }
    }
    // PV
    short8 pa[2];
#pragma unroll
    for (int f = 0; f < 2; ++f)
      pa[f] = *(const short8*)&sPw[(f * 16 + lrow) * 40 + lg * 8];
#pragma unroll
    for (int ct = 0; ct < 2; ++ct) {
      short8 vf = *(const short8*)(sV + (ct * 16 + lrow) * 264 + c * 32 + lg * 8);
#pragma unroll
      for (int f = 0; f < 2; ++f)
        oc[f][ct] = __builtin_amdgcn_mfma_f32_16x16x32_bf16(pa[f], vf, oc[f][ct], 0, 0, 0);
    }
  }
  // epilogue: normalize (stats live at q=l&15; output rows are q=lg*4+r)
#pragma unroll
  for (int f = 0; f < 2; ++f) {
    float inv = 1.f / lrun[f];
    float invq[4];
#pragma unroll
    for (int r = 0; r < 4; ++r) invq[r] = __shfl(inv, lg * 4 + r);
#pragma unroll
    for (int ct = 0; ct < 2; ++ct)
#pragma unroll
      for (int r = 0; r < 4; ++r) {
        int m = m0 + f * 16 + lg * 4 + r;
        aot[((size_t)b * HW_ + m) * C_ + h * HC_ + ct * 16 + lrow] =
            f2bf(oc[f][ct][r] * invq[r]);
      }
  }
}

}  // namespace

extern "C" void kernel_launch(void* const* d_in, const int* in_sizes, int n_in,
                              void* d_out, int out_size, void* d_ws,
                              size_t ws_size, hipStream_t stream) {
  const float* x_in = (const float*)d_in[0];
  const float* lpu_w = (const float*)d_in[1];
  const float* lpu_b = (const float*)d_in[2];
  const float* wq = (const float*)d_in[3];
  const float* bq = (const float*)d_in[4];
  const float* wk = (const float*)d_in[5];
  const float* bk = (const float*)d_in[6];
  const float* wv = (const float*)d_in[7];
  const float* bv = (const float*)d_in[8];
  const float* wo = (const float*)d_in[9];
  const float* bo = (const float*)d_in[10];
  const float* odw = (const float*)d_in[11];
  const float* odb = (const float*)d_in[12];
  const float* olw = (const float*)d_in[13];
  const float* olb = (const float*)d_in[14];
  const float* opw = (const float*)d_in[15];
  const float* rpe = (const float*)d_in[16];
  const float* w1 = (const float*)d_in[17];
  const float* b1 = (const float*)d_in[18];
  const float* mdw = (const float*)d_in[19];
  const float* mdb = (const float*)d_in[20];
  const float* w2 = (const float*)d_in[21];
  const float* b2 = (const float*)d_in[22];
  float* out = (float*)d_out;

  constexpr size_t XSZ = (size_t)B_ * C_ * HW_;
  constexpr size_t SSZ = (size_t)B_ * C_ * NS_;
  constexpr size_t HSZ = (size_t)B_ * D2_ * HW_;

  char* base = (char*)d_ws;
  auto alloc = [&](size_t bytes) {
    char* p = base;
    base += (bytes + 255) & ~(size_t)255;
    return p;
  };
  float* bufX = (float*)alloc(XSZ * 4);
  float* y1 = (float*)alloc(XSZ * 4);
  float* x2 = (float*)alloc(XSZ * 4);
  float* xs = (float*)alloc(SSZ * 4);
  float* pos = (float*)alloc(48 * 512 * 4);
  ushort_t* qt = (ushort_t*)alloc(XSZ * 2);
  ushort_t* tb1 = (ushort_t*)alloc(XSZ * 2);
  ushort_t* aot = (ushort_t*)alloc(XSZ * 2);
  ushort_t* xst = (ushort_t*)alloc(SSZ * 2);
  ushort_t* ktb = (ushort_t*)alloc(SSZ * 2);
  ushort_t* vbn = (ushort_t*)alloc(SSZ * 2);
  ushort_t* h1b = (ushort_t*)alloc(HSZ * 2);
  ushort_t* h3t = (ushort_t*)alloc(HSZ * 2);
  ushort_t* wb = (ushort_t*)alloc((size_t)3538944 * 2);

  ushort_t* wqb = wb;
  ushort_t* wkb = wb + 294912;
  ushort_t* wvb = wb + 589824;
  ushort_t* wob = wb + 884736;
  ushort_t* w1b = wb + 1179648;
  ushort_t* w2b = wb + 2359296;

  wcvt_kernel<<<3538944 / 256, 256, 0, stream>>>(wq, wk, wv, wo, w1, w2, wb);

  for (int d = 0; d < 2; ++d) {
    const float* xin = (d == 0) ? x_in : bufX;
    float* xnext = (d == 1) ? out : bufX;
    const ushort_t* wqd = wqb + (size_t)d * 147456;
    const ushort_t* wkd = wkb + (size_t)d * 147456;
    const ushort_t* wvd = wvb + (size_t)d * 147456;
    const ushort_t* wod = wob + (size_t)d * 147456;
    const ushort_t* w1d = w1b + (size_t)d * 589824;
    const ushort_t* w2d = w2b + (size_t)d * 589824;

    dwconv_lpu<<<dim3(32, 12, 8), 256, 0, stream>>>(xin, lpu_w + d * C_ * 9,
                                                    lpu_b + d * C_, y1, tb1);
    // q = Wq @ y1 (bf16T)
    gemm128<false, false, true, false><<<dim3(8, 3, 8), 256, 0, stream>>>(
        wqd, tb1, bq + d * C_, nullptr, nullptr, qt, C_, C_, HW_);
    offset_kernel<<<48, 256, 0, stream>>>(qt, odw + d * CG_ * 9, odb + d * CG_,
                                          olw + d * CG_, olb + d * CG_,
                                          opw + d * 2 * CG_, pos);
    sample_xs<<<(int)(SSZ / 256), 256, 0, stream>>>(y1, pos, xs);
    t_xs<<<dim3(8, 2, 48), 256, 0, stream>>>(xs, xst);
    // k (bf16T [b][n][C]), v (bf16N [b][C][n])
    gemm_bf16<false, false, true, false><<<dim3(4, 6, 8), 256, 0, stream>>>(
        wkd, xst, bk + d * C_, nullptr, nullptr, ktb, C_, C_, NS_);
    gemm_bf16<false, true, false, false><<<dim3(4, 6, 8), 256, 0, stream>>>(
        wvd, xst, bv + d * C_, nullptr, nullptr, vbn, C_, C_, NS_);
    attn_kernel<<<dim3(8, 12, 8), 256, 0, stream>>>(
        qt, ktb, vbn, pos, rpe + (size_t)d * HEADS_ * 3969, aot);
    // x2 = y1 + Wo @ ao (fp32) ; x2t bf16T
    gemm128<true, false, true, true><<<dim3(8, 3, 8), 256, 0, stream>>>(
        wod, aot, bo + d * C_, y1, x2, tb1, C_, C_, HW_);
    // mlp1: h1b bf16N [b][D2][hw]
    gemm128<false, true, false, false><<<dim3(8, 12, 8), 256, 0, stream>>>(
        w1d, tb1, b1 + d * D2_, nullptr, nullptr, h1b, D2_, C_, HW_);
    dwgelu_t<<<dim3(32, 48, 8), 256, 0, stream>>>(h1b, mdw + d * D2_ * 9,
                                                  mdb + d * D2_, h3t);
    // mlp2: xnext = x2 + W2 @ h3 (fp32)
    gemm128<true, false, false, true><<<dim3(8, 3, 8), 256, 0, stream>>>(
        w2d, h3t, b2 + d * C_, x2, xnext, nullptr, C_, D2_, HW_);
  }
}

// Round 5
// 527.543 us; speedup vs baseline: 3.3044x; 1.6746x over previous
//
#include <hip/hip_runtime.h>
#include <hip/hip_bf16.h>
#include <math.h>

namespace {

constexpr int B_ = 8, C_ = 384, H_ = 32, W_ = 32, HW_ = 1024;
constexpr int HEADS_ = 12, G_ = 6, HC_ = 32, CG_ = 64, NS_ = 256, D2_ = 1536;
constexpr float SCALE_ = 0.17677669529663687f;  // 32^-0.5

using short8 = __attribute__((ext_vector_type(8))) short;
using f32x4 = __attribute__((ext_vector_type(4))) float;
using u32x4 = __attribute__((ext_vector_type(4))) unsigned;
typedef unsigned short ushort_t;

__device__ __forceinline__ float gelu_exact(float x) {
  return 0.5f * x * (1.f + erff(x * 0.70710678118654752f));
}
__device__ __forceinline__ ushort_t f2bf(float f) {
  unsigned u = __float_as_uint(f);
  u = (u + 0x7FFFu + ((u >> 16) & 1u)) >> 16;
  return (ushort_t)u;
}
__device__ __forceinline__ float bf2f(ushort_t s) {
  return __uint_as_float(((unsigned)s) << 16);
}
__device__ __forceinline__ float bflo(unsigned u) { return __uint_as_float(u << 16); }
__device__ __forceinline__ float bfhi(unsigned u) { return __uint_as_float(u & 0xFFFF0000u); }
__device__ __forceinline__ unsigned pack2(float a, float b) {
  return (unsigned)f2bf(a) | ((unsigned)f2bf(b) << 16);
}

typedef __attribute__((address_space(1))) const unsigned int gq_u32;
typedef __attribute__((address_space(3))) unsigned int lq_u32;
__device__ __forceinline__ void gload16(const ushort_t* g, ushort_t* l) {
  __builtin_amdgcn_global_load_lds((gq_u32*)g, (lq_u32*)l, 16, 0, 0);
}

// ---- weight fp32 -> bf16
__global__ __launch_bounds__(256) void wcvt_kernel(
    const float* __restrict__ s0, const float* __restrict__ s1,
    const float* __restrict__ s2, const float* __restrict__ s3,
    const float* __restrict__ s4, const float* __restrict__ s5,
    ushort_t* __restrict__ dst) {
  long idx = (long)blockIdx.x * 256 + threadIdx.x;
  long off = idx;
  const float* s;
  if (off < 294912) s = s0;
  else if ((off -= 294912) < 294912) s = s1;
  else if ((off -= 294912) < 294912) s = s2;
  else if ((off -= 294912) < 294912) s = s3;
  else if ((off -= 294912) < 1179648) s = s4;
  else { off -= 1179648; s = s5; }
  dst[idx] = f2bf(s[off]);
}

// ---- LPU: y = x + dwconv3x3(x), vectorized 4 px/thread.
// writes y fp32 [b][c][hw] and yt bf16 [b][hw][c]
__global__ __launch_bounds__(256) void dwconv_lpu(
    const float* __restrict__ x, const float* __restrict__ w,
    const float* __restrict__ bias, float* __restrict__ y,
    ushort_t* __restrict__ yt) {
  __shared__ __align__(16) float tile[32][33];
  int hp = blockIdx.x, c0 = blockIdx.y * 32, b = blockIdx.z;
  int t = threadIdx.x;
  int cl = t >> 3, g4 = t & 7;
  int c = c0 + cl;
  const float* img = x + ((size_t)b * C_ + c) * HW_;
  const float* wc = w + c * 9;
  float o0 = bias[c], o1 = o0, o2 = o0, o3 = o0;
#pragma unroll
  for (int ky = 0; ky < 3; ++ky) {
    int ih = hp + ky - 1;
    if ((unsigned)ih >= 32u) continue;
    const float* row = img + ih * 32 + g4 * 4;
    float4 m = *(const float4*)row;
    float v0 = (g4 > 0) ? row[-1] : 0.f;
    float v5 = (g4 < 7) ? row[4] : 0.f;
    float k0 = wc[ky * 3], k1 = wc[ky * 3 + 1], k2 = wc[ky * 3 + 2];
    o0 = fmaf(k0, v0, fmaf(k1, m.x, fmaf(k2, m.y, o0)));
    o1 = fmaf(k0, m.x, fmaf(k1, m.y, fmaf(k2, m.z, o1)));
    o2 = fmaf(k0, m.y, fmaf(k1, m.z, fmaf(k2, m.w, o2)));
    o3 = fmaf(k0, m.z, fmaf(k1, m.w, fmaf(k2, v5, o3)));
  }
  float4 ctr = *(const float4*)(img + hp * 32 + g4 * 4);
  o0 += ctr.x; o1 += ctr.y; o2 += ctr.z; o3 += ctr.w;
  *(float4*)(y + ((size_t)b * C_ + c) * HW_ + hp * 32 + g4 * 4) =
      make_float4(o0, o1, o2, o3);
  tile[cl][g4 * 4 + 0] = o0;
  tile[cl][g4 * 4 + 1] = o1;
  tile[cl][g4 * 4 + 2] = o2;
  tile[cl][g4 * 4 + 3] = o3;
  __syncthreads();
  int wl = t >> 3, cg = t & 7;
  unsigned p0 = pack2(tile[cg * 4 + 0][wl], tile[cg * 4 + 1][wl]);
  unsigned p1 = pack2(tile[cg * 4 + 2][wl], tile[cg * 4 + 3][wl]);
  unsigned* dst = (unsigned*)(yt + ((size_t)b * HW_ + hp * 32 + wl) * C_ + c0 + cg * 4);
  dst[0] = p0;
  dst[1] = p1;
}

// ---- MLP dw: h3t[b][hw][c] = bf16(gelu(h + dwconv(h)+bias)); 8 px/thread, 2 rows/block
__global__ __launch_bounds__(256) void dwgelu_t(
    const ushort_t* __restrict__ hin, const float* __restrict__ w,
    const float* __restrict__ bias, ushort_t* __restrict__ ht) {
  __shared__ __align__(16) float tile[2][32][33];
  int hp0 = blockIdx.x * 2, c0 = blockIdx.y * 32, b = blockIdx.z;
  int t = threadIdx.x;
  int cl = t >> 3, rw = (t >> 2) & 1, g8 = t & 3;
  int hp = hp0 + rw;
  int c = c0 + cl;
  const ushort_t* img = hin + ((size_t)b * D2_ + c) * HW_;
  const float* wc = w + c * 9;
  float o[8];
  float bi = bias[c];
#pragma unroll
  for (int j = 0; j < 8; ++j) o[j] = bi;
#pragma unroll
  for (int ky = 0; ky < 3; ++ky) {
    int ih = hp + ky - 1;
    if ((unsigned)ih >= 32u) continue;
    const ushort_t* row = img + ih * 32 + g8 * 8;
    uint4 u = *(const uint4*)row;
    float vv[10];
    vv[0] = (g8 > 0) ? bf2f(row[-1]) : 0.f;
    vv[1] = bflo(u.x); vv[2] = bfhi(u.x); vv[3] = bflo(u.y); vv[4] = bfhi(u.y);
    vv[5] = bflo(u.z); vv[6] = bfhi(u.z); vv[7] = bflo(u.w); vv[8] = bfhi(u.w);
    vv[9] = (g8 < 3) ? bf2f(row[8]) : 0.f;
    float k0 = wc[ky * 3], k1 = wc[ky * 3 + 1], k2 = wc[ky * 3 + 2];
#pragma unroll
    for (int j = 0; j < 8; ++j)
      o[j] = fmaf(k0, vv[j], fmaf(k1, vv[j + 1], fmaf(k2, vv[j + 2], o[j])));
  }
  {
    uint4 u = *(const uint4*)(img + hp * 32 + g8 * 8);
    float cv[8] = {bflo(u.x), bfhi(u.x), bflo(u.y), bfhi(u.y),
                   bflo(u.z), bfhi(u.z), bflo(u.w), bfhi(u.w)};
#pragma unroll
    for (int j = 0; j < 8; ++j) {
      o[j] += cv[j];
      tile[rw][cl][g8 * 8 + j] = gelu_exact(o[j]);
    }
  }
  __syncthreads();
  int wl = t >> 3, cg = t & 7;
#pragma unroll
  for (int rr = 0; rr < 2; ++rr) {
    unsigned p0 = pack2(tile[rr][cg * 4 + 0][wl], tile[rr][cg * 4 + 1][wl]);
    unsigned p1 = pack2(tile[rr][cg * 4 + 2][wl], tile[rr][cg * 4 + 3][wl]);
    unsigned* dst = (unsigned*)(ht + ((size_t)b * HW_ + (hp0 + rr) * 32 + wl) * D2_ + c0 + cg * 4);
    dst[0] = p0;
    dst[1] = p1;
  }
}

// ---- 64-tile bf16 MFMA GEMM (K/V projections, N=256)
template <bool F32, bool B16N, bool B16T, bool RES>
__global__ __launch_bounds__(256) void gemm_bf16(
    const ushort_t* __restrict__ Wb, const ushort_t* __restrict__ Xt,
    const float* __restrict__ bias, const float* __restrict__ resid,
    float* __restrict__ Y, ushort_t* __restrict__ Yb, int O, int K, int N) {
  struct __align__(16) SMem {
    union {
      struct { char a[8192]; char b[8192]; } st;
      float shuf[64 * 68];
    };
  };
  __shared__ SMem sm;
  int t = threadIdx.x;
  int lane = t & 63, wave = t >> 6;
  int wm = (wave >> 1) * 32, wn = (wave & 1) * 32;
  int bz = blockIdx.z;
  int o0 = blockIdx.y * 64, n0 = blockIdx.x * 64;
  const ushort_t* Ag = Wb + (size_t)o0 * K;
  const ushort_t* Bg = Xt + ((size_t)bz * N + n0) * K;
  int sr = t >> 3, sc = t & 7;
  int swz = ((sc ^ (sr & 7)) << 4);
  f32x4 acc[2][2];
#pragma unroll
  for (int fi = 0; fi < 2; ++fi)
#pragma unroll
    for (int fj = 0; fj < 2; ++fj) acc[fi][fj] = f32x4{0.f, 0.f, 0.f, 0.f};
  int lrow = lane & 15, lk = lane >> 4;
  for (int k0 = 0; k0 < K; k0 += 64) {
    short8 a0 = *(const short8*)(Ag + (size_t)sr * K + k0 + sc * 8);
    short8 a1 = *(const short8*)(Ag + (size_t)(sr + 32) * K + k0 + sc * 8);
    short8 b0 = *(const short8*)(Bg + (size_t)sr * K + k0 + sc * 8);
    short8 b1 = *(const short8*)(Bg + (size_t)(sr + 32) * K + k0 + sc * 8);
    __syncthreads();
    *(short8*)(sm.st.a + sr * 128 + swz) = a0;
    *(short8*)(sm.st.a + (sr + 32) * 128 + swz) = a1;
    *(short8*)(sm.st.b + sr * 128 + swz) = b0;
    *(short8*)(sm.st.b + (sr + 32) * 128 + swz) = b1;
    __syncthreads();
#pragma unroll
    for (int kk = 0; kk < 2; ++kk) {
      short8 af[2], bfr[2];
#pragma unroll
      for (int fi = 0; fi < 2; ++fi) {
        int row = wm + fi * 16 + lrow;
        af[fi] = *(const short8*)(sm.st.a + row * 128 + (((kk * 4 + lk) ^ (row & 7)) << 4));
      }
#pragma unroll
      for (int fj = 0; fj < 2; ++fj) {
        int row = wn + fj * 16 + lrow;
        bfr[fj] = *(const short8*)(sm.st.b + row * 128 + (((kk * 4 + lk) ^ (row & 7)) << 4));
      }
#pragma unroll
      for (int fi = 0; fi < 2; ++fi)
#pragma unroll
        for (int fj = 0; fj < 2; ++fj)
          acc[fi][fj] = __builtin_amdgcn_mfma_f32_16x16x32_bf16(af[fi], bfr[fj], acc[fi][fj], 0, 0, 0);
    }
  }
  if (B16N || B16T) __syncthreads();
#pragma unroll
  for (int fi = 0; fi < 2; ++fi) {
#pragma unroll
    for (int r = 0; r < 4; ++r) {
      int ol = wm + fi * 16 + lk * 4 + r;
      float bi = bias[o0 + ol];
#pragma unroll
      for (int fj = 0; fj < 2; ++fj) {
        int nl = wn + fj * 16 + lrow;
        float v = acc[fi][fj][r] + bi;
        if (RES) v += resid[((size_t)bz * O + (o0 + ol)) * N + n0 + nl];
        if (F32) Y[((size_t)bz * O + (o0 + ol)) * N + n0 + nl] = v;
        if (B16N || B16T) sm.shuf[ol * 68 + nl] = v;
      }
    }
  }
  if (B16N || B16T) {
    __syncthreads();
    if (B16T) {
      int nl = t >> 2, og = (t & 3) * 16;
      unsigned pk[8];
#pragma unroll
      for (int i = 0; i < 8; ++i)
        pk[i] = pack2(sm.shuf[(og + 2 * i) * 68 + nl], sm.shuf[(og + 2 * i + 1) * 68 + nl]);
      unsigned* dst = (unsigned*)(Yb + ((size_t)bz * N + (n0 + nl)) * O + o0 + og);
      *(uint4*)(dst) = make_uint4(pk[0], pk[1], pk[2], pk[3]);
      *(uint4*)(dst + 4) = make_uint4(pk[4], pk[5], pk[6], pk[7]);
    } else {
      int ol = t >> 2, ng = (t & 3) * 16;
      unsigned pk[8];
#pragma unroll
      for (int i = 0; i < 8; ++i)
        pk[i] = pack2(sm.shuf[ol * 68 + ng + 2 * i], sm.shuf[ol * 68 + ng + 2 * i + 1]);
      unsigned* dst = (unsigned*)(Yb + ((size_t)bz * O + (o0 + ol)) * N + n0 + ng);
      *(uint4*)(dst) = make_uint4(pk[0], pk[1], pk[2], pk[3]);
      *(uint4*)(dst + 4) = make_uint4(pk[4], pk[5], pk[6], pk[7]);
    }
  }
}

// ---- m97-style 128x128x64 bf16 GEMM with global_load_lds staging.
template <bool F32, bool B16N, bool B16T, bool RES>
__global__ __launch_bounds__(256) void gemm128(
    const ushort_t* __restrict__ Wb, const ushort_t* __restrict__ Xt,
    const float* __restrict__ bias, const float* __restrict__ resid,
    float* __restrict__ Y, ushort_t* __restrict__ Yb, int O, int K, int N) {
  __shared__ __align__(16) ushort_t sA[128 * 64];
  __shared__ __align__(16) ushort_t sB[128 * 64];
  int t = threadIdx.x;
  int l = t & 63, w = t >> 6;
  int o0 = blockIdx.y * 128, n0 = blockIdx.x * 128, bz = blockIdx.z;
  const ushort_t* Ag = Wb + (size_t)o0 * K;
  const ushort_t* Bg = Xt + ((size_t)bz * N + n0) * K;
  int srow = w * 32 + (l >> 3);
  int scol = (l & 7) * 8;
  int lrow = l & 15, lg = l >> 4;
  int wm = (w >> 1) * 64, wn = (w & 1) * 64;
  f32x4 acc[4][4];
#pragma unroll
  for (int fi = 0; fi < 4; ++fi)
#pragma unroll
    for (int fj = 0; fj < 4; ++fj) acc[fi][fj] = f32x4{0.f, 0.f, 0.f, 0.f};
  for (int k0 = 0; k0 < K; k0 += 64) {
#pragma unroll
    for (int i = 0; i < 4; ++i) {
      gload16(Ag + (size_t)(srow + i * 8) * K + k0 + scol, sA + (w * 32 + i * 8) * 64);
      gload16(Bg + (size_t)(srow + i * 8) * K + k0 + scol, sB + (w * 32 + i * 8) * 64);
    }
    __syncthreads();
#pragma unroll
    for (int kk = 0; kk < 2; ++kk) {
      short8 af[4], bfr[4];
#pragma unroll
      for (int fi = 0; fi < 4; ++fi)
        af[fi] = *(const short8*)(sA + (wm + fi * 16 + lrow) * 64 + kk * 32 + lg * 8);
#pragma unroll
      for (int fj = 0; fj < 4; ++fj)
        bfr[fj] = *(const short8*)(sB + (wn + fj * 16 + lrow) * 64 + kk * 32 + lg * 8);
#pragma unroll
      for (int fi = 0; fi < 4; ++fi)
#pragma unroll
        for (int fj = 0; fj < 4; ++fj)
          acc[fi][fj] = __builtin_amdgcn_mfma_f32_16x16x32_bf16(af[fi], bfr[fj], acc[fi][fj], 0, 0, 0);
    }
    __syncthreads();
  }
#pragma unroll
  for (int fi = 0; fi < 4; ++fi) {
    int ob = wm + fi * 16 + lg * 4;
    float bi[4];
#pragma unroll
    for (int r = 0; r < 4; ++r) bi[r] = bias[o0 + ob + r];
#pragma unroll
    for (int fj = 0; fj < 4; ++fj) {
      int n = n0 + wn + fj * 16 + lrow;
      float v[4];
#pragma unroll
      for (int r = 0; r < 4; ++r) {
        v[r] = acc[fi][fj][r] + bi[r];
        if (RES) v[r] += resid[((size_t)bz * O + ob + r + o0) * N + n];
        if (F32) Y[((size_t)bz * O + ob + r + o0) * N + n] = v[r];
        if (B16N) Yb[((size_t)bz * O + ob + r + o0) * N + n] = f2bf(v[r]);
      }
      if (B16T) {
        uint2 u;
        u.x = pack2(v[0], v[1]);
        u.y = pack2(v[2], v[3]);
        *(uint2*)&Yb[((size_t)bz * N + n) * O + o0 + ob] = u;
      }
    }
  }
}

// ---- offset branch, all-register, vectorized q loads
__global__ __launch_bounds__(256) void offset_kernel(
    const ushort_t* __restrict__ qt, const float* __restrict__ odw,
    const float* __restrict__ odb, const float* __restrict__ olw,
    const float* __restrict__ olb, const float* __restrict__ opw,
    float* __restrict__ pos) {
  int bg = blockIdx.x;
  int b = bg / G_, g = bg % G_;
  int t = threadIdx.x;
  int hk = t >> 4, wk = t & 15;
  const ushort_t* qb = qt + (size_t)b * HW_ * C_ + g * CG_;
  float sv[CG_];
#pragma unroll
  for (int cc = 0; cc < 8; ++cc) {
    float a8[8];
#pragma unroll
    for (int j = 0; j < 8; ++j) a8[j] = odb[cc * 8 + j];
#pragma unroll
    for (int ky = 0; ky < 3; ++ky) {
      int ih = 2 * hk + ky - 1;
      if ((unsigned)ih >= 32u) continue;
#pragma unroll
      for (int kx = 0; kx < 3; ++kx) {
        int iw = 2 * wk + kx - 1;
        if ((unsigned)iw >= 32u) continue;
        uint4 u = *(const uint4*)(qb + (size_t)(ih * 32 + iw) * C_ + cc * 8);
        float vv[8] = {bflo(u.x), bfhi(u.x), bflo(u.y), bfhi(u.y),
                       bflo(u.z), bfhi(u.z), bflo(u.w), bfhi(u.w)};
#pragma unroll
        for (int j = 0; j < 8; ++j)
          a8[j] = fmaf(odw[(cc * 8 + j) * 9 + ky * 3 + kx], vv[j], a8[j]);
      }
    }
#pragma unroll
    for (int j = 0; j < 8; ++j) sv[cc * 8 + j] = a8[j];
  }
  float mu = 0.f;
#pragma unroll
  for (int c = 0; c < CG_; c++) mu += sv[c];
  mu *= (1.f / CG_);
  float var = 0.f;
#pragma unroll
  for (int c = 0; c < CG_; c++) {
    float d = sv[c] - mu;
    var = fmaf(d, d, var);
  }
  var *= (1.f / CG_);
  float rs = rsqrtf(var + 1e-5f);
  float dy = 0.f, dx = 0.f;
#pragma unroll
  for (int c = 0; c < CG_; c++) {
    float tv = (sv[c] - mu) * rs * olw[c] + olb[c];
    float ge = gelu_exact(tv);
    dy = fmaf(opw[c], ge, dy);
    dx = fmaf(opw[CG_ + c], ge, dx);
  }
  float ry = (hk + 0.5f) * (2.f / 15.f) - 1.f;
  float rx = (wk + 0.5f) * (2.f / 15.f) - 1.f;
  pos[(size_t)bg * 512 + t * 2 + 0] = fminf(fmaxf(dy + ry, -1.f), 1.f);
  pos[(size_t)bg * 512 + t * 2 + 1] = fminf(fmaxf(dx + rx, -1.f), 1.f);
}

// ---- fused deformable sampling + transpose: y1 fp32 -> xst bf16 [b][n][C]
__global__ __launch_bounds__(256) void sample_xst(
    const float* __restrict__ y1, const float* __restrict__ pos,
    ushort_t* __restrict__ xst) {
  int bg = blockIdx.y;
  int b = bg / G_, g = bg % G_;
  int t = threadIdx.x;
  int cg = t & 63, nl = t >> 6;
  int n = blockIdx.x * 4 + nl;
  float py = pos[(size_t)bg * 512 + 2 * n];
  float px = pos[(size_t)bg * 512 + 2 * n + 1];
  float gx = (px + 1.f) * 15.5f, gy = (py + 1.f) * 15.5f;
  float fx = floorf(gx), fy = floorf(gy);
  float wx = gx - fx, wy = gy - fy;
  int x0 = min(max((int)fx, 0), 31), y0 = min(max((int)fy, 0), 31);
  int x1 = min(x0 + 1, 31), y1i = min(y0 + 1, 31);
  const float* img = y1 + ((size_t)b * C_ + g * CG_ + cg) * HW_;
  float v00 = img[y0 * 32 + x0], v01 = img[y0 * 32 + x1];
  float v10 = img[y1i * 32 + x0], v11 = img[y1i * 32 + x1];
  float v = v00 * (1.f - wx) * (1.f - wy) + v01 * wx * (1.f - wy) +
            v10 * (1.f - wx) * wy + v11 * wx * wy;
  xst[((size_t)b * NS_ + n) * C_ + g * CG_ + cg] = f2bf(v);
}

// ---- MFMA flash attention, quad-packed rpe gather, no K/V staging.
// 1D grid 768 blocks (XCD-swizzled), 256 thr = 4 waves, wave = 32 q-rows.
__global__ __launch_bounds__(256) void attn_kernel(
    const ushort_t* __restrict__ qt, const ushort_t* __restrict__ kt,
    const ushort_t* __restrict__ vbn, const float* __restrict__ pos,
    const float* __restrict__ rpe, ushort_t* __restrict__ aot) {
  __shared__ __align__(16) uint2 sRPQ[4096];         // 32 KB: 2x2 bf16 taps per (y,x)
  __shared__ __align__(16) ushort_t sP[4][32 * 40];  // 10 KB P bounce
  __shared__ unsigned sIB[256];
  __shared__ float sW2[512];
  int bid = blockIdx.x;
  int swzb = (bid & 7) * 96 + (bid >> 3);  // 768 = 8 XCD * 96
  int qb = swzb & 7;
  int grp = swzb >> 3;
  int h = grp % HEADS_;
  int b = grp / HEADS_;
  int t = threadIdx.x;
  int l = t & 63, wv = t >> 6;
  int lrow = l & 15, lg = l >> 4;
  int bg = b * G_ + (h >> 1);
  {
    const float* rph = rpe + (size_t)h * 3969;
    for (int i = t; i < 4096; i += 256) {
      int y = i >> 6, x = i & 63;
      float v00 = 0.f, v01 = 0.f, v10 = 0.f, v11 = 0.f;
      if (y < 63) {
        if (x < 63) v00 = rph[y * 63 + x];
        if (x < 62) v01 = rph[y * 63 + x + 1];
      }
      if (y < 62) {
        if (x < 63) v10 = rph[(y + 1) * 63 + x];
        if (x < 62) v11 = rph[(y + 1) * 63 + x + 1];
      }
      sRPQ[i] = make_uint2(pack2(v00, v01), pack2(v10, v11));
    }
  }
  {
    float py = pos[(size_t)bg * 512 + 2 * t];
    float px = pos[(size_t)bg * 512 + 2 * t + 1];
    float cy = 15.5f - 15.5f * py;
    float cx = 15.5f - 15.5f * px;
    float fy = floorf(cy), fx = floorf(cx);
    sIB[t] = (unsigned)((int)fy * 64 + (int)fx);
    sW2[2 * t] = cy - fy;
    sW2[2 * t + 1] = cx - fx;
  }
  __syncthreads();

  int m0 = qb * 128 + wv * 32;
  short8 qf[2];
  int aq[2];
#pragma unroll
  for (int f = 0; f < 2; ++f) {
    int m = m0 + f * 16 + lrow;
    qf[f] = *(const short8*)(qt + ((size_t)b * HW_ + m) * C_ + h * HC_ + lg * 8);
    aq[f] = (m >> 5) * 64 + (m & 31);
  }
  const ushort_t* kbase = kt + (size_t)b * NS_ * C_ + h * HC_;
  const ushort_t* vbase = vbn + ((size_t)b * C_ + h * HC_) * NS_;
  f32x4 oc[2][2];
#pragma unroll
  for (int f = 0; f < 2; ++f)
#pragma unroll
    for (int ct = 0; ct < 2; ++ct) oc[f][ct] = f32x4{0.f, 0.f, 0.f, 0.f};
  float mrun[2] = {-1e30f, -1e30f}, lrun[2] = {0.f, 0.f};
  ushort_t* sPw = sP[wv];

  for (int c = 0; c < 8; ++c) {
    f32x4 s[2][2];
    __builtin_amdgcn_s_setprio(1);
#pragma unroll
    for (int T = 0; T < 2; ++T) {
      short8 kf = *(const short8*)(kbase + (size_t)((c * 2 + T) * 16 + lrow) * C_ + lg * 8);
#pragma unroll
      for (int f = 0; f < 2; ++f)
        s[f][T] = __builtin_amdgcn_mfma_f32_16x16x32_bf16(kf, qf[f], f32x4{0.f, 0.f, 0.f, 0.f}, 0, 0, 0);
    }
    __builtin_amdgcn_s_setprio(0);
    u32x4 ibT[2];
    f32x4 wA[2], wB[2];
#pragma unroll
    for (int T = 0; T < 2; ++T) {
      int kbase2 = c * 32 + T * 16 + lg * 4;
      ibT[T] = *(const u32x4*)&sIB[kbase2];
      wA[T] = *(const f32x4*)&sW2[2 * kbase2];
      wB[T] = *(const f32x4*)&sW2[2 * kbase2 + 4];
    }
#pragma unroll
    for (int f = 0; f < 2; ++f)
#pragma unroll
      for (int T = 0; T < 2; ++T)
#pragma unroll
        for (int r = 0; r < 4; ++r) {
          int a = aq[f] + (int)ibT[T][r];
          float wy = (r < 2) ? wA[T][(r & 1) * 2] : wB[T][(r & 1) * 2];
          float wx = (r < 2) ? wA[T][(r & 1) * 2 + 1] : wB[T][(r & 1) * 2 + 1];
          uint2 qd = sRPQ[a];
          float b00 = bflo(qd.x), b01 = bfhi(qd.x);
          float b10 = bflo(qd.y), b11 = bfhi(qd.y);
          float r0 = b00 + wx * (b01 - b00);
          float r1 = b10 + wx * (b11 - b10);
          s[f][T][r] = s[f][T][r] * SCALE_ + r0 + wy * (r1 - r0);
        }
#pragma unroll
    for (int f = 0; f < 2; ++f) {
      float mx = s[f][0][0];
#pragma unroll
      for (int T = 0; T < 2; ++T)
#pragma unroll
        for (int r = 0; r < 4; ++r) mx = fmaxf(mx, s[f][T][r]);
      mx = fmaxf(mx, __shfl_xor(mx, 16));
      mx = fmaxf(mx, __shfl_xor(mx, 32));
      float newm = fmaxf(mrun[f], mx);
      float fac = __expf(mrun[f] - newm);
      mrun[f] = newm;
      float ps = 0.f;
#pragma unroll
      for (int T = 0; T < 2; ++T)
#pragma unroll
        for (int r = 0; r < 4; ++r) {
          float p = __expf(s[f][T][r] - newm);
          s[f][T][r] = p;
          ps += p;
        }
      ps += __shfl_xor(ps, 16);
      ps += __shfl_xor(ps, 32);
      lrun[f] = lrun[f] * fac + ps;
#pragma unroll
      for (int ct = 0; ct < 2; ++ct)
#pragma unroll
        for (int r = 0; r < 4; ++r) oc[f][ct][r] *= fac;
#pragma unroll
      for (int T = 0; T < 2; ++T) {
        uint2 u;
        u.x = pack2(s[f][T][0], s[f][T][1]);
        u.y = pack2(s[f][T][2], s[f][T][3]);
        *(uint2*)&sPw[(f * 16 + lrow) * 40 + T * 16 + lg * 4] = u;
      }
    }
    short8 pa[2];
#pragma unroll
    for (int f = 0; f < 2; ++f)
      pa[f] = *(const short8*)&sPw[(f * 16 + lrow) * 40 + lg * 8];
    __builtin_amdgcn_s_setprio(1);
#pragma unroll
    for (int ct = 0; ct < 2; ++ct) {
      short8 vf = *(const short8*)(vbase + (size_t)(ct * 16 + lrow) * NS_ + c * 32 + lg * 8);
#pragma unroll
      for (int f = 0; f < 2; ++f)
        oc[f][ct] = __builtin_amdgcn_mfma_f32_16x16x32_bf16(pa[f], vf, oc[f][ct], 0, 0, 0);
    }
    __builtin_amdgcn_s_setprio(0);
  }
#pragma unroll
  for (int f = 0; f < 2; ++f) {
    float inv = 1.f / lrun[f];
    float invq[4];
#pragma unroll
    for (int r = 0; r < 4; ++r) invq[r] = __shfl(inv, lg * 4 + r);
#pragma unroll
    for (int ct = 0; ct < 2; ++ct)
#pragma unroll
      for (int r = 0; r < 4; ++r) {
        int m = m0 + f * 16 + lg * 4 + r;
        aot[((size_t)b * HW_ + m) * C_ + h * HC_ + ct * 16 + lrow] =
            f2bf(oc[f][ct][r] * invq[r]);
      }
  }
}

}  // namespace

extern "C" void kernel_launch(void* const* d_in, const int* in_sizes, int n_in,
                              void* d_out, int out_size, void* d_ws,
                              size_t ws_size, hipStream_t stream) {
  const float* x_in = (const float*)d_in[0];
  const float* lpu_w = (const float*)d_in[1];
  const float* lpu_b = (const float*)d_in[2];
  const float* wq = (const float*)d_in[3];
  const float* bq = (const float*)d_in[4];
  const float* wk = (const float*)d_in[5];
  const float* bk = (const float*)d_in[6];
  const float* wv = (const float*)d_in[7];
  const float* bv = (const float*)d_in[8];
  const float* wo = (const float*)d_in[9];
  const float* bo = (const float*)d_in[10];
  const float* odw = (const float*)d_in[11];
  const float* odb = (const float*)d_in[12];
  const float* olw = (const float*)d_in[13];
  const float* olb = (const float*)d_in[14];
  const float* opw = (const float*)d_in[15];
  const float* rpe = (const float*)d_in[16];
  const float* w1 = (const float*)d_in[17];
  const float* b1 = (const float*)d_in[18];
  const float* mdw = (const float*)d_in[19];
  const float* mdb = (const float*)d_in[20];
  const float* w2 = (const float*)d_in[21];
  const float* b2 = (const float*)d_in[22];
  float* out = (float*)d_out;

  constexpr size_t XSZ = (size_t)B_ * C_ * HW_;
  constexpr size_t SSZ = (size_t)B_ * C_ * NS_;
  constexpr size_t HSZ = (size_t)B_ * D2_ * HW_;

  char* base = (char*)d_ws;
  auto alloc = [&](size_t bytes) {
    char* p = base;
    base += (bytes + 255) & ~(size_t)255;
    return p;
  };
  float* bufX = (float*)alloc(XSZ * 4);
  float* y1 = (float*)alloc(XSZ * 4);
  float* x2 = (float*)alloc(XSZ * 4);
  float* pos = (float*)alloc(48 * 512 * 4);
  ushort_t* qt = (ushort_t*)alloc(XSZ * 2);
  ushort_t* tb1 = (ushort_t*)alloc(XSZ * 2);
  ushort_t* aot = (ushort_t*)alloc(XSZ * 2);
  ushort_t* xst = (ushort_t*)alloc(SSZ * 2);
  ushort_t* ktb = (ushort_t*)alloc(SSZ * 2);
  ushort_t* vbn = (ushort_t*)alloc(SSZ * 2);
  ushort_t* h1b = (ushort_t*)alloc(HSZ * 2);
  ushort_t* h3t = (ushort_t*)alloc(HSZ * 2);
  ushort_t* wb = (ushort_t*)alloc((size_t)3538944 * 2);

  ushort_t* wqb = wb;
  ushort_t* wkb = wb + 294912;
  ushort_t* wvb = wb + 589824;
  ushort_t* wob = wb + 884736;
  ushort_t* w1b = wb + 1179648;
  ushort_t* w2b = wb + 2359296;

  wcvt_kernel<<<3538944 / 256, 256, 0, stream>>>(wq, wk, wv, wo, w1, w2, wb);

  for (int d = 0; d < 2; ++d) {
    const float* xin = (d == 0) ? x_in : bufX;
    float* xnext = (d == 1) ? out : bufX;
    const ushort_t* wqd = wqb + (size_t)d * 147456;
    const ushort_t* wkd = wkb + (size_t)d * 147456;
    const ushort_t* wvd = wvb + (size_t)d * 147456;
    const ushort_t* wod = wob + (size_t)d * 147456;
    const ushort_t* w1d = w1b + (size_t)d * 589824;
    const ushort_t* w2d = w2b + (size_t)d * 589824;

    dwconv_lpu<<<dim3(32, 12, 8), 256, 0, stream>>>(xin, lpu_w + d * C_ * 9,
                                                    lpu_b + d * C_, y1, tb1);
    gemm128<false, false, true, false><<<dim3(8, 3, 8), 256, 0, stream>>>(
        wqd, tb1, bq + d * C_, nullptr, nullptr, qt, C_, C_, HW_);
    offset_kernel<<<48, 256, 0, stream>>>(qt, odw + d * CG_ * 9, odb + d * CG_,
                                          olw + d * CG_, olb + d * CG_,
                                          opw + d * 2 * CG_, pos);
    sample_xst<<<dim3(64, 48), 256, 0, stream>>>(y1, pos, xst);
    gemm_bf16<false, false, true, false><<<dim3(4, 6, 8), 256, 0, stream>>>(
        wkd, xst, bk + d * C_, nullptr, nullptr, ktb, C_, C_, NS_);
    gemm_bf16<false, true, false, false><<<dim3(4, 6, 8), 256, 0, stream>>>(
        wvd, xst, bv + d * C_, nullptr, nullptr, vbn, C_, C_, NS_);
    attn_kernel<<<768, 256, 0, stream>>>(
        qt, ktb, vbn, pos, rpe + (size_t)d * HEADS_ * 3969, aot);
    gemm128<true, false, true, true><<<dim3(8, 3, 8), 256, 0, stream>>>(
        wod, aot, bo + d * C_, y1, x2, tb1, C_, C_, HW_);
    gemm128<false, true, false, false><<<dim3(8, 12, 8), 256, 0, stream>>>(
        w1d, tb1, b1 + d * D2_, nullptr, nullptr, h1b, D2_, C_, HW_);
    dwgelu_t<<<dim3(16, 48, 8), 256, 0, stream>>>(h1b, mdw + d * D2_ * 9,
                                                  mdb + d * D2_, h3t);
    gemm128<true, false, false, true><<<dim3(8, 3, 8), 256, 0, stream>>>(
        w2d, h3t, b2 + d * C_, x2, xnext, nullptr, C_, D2_, HW_);
  }
}

// Round 6
// 506.827 us; speedup vs baseline: 3.4395x; 1.0409x over previous
//
#include <hip/hip_runtime.h>
#include <hip/hip_bf16.h>
#include <math.h>

namespace {

constexpr int B_ = 8, C_ = 384, H_ = 32, W_ = 32, HW_ = 1024;
constexpr int HEADS_ = 12, G_ = 6, HC_ = 32, CG_ = 64, NS_ = 256, D2_ = 1536;
constexpr float SCALE_ = 0.17677669529663687f;  // 32^-0.5

using short8 = __attribute__((ext_vector_type(8))) short;
using f32x4 = __attribute__((ext_vector_type(4))) float;
using u32x4 = __attribute__((ext_vector_type(4))) unsigned;
typedef unsigned short ushort_t;

__device__ __forceinline__ float gelu_exact(float x) {
  return 0.5f * x * (1.f + erff(x * 0.70710678118654752f));
}
__device__ __forceinline__ ushort_t f2bf(float f) {
  unsigned u = __float_as_uint(f);
  u = (u + 0x7FFFu + ((u >> 16) & 1u)) >> 16;
  return (ushort_t)u;
}
__device__ __forceinline__ float bf2f(ushort_t s) {
  return __uint_as_float(((unsigned)s) << 16);
}
__device__ __forceinline__ float bflo(unsigned u) { return __uint_as_float(u << 16); }
__device__ __forceinline__ float bfhi(unsigned u) { return __uint_as_float(u & 0xFFFF0000u); }
__device__ __forceinline__ unsigned pack2(float a, float b) {
  return (unsigned)f2bf(a) | ((unsigned)f2bf(b) << 16);
}

typedef __attribute__((address_space(1))) const unsigned int gq_u32;
typedef __attribute__((address_space(3))) unsigned int lq_u32;
__device__ __forceinline__ void gload16(const ushort_t* g, ushort_t* l) {
  __builtin_amdgcn_global_load_lds((gq_u32*)g, (lq_u32*)l, 16, 0, 0);
}

// ---- weight fp32 -> bf16
__global__ __launch_bounds__(256) void wcvt_kernel(
    const float* __restrict__ s0, const float* __restrict__ s1,
    const float* __restrict__ s2, const float* __restrict__ s3,
    const float* __restrict__ s4, const float* __restrict__ s5,
    ushort_t* __restrict__ dst) {
  long idx = (long)blockIdx.x * 256 + threadIdx.x;
  long off = idx;
  const float* s;
  if (off < 294912) s = s0;
  else if ((off -= 294912) < 294912) s = s1;
  else if ((off -= 294912) < 294912) s = s2;
  else if ((off -= 294912) < 294912) s = s3;
  else if ((off -= 294912) < 1179648) s = s4;
  else { off -= 1179648; s = s5; }
  dst[idx] = f2bf(s[off]);
}

// ---- rpe quad-pack precompute: rpq[d][h][y*64+x] = {(v00,v01),(v10,v11)} bf16
__global__ __launch_bounds__(256) void rpe_pack(const float* __restrict__ rpe,
                                               uint2* __restrict__ rpq) {
  int h = blockIdx.x, d = blockIdx.y;
  const float* rph = rpe + ((size_t)d * HEADS_ + h) * 3969;
  uint2* dst = rpq + ((size_t)d * HEADS_ + h) * 4096;
  for (int i = threadIdx.x; i < 4096; i += 256) {
    int y = i >> 6, x = i & 63;
    float v00 = 0.f, v01 = 0.f, v10 = 0.f, v11 = 0.f;
    if (y < 63) {
      if (x < 63) v00 = rph[y * 63 + x];
      if (x < 62) v01 = rph[y * 63 + x + 1];
    }
    if (y < 62) {
      if (x < 63) v10 = rph[(y + 1) * 63 + x];
      if (x < 62) v11 = rph[(y + 1) * 63 + x + 1];
    }
    dst[i] = make_uint2(pack2(v00, v01), pack2(v10, v11));
  }
}

// ---- LPU: y = x + dwconv3x3(x), vectorized 4 px/thread.
__global__ __launch_bounds__(256) void dwconv_lpu(
    const float* __restrict__ x, const float* __restrict__ w,
    const float* __restrict__ bias, float* __restrict__ y,
    ushort_t* __restrict__ yt) {
  __shared__ __align__(16) float tile[32][33];
  int hp = blockIdx.x, c0 = blockIdx.y * 32, b = blockIdx.z;
  int t = threadIdx.x;
  int cl = t >> 3, g4 = t & 7;
  int c = c0 + cl;
  const float* img = x + ((size_t)b * C_ + c) * HW_;
  const float* wc = w + c * 9;
  float o0 = bias[c], o1 = o0, o2 = o0, o3 = o0;
#pragma unroll
  for (int ky = 0; ky < 3; ++ky) {
    int ih = hp + ky - 1;
    if ((unsigned)ih >= 32u) continue;
    const float* row = img + ih * 32 + g4 * 4;
    float4 m = *(const float4*)row;
    float v0 = (g4 > 0) ? row[-1] : 0.f;
    float v5 = (g4 < 7) ? row[4] : 0.f;
    float k0 = wc[ky * 3], k1 = wc[ky * 3 + 1], k2 = wc[ky * 3 + 2];
    o0 = fmaf(k0, v0, fmaf(k1, m.x, fmaf(k2, m.y, o0)));
    o1 = fmaf(k0, m.x, fmaf(k1, m.y, fmaf(k2, m.z, o1)));
    o2 = fmaf(k0, m.y, fmaf(k1, m.z, fmaf(k2, m.w, o2)));
    o3 = fmaf(k0, m.z, fmaf(k1, m.w, fmaf(k2, v5, o3)));
  }
  float4 ctr = *(const float4*)(img + hp * 32 + g4 * 4);
  o0 += ctr.x; o1 += ctr.y; o2 += ctr.z; o3 += ctr.w;
  *(float4*)(y + ((size_t)b * C_ + c) * HW_ + hp * 32 + g4 * 4) =
      make_float4(o0, o1, o2, o3);
  tile[cl][g4 * 4 + 0] = o0;
  tile[cl][g4 * 4 + 1] = o1;
  tile[cl][g4 * 4 + 2] = o2;
  tile[cl][g4 * 4 + 3] = o3;
  __syncthreads();
  int wl = t >> 3, cg = t & 7;
  unsigned p0 = pack2(tile[cg * 4 + 0][wl], tile[cg * 4 + 1][wl]);
  unsigned p1 = pack2(tile[cg * 4 + 2][wl], tile[cg * 4 + 3][wl]);
  unsigned* dst = (unsigned*)(yt + ((size_t)b * HW_ + hp * 32 + wl) * C_ + c0 + cg * 4);
  dst[0] = p0;
  dst[1] = p1;
}

// ---- MLP dw: h3t[b][hw][c] = bf16(gelu(h + dwconv(h)+bias)); 8 px/thread
__global__ __launch_bounds__(256) void dwgelu_t(
    const ushort_t* __restrict__ hin, const float* __restrict__ w,
    const float* __restrict__ bias, ushort_t* __restrict__ ht) {
  __shared__ __align__(16) float tile[2][32][33];
  int hp0 = blockIdx.x * 2, c0 = blockIdx.y * 32, b = blockIdx.z;
  int t = threadIdx.x;
  int cl = t >> 3, rw = (t >> 2) & 1, g8 = t & 3;
  int hp = hp0 + rw;
  int c = c0 + cl;
  const ushort_t* img = hin + ((size_t)b * D2_ + c) * HW_;
  const float* wc = w + c * 9;
  float o[8];
  float bi = bias[c];
#pragma unroll
  for (int j = 0; j < 8; ++j) o[j] = bi;
#pragma unroll
  for (int ky = 0; ky < 3; ++ky) {
    int ih = hp + ky - 1;
    if ((unsigned)ih >= 32u) continue;
    const ushort_t* row = img + ih * 32 + g8 * 8;
    uint4 u = *(const uint4*)row;
    float vv[10];
    vv[0] = (g8 > 0) ? bf2f(row[-1]) : 0.f;
    vv[1] = bflo(u.x); vv[2] = bfhi(u.x); vv[3] = bflo(u.y); vv[4] = bfhi(u.y);
    vv[5] = bflo(u.z); vv[6] = bfhi(u.z); vv[7] = bflo(u.w); vv[8] = bfhi(u.w);
    vv[9] = (g8 < 3) ? bf2f(row[8]) : 0.f;
    float k0 = wc[ky * 3], k1 = wc[ky * 3 + 1], k2 = wc[ky * 3 + 2];
#pragma unroll
    for (int j = 0; j < 8; ++j)
      o[j] = fmaf(k0, vv[j], fmaf(k1, vv[j + 1], fmaf(k2, vv[j + 2], o[j])));
  }
  {
    uint4 u = *(const uint4*)(img + hp * 32 + g8 * 8);
    float cv[8] = {bflo(u.x), bfhi(u.x), bflo(u.y), bfhi(u.y),
                   bflo(u.z), bfhi(u.z), bflo(u.w), bfhi(u.w)};
#pragma unroll
    for (int j = 0; j < 8; ++j) {
      o[j] += cv[j];
      tile[rw][cl][g8 * 8 + j] = gelu_exact(o[j]);
    }
  }
  __syncthreads();
  int wl = t >> 3, cg = t & 7;
#pragma unroll
  for (int rr = 0; rr < 2; ++rr) {
    unsigned p0 = pack2(tile[rr][cg * 4 + 0][wl], tile[rr][cg * 4 + 1][wl]);
    unsigned p1 = pack2(tile[rr][cg * 4 + 2][wl], tile[rr][cg * 4 + 3][wl]);
    unsigned* dst = (unsigned*)(ht + ((size_t)b * HW_ + (hp0 + rr) * 32 + wl) * D2_ + c0 + cg * 4);
    dst[0] = p0;
    dst[1] = p1;
  }
}

// ---- fused K+V projection, 64-tile, reg-prefetch pipeline.
// by<6: K-half -> ktb bf16T [b][n][C]; by>=6: V-half -> vbn bf16N [b][C][n]
__global__ __launch_bounds__(256) void gemm_kv(
    const ushort_t* __restrict__ Wk, const ushort_t* __restrict__ Wv,
    const ushort_t* __restrict__ Xt, const float* __restrict__ bk,
    const float* __restrict__ bv, ushort_t* __restrict__ ktb,
    ushort_t* __restrict__ vbn) {
  constexpr int K = C_, N = NS_, O = C_;
  struct __align__(16) SMem {
    union {
      struct { char a[8192]; char b[8192]; } st;
      float shuf[64 * 68];
    };
  };
  __shared__ SMem sm;
  int t = threadIdx.x;
  int lane = t & 63, wave = t >> 6;
  int wm = (wave >> 1) * 32, wn = (wave & 1) * 32;
  int bz = blockIdx.z;
  bool isK = blockIdx.y < 6;
  int o0 = (isK ? blockIdx.y : blockIdx.y - 6) * 64;
  int n0 = blockIdx.x * 64;
  const ushort_t* Wb = isK ? Wk : Wv;
  const float* bias = isK ? bk : bv;
  const ushort_t* Ag = Wb + (size_t)o0 * K;
  const ushort_t* Bg = Xt + ((size_t)bz * N + n0) * K;
  int sr = t >> 3, sc = t & 7;
  int swz = ((sc ^ (sr & 7)) << 4);
  f32x4 acc[2][2];
#pragma unroll
  for (int fi = 0; fi < 2; ++fi)
#pragma unroll
    for (int fj = 0; fj < 2; ++fj) acc[fi][fj] = f32x4{0.f, 0.f, 0.f, 0.f};
  int lrow = lane & 15, lk = lane >> 4;
  short8 a0 = *(const short8*)(Ag + (size_t)sr * K + sc * 8);
  short8 a1 = *(const short8*)(Ag + (size_t)(sr + 32) * K + sc * 8);
  short8 b0 = *(const short8*)(Bg + (size_t)sr * K + sc * 8);
  short8 b1 = *(const short8*)(Bg + (size_t)(sr + 32) * K + sc * 8);
  constexpr int NSTEP = K / 64;
#pragma unroll
  for (int s = 0; s < NSTEP; ++s) {
    if (s) __syncthreads();
    *(short8*)(sm.st.a + sr * 128 + swz) = a0;
    *(short8*)(sm.st.a + (sr + 32) * 128 + swz) = a1;
    *(short8*)(sm.st.b + sr * 128 + swz) = b0;
    *(short8*)(sm.st.b + (sr + 32) * 128 + swz) = b1;
    __syncthreads();
    if (s + 1 < NSTEP) {
      int k0 = (s + 1) * 64;
      a0 = *(const short8*)(Ag + (size_t)sr * K + k0 + sc * 8);
      a1 = *(const short8*)(Ag + (size_t)(sr + 32) * K + k0 + sc * 8);
      b0 = *(const short8*)(Bg + (size_t)sr * K + k0 + sc * 8);
      b1 = *(const short8*)(Bg + (size_t)(sr + 32) * K + k0 + sc * 8);
    }
#pragma unroll
    for (int kk = 0; kk < 2; ++kk) {
      short8 af[2], bfr[2];
#pragma unroll
      for (int fi = 0; fi < 2; ++fi) {
        int row = wm + fi * 16 + lrow;
        af[fi] = *(const short8*)(sm.st.a + row * 128 + (((kk * 4 + lk) ^ (row & 7)) << 4));
      }
#pragma unroll
      for (int fj = 0; fj < 2; ++fj) {
        int row = wn + fj * 16 + lrow;
        bfr[fj] = *(const short8*)(sm.st.b + row * 128 + (((kk * 4 + lk) ^ (row & 7)) << 4));
      }
#pragma unroll
      for (int fi = 0; fi < 2; ++fi)
#pragma unroll
        for (int fj = 0; fj < 2; ++fj)
          acc[fi][fj] = __builtin_amdgcn_mfma_f32_16x16x32_bf16(af[fi], bfr[fj], acc[fi][fj], 0, 0, 0);
    }
  }
  __syncthreads();
#pragma unroll
  for (int fi = 0; fi < 2; ++fi) {
#pragma unroll
    for (int r = 0; r < 4; ++r) {
      int ol = wm + fi * 16 + lk * 4 + r;
      float bi = bias[o0 + ol];
#pragma unroll
      for (int fj = 0; fj < 2; ++fj) {
        int nl = wn + fj * 16 + lrow;
        sm.shuf[ol * 68 + nl] = acc[fi][fj][r] + bi;
      }
    }
  }
  __syncthreads();
  if (isK) {
    int nl = t >> 2, og = (t & 3) * 16;
    unsigned pk[8];
#pragma unroll
    for (int i = 0; i < 8; ++i)
      pk[i] = pack2(sm.shuf[(og + 2 * i) * 68 + nl], sm.shuf[(og + 2 * i + 1) * 68 + nl]);
    unsigned* dst = (unsigned*)(ktb + ((size_t)bz * N + (n0 + nl)) * O + o0 + og);
    *(uint4*)(dst) = make_uint4(pk[0], pk[1], pk[2], pk[3]);
    *(uint4*)(dst + 4) = make_uint4(pk[4], pk[5], pk[6], pk[7]);
  } else {
    int ol = t >> 2, ng = (t & 3) * 16;
    unsigned pk[8];
#pragma unroll
    for (int i = 0; i < 8; ++i)
      pk[i] = pack2(sm.shuf[ol * 68 + ng + 2 * i], sm.shuf[ol * 68 + ng + 2 * i + 1]);
    unsigned* dst = (unsigned*)(vbn + ((size_t)bz * O + (o0 + ol)) * N + n0 + ng);
    *(uint4*)(dst) = make_uint4(pk[0], pk[1], pk[2], pk[3]);
    *(uint4*)(dst + 4) = make_uint4(pk[4], pk[5], pk[6], pk[7]);
  }
}

// ---- 128x128x64 bf16 GEMM, double-buffered global_load_lds (2-phase pipeline)
template <bool F32, bool B16N, bool B16T, bool RES>
__global__ __launch_bounds__(256) void gemm128(
    const ushort_t* __restrict__ Wb, const ushort_t* __restrict__ Xt,
    const float* __restrict__ bias, const float* __restrict__ resid,
    float* __restrict__ Y, ushort_t* __restrict__ Yb, int O, int K, int N) {
  __shared__ __align__(16) ushort_t sA[2][128 * 64];
  __shared__ __align__(16) ushort_t sB[2][128 * 64];
  int t = threadIdx.x;
  int l = t & 63, w = t >> 6;
  int o0 = blockIdx.y * 128, n0 = blockIdx.x * 128, bz = blockIdx.z;
  const ushort_t* Ag = Wb + (size_t)o0 * K;
  const ushort_t* Bg = Xt + ((size_t)bz * N + n0) * K;
  int srow = w * 32 + (l >> 3);
  int scol = (l & 7) * 8;
  int lrow = l & 15, lg = l >> 4;
  int wm = (w >> 1) * 64, wn = (w & 1) * 64;
  f32x4 acc[4][4];
#pragma unroll
  for (int fi = 0; fi < 4; ++fi)
#pragma unroll
    for (int fj = 0; fj < 4; ++fj) acc[fi][fj] = f32x4{0.f, 0.f, 0.f, 0.f};
  auto stage = [&](int buf, int k0) {
#pragma unroll
    for (int i = 0; i < 4; ++i) {
      gload16(Ag + (size_t)(srow + i * 8) * K + k0 + scol, sA[buf] + (w * 32 + i * 8) * 64);
      gload16(Bg + (size_t)(srow + i * 8) * K + k0 + scol, sB[buf] + (w * 32 + i * 8) * 64);
    }
  };
  stage(0, 0);
  __syncthreads();
  int nstep = K >> 6;
  for (int s = 0; s < nstep; ++s) {
    int cur = s & 1;
    if (s + 1 < nstep) stage(cur ^ 1, (s + 1) * 64);
#pragma unroll
    for (int kk = 0; kk < 2; ++kk) {
      short8 af[4], bfr[4];
#pragma unroll
      for (int fi = 0; fi < 4; ++fi)
        af[fi] = *(const short8*)(sA[cur] + (wm + fi * 16 + lrow) * 64 + kk * 32 + lg * 8);
#pragma unroll
      for (int fj = 0; fj < 4; ++fj)
        bfr[fj] = *(const short8*)(sB[cur] + (wn + fj * 16 + lrow) * 64 + kk * 32 + lg * 8);
#pragma unroll
      for (int fi = 0; fi < 4; ++fi)
#pragma unroll
        for (int fj = 0; fj < 4; ++fj)
          acc[fi][fj] = __builtin_amdgcn_mfma_f32_16x16x32_bf16(af[fi], bfr[fj], acc[fi][fj], 0, 0, 0);
    }
    __syncthreads();
  }
#pragma unroll
  for (int fi = 0; fi < 4; ++fi) {
    int ob = wm + fi * 16 + lg * 4;
    float bi[4];
#pragma unroll
    for (int r = 0; r < 4; ++r) bi[r] = bias[o0 + ob + r];
#pragma unroll
    for (int fj = 0; fj < 4; ++fj) {
      int n = n0 + wn + fj * 16 + lrow;
      float v[4];
#pragma unroll
      for (int r = 0; r < 4; ++r) {
        v[r] = acc[fi][fj][r] + bi[r];
        if (RES) v[r] += resid[((size_t)bz * O + ob + r + o0) * N + n];
        if (F32) Y[((size_t)bz * O + ob + r + o0) * N + n] = v[r];
        if (B16N) Yb[((size_t)bz * O + ob + r + o0) * N + n] = f2bf(v[r]);
      }
      if (B16T) {
        uint2 u;
        u.x = pack2(v[0], v[1]);
        u.y = pack2(v[2], v[3]);
        *(uint2*)&Yb[((size_t)bz * N + n) * O + o0 + ob] = u;
      }
    }
  }
}

// ---- offset branch, all-register, vectorized q loads
__global__ __launch_bounds__(256) void offset_kernel(
    const ushort_t* __restrict__ qt, const float* __restrict__ odw,
    const float* __restrict__ odb, const float* __restrict__ olw,
    const float* __restrict__ olb, const float* __restrict__ opw,
    float* __restrict__ pos) {
  int bg = blockIdx.x;
  int b = bg / G_, g = bg % G_;
  int t = threadIdx.x;
  int hk = t >> 4, wk = t & 15;
  const ushort_t* qb = qt + (size_t)b * HW_ * C_ + g * CG_;
  float sv[CG_];
#pragma unroll
  for (int cc = 0; cc < 8; ++cc) {
    float a8[8];
#pragma unroll
    for (int j = 0; j < 8; ++j) a8[j] = odb[cc * 8 + j];
#pragma unroll
    for (int ky = 0; ky < 3; ++ky) {
      int ih = 2 * hk + ky - 1;
      if ((unsigned)ih >= 32u) continue;
#pragma unroll
      for (int kx = 0; kx < 3; ++kx) {
        int iw = 2 * wk + kx - 1;
        if ((unsigned)iw >= 32u) continue;
        uint4 u = *(const uint4*)(qb + (size_t)(ih * 32 + iw) * C_ + cc * 8);
        float vv[8] = {bflo(u.x), bfhi(u.x), bflo(u.y), bfhi(u.y),
                       bflo(u.z), bfhi(u.z), bflo(u.w), bfhi(u.w)};
#pragma unroll
        for (int j = 0; j < 8; ++j)
          a8[j] = fmaf(odw[(cc * 8 + j) * 9 + ky * 3 + kx], vv[j], a8[j]);
      }
    }
#pragma unroll
    for (int j = 0; j < 8; ++j) sv[cc * 8 + j] = a8[j];
  }
  float mu = 0.f;
#pragma unroll
  for (int c = 0; c < CG_; c++) mu += sv[c];
  mu *= (1.f / CG_);
  float var = 0.f;
#pragma unroll
  for (int c = 0; c < CG_; c++) {
    float d = sv[c] - mu;
    var = fmaf(d, d, var);
  }
  var *= (1.f / CG_);
  float rs = rsqrtf(var + 1e-5f);
  float dy = 0.f, dx = 0.f;
#pragma unroll
  for (int c = 0; c < CG_; c++) {
    float tv = (sv[c] - mu) * rs * olw[c] + olb[c];
    float ge = gelu_exact(tv);
    dy = fmaf(opw[c], ge, dy);
    dx = fmaf(opw[CG_ + c], ge, dx);
  }
  float ry = (hk + 0.5f) * (2.f / 15.f) - 1.f;
  float rx = (wk + 0.5f) * (2.f / 15.f) - 1.f;
  pos[(size_t)bg * 512 + t * 2 + 0] = fminf(fmaxf(dy + ry, -1.f), 1.f);
  pos[(size_t)bg * 512 + t * 2 + 1] = fminf(fmaxf(dx + rx, -1.f), 1.f);
}

// ---- fused deformable sampling + transpose: y1 fp32 -> xst bf16 [b][n][C]
__global__ __launch_bounds__(256) void sample_xst(
    const float* __restrict__ y1, const float* __restrict__ pos,
    ushort_t* __restrict__ xst) {
  int bg = blockIdx.y;
  int b = bg / G_, g = bg % G_;
  int t = threadIdx.x;
  int cg = t & 63, nl = t >> 6;
  int n = blockIdx.x * 4 + nl;
  float py = pos[(size_t)bg * 512 + 2 * n];
  float px = pos[(size_t)bg * 512 + 2 * n + 1];
  float gx = (px + 1.f) * 15.5f, gy = (py + 1.f) * 15.5f;
  float fx = floorf(gx), fy = floorf(gy);
  float wx = gx - fx, wy = gy - fy;
  int x0 = min(max((int)fx, 0), 31), y0 = min(max((int)fy, 0), 31);
  int x1 = min(x0 + 1, 31), y1i = min(y0 + 1, 31);
  const float* img = y1 + ((size_t)b * C_ + g * CG_ + cg) * HW_;
  float v00 = img[y0 * 32 + x0], v01 = img[y0 * 32 + x1];
  float v10 = img[y1i * 32 + x0], v11 = img[y1i * 32 + x1];
  float v = v00 * (1.f - wx) * (1.f - wy) + v01 * wx * (1.f - wy) +
            v10 * (1.f - wx) * wy + v11 * wx * wy;
  xst[((size_t)b * NS_ + n) * C_ + g * CG_ + cg] = f2bf(v);
}

// ---- MFMA flash attention; rpe quad table via global_load_lds.
__global__ __launch_bounds__(256) void attn_kernel(
    const ushort_t* __restrict__ qt, const ushort_t* __restrict__ kt,
    const ushort_t* __restrict__ vbn, const float* __restrict__ pos,
    const uint2* __restrict__ rpq, ushort_t* __restrict__ aot) {
  __shared__ __align__(16) uint2 sRPQ[4096];         // 32 KB
  __shared__ __align__(16) ushort_t sP[4][32 * 40];  // 10 KB P bounce
  __shared__ unsigned sIB[256];
  __shared__ float sW2[512];
  int bid = blockIdx.x;
  int swzb = (bid & 7) * 96 + (bid >> 3);  // 768 = 8 XCD * 96
  int qb = swzb & 7;
  int grp = swzb >> 3;
  int h = grp % HEADS_;
  int b = grp / HEADS_;
  int t = threadIdx.x;
  int l = t & 63, wv = t >> 6;
  int lrow = l & 15, lg = l >> 4;
  int bg = b * G_ + (h >> 1);
  {
    const ushort_t* src = (const ushort_t*)(rpq + (size_t)h * 4096);
    ushort_t* dstb = (ushort_t*)sRPQ;
#pragma unroll
    for (int i = 0; i < 8; ++i)
      gload16(src + i * 2048 + t * 8, dstb + i * 2048 + wv * 512);
  }
  {
    float py = pos[(size_t)bg * 512 + 2 * t];
    float px = pos[(size_t)bg * 512 + 2 * t + 1];
    float cy = 15.5f - 15.5f * py;
    float cx = 15.5f - 15.5f * px;
    float fy = floorf(cy), fx = floorf(cx);
    sIB[t] = (unsigned)((int)fy * 64 + (int)fx);
    sW2[2 * t] = cy - fy;
    sW2[2 * t + 1] = cx - fx;
  }
  __syncthreads();

  int m0 = qb * 128 + wv * 32;
  short8 qf[2];
  int aq[2];
#pragma unroll
  for (int f = 0; f < 2; ++f) {
    int m = m0 + f * 16 + lrow;
    qf[f] = *(const short8*)(qt + ((size_t)b * HW_ + m) * C_ + h * HC_ + lg * 8);
    aq[f] = (m >> 5) * 64 + (m & 31);
  }
  const ushort_t* kbase = kt + (size_t)b * NS_ * C_ + h * HC_;
  const ushort_t* vbase = vbn + ((size_t)b * C_ + h * HC_) * NS_;
  f32x4 oc[2][2];
#pragma unroll
  for (int f = 0; f < 2; ++f)
#pragma unroll
    for (int ct = 0; ct < 2; ++ct) oc[f][ct] = f32x4{0.f, 0.f, 0.f, 0.f};
  float mrun[2] = {-1e30f, -1e30f}, lrun[2] = {0.f, 0.f};
  ushort_t* sPw = sP[wv];

  for (int c = 0; c < 8; ++c) {
    f32x4 s[2][2];
    __builtin_amdgcn_s_setprio(1);
#pragma unroll
    for (int T = 0; T < 2; ++T) {
      short8 kf = *(const short8*)(kbase + (size_t)((c * 2 + T) * 16 + lrow) * C_ + lg * 8);
#pragma unroll
      for (int f = 0; f < 2; ++f)
        s[f][T] = __builtin_amdgcn_mfma_f32_16x16x32_bf16(kf, qf[f], f32x4{0.f, 0.f, 0.f, 0.f}, 0, 0, 0);
    }
    __builtin_amdgcn_s_setprio(0);
    u32x4 ibT[2];
    f32x4 wA[2], wB[2];
#pragma unroll
    for (int T = 0; T < 2; ++T) {
      int kbase2 = c * 32 + T * 16 + lg * 4;
      ibT[T] = *(const u32x4*)&sIB[kbase2];
      wA[T] = *(const f32x4*)&sW2[2 * kbase2];
      wB[T] = *(const f32x4*)&sW2[2 * kbase2 + 4];
    }
#pragma unroll
    for (int f = 0; f < 2; ++f)
#pragma unroll
      for (int T = 0; T < 2; ++T)
#pragma unroll
        for (int r = 0; r < 4; ++r) {
          int a = aq[f] + (int)ibT[T][r];
          float wy = (r < 2) ? wA[T][(r & 1) * 2] : wB[T][(r & 1) * 2];
          float wx = (r < 2) ? wA[T][(r & 1) * 2 + 1] : wB[T][(r & 1) * 2 + 1];
          uint2 qd = sRPQ[a];
          float b00 = bflo(qd.x), b01 = bfhi(qd.x);
          float b10 = bflo(qd.y), b11 = bfhi(qd.y);
          float r0 = b00 + wx * (b01 - b00);
          float r1 = b10 + wx * (b11 - b10);
          s[f][T][r] = s[f][T][r] * SCALE_ + r0 + wy * (r1 - r0);
        }
#pragma unroll
    for (int f = 0; f < 2; ++f) {
      float mx = s[f][0][0];
#pragma unroll
      for (int T = 0; T < 2; ++T)
#pragma unroll
        for (int r = 0; r < 4; ++r) mx = fmaxf(mx, s[f][T][r]);
      mx = fmaxf(mx, __shfl_xor(mx, 16));
      mx = fmaxf(mx, __shfl_xor(mx, 32));
      float newm = fmaxf(mrun[f], mx);
      float fac = __expf(mrun[f] - newm);
      mrun[f] = newm;
      float ps = 0.f;
#pragma unroll
      for (int T = 0; T < 2; ++T)
#pragma unroll
        for (int r = 0; r < 4; ++r) {
          float p = __expf(s[f][T][r] - newm);
          s[f][T][r] = p;
          ps += p;
        }
      ps += __shfl_xor(ps, 16);
      ps += __shfl_xor(ps, 32);
      lrun[f] = lrun[f] * fac + ps;
#pragma unroll
      for (int ct = 0; ct < 2; ++ct)
#pragma unroll
        for (int r = 0; r < 4; ++r) oc[f][ct][r] *= fac;
#pragma unroll
      for (int T = 0; T < 2; ++T) {
        uint2 u;
        u.x = pack2(s[f][T][0], s[f][T][1]);
        u.y = pack2(s[f][T][2], s[f][T][3]);
        *(uint2*)&sPw[(f * 16 + lrow) * 40 + T * 16 + lg * 4] = u;
      }
    }
    short8 pa[2];
#pragma unroll
    for (int f = 0; f < 2; ++f)
      pa[f] = *(const short8*)&sPw[(f * 16 + lrow) * 40 + lg * 8];
    __builtin_amdgcn_s_setprio(1);
#pragma unroll
    for (int ct = 0; ct < 2; ++ct) {
      short8 vf = *(const short8*)(vbase + (size_t)(ct * 16 + lrow) * NS_ + c * 32 + lg * 8);
#pragma unroll
      for (int f = 0; f < 2; ++f)
        oc[f][ct] = __builtin_amdgcn_mfma_f32_16x16x32_bf16(pa[f], vf, oc[f][ct], 0, 0, 0);
    }
    __builtin_amdgcn_s_setprio(0);
  }
#pragma unroll
  for (int f = 0; f < 2; ++f) {
    float inv = 1.f / lrun[f];
    float invq[4];
#pragma unroll
    for (int r = 0; r < 4; ++r) invq[r] = __shfl(inv, lg * 4 + r);
#pragma unroll
    for (int ct = 0; ct < 2; ++ct)
#pragma unroll
      for (int r = 0; r < 4; ++r) {
        int m = m0 + f * 16 + lg * 4 + r;
        aot[((size_t)b * HW_ + m) * C_ + h * HC_ + ct * 16 + lrow] =
            f2bf(oc[f][ct][r] * invq[r]);
      }
  }
}

}  // namespace

extern "C" void kernel_launch(void* const* d_in, const int* in_sizes, int n_in,
                              void* d_out, int out_size, void* d_ws,
                              size_t ws_size, hipStream_t stream) {
  const float* x_in = (const float*)d_in[0];
  const float* lpu_w = (const float*)d_in[1];
  const float* lpu_b = (const float*)d_in[2];
  const float* wq = (const float*)d_in[3];
  const float* bq = (const float*)d_in[4];
  const float* wk = (const float*)d_in[5];
  const float* bk = (const float*)d_in[6];
  const float* wv = (const float*)d_in[7];
  const float* bv = (const float*)d_in[8];
  const float* wo = (const float*)d_in[9];
  const float* bo = (const float*)d_in[10];
  const float* odw = (const float*)d_in[11];
  const float* odb = (const float*)d_in[12];
  const float* olw = (const float*)d_in[13];
  const float* olb = (const float*)d_in[14];
  const float* opw = (const float*)d_in[15];
  const float* rpe = (const float*)d_in[16];
  const float* w1 = (const float*)d_in[17];
  const float* b1 = (const float*)d_in[18];
  const float* mdw = (const float*)d_in[19];
  const float* mdb = (const float*)d_in[20];
  const float* w2 = (const float*)d_in[21];
  const float* b2 = (const float*)d_in[22];
  float* out = (float*)d_out;

  constexpr size_t XSZ = (size_t)B_ * C_ * HW_;
  constexpr size_t SSZ = (size_t)B_ * C_ * NS_;
  constexpr size_t HSZ = (size_t)B_ * D2_ * HW_;

  char* base = (char*)d_ws;
  auto alloc = [&](size_t bytes) {
    char* p = base;
    base += (bytes + 255) & ~(size_t)255;
    return p;
  };
  float* bufX = (float*)alloc(XSZ * 4);
  float* y1 = (float*)alloc(XSZ * 4);
  float* x2 = (float*)alloc(XSZ * 4);
  float* pos = (float*)alloc(48 * 512 * 4);
  ushort_t* qt = (ushort_t*)alloc(XSZ * 2);
  ushort_t* tb1 = (ushort_t*)alloc(XSZ * 2);
  ushort_t* aot = (ushort_t*)alloc(XSZ * 2);
  ushort_t* xst = (ushort_t*)alloc(SSZ * 2);
  ushort_t* ktb = (ushort_t*)alloc(SSZ * 2);
  ushort_t* vbn = (ushort_t*)alloc(SSZ * 2);
  ushort_t* h1b = (ushort_t*)alloc(HSZ * 2);
  ushort_t* h3t = (ushort_t*)alloc(HSZ * 2);
  ushort_t* wb = (ushort_t*)alloc((size_t)3538944 * 2);
  uint2* rpq = (uint2*)alloc((size_t)2 * HEADS_ * 4096 * 8);

  ushort_t* wqb = wb;
  ushort_t* wkb = wb + 294912;
  ushort_t* wvb = wb + 589824;
  ushort_t* wob = wb + 884736;
  ushort_t* w1b = wb + 1179648;
  ushort_t* w2b = wb + 2359296;

  wcvt_kernel<<<3538944 / 256, 256, 0, stream>>>(wq, wk, wv, wo, w1, w2, wb);
  rpe_pack<<<dim3(HEADS_, 2), 256, 0, stream>>>(rpe, rpq);

  for (int d = 0; d < 2; ++d) {
    const float* xin = (d == 0) ? x_in : bufX;
    float* xnext = (d == 1) ? out : bufX;
    const ushort_t* wqd = wqb + (size_t)d * 147456;
    const ushort_t* wkd = wkb + (size_t)d * 147456;
    const ushort_t* wvd = wvb + (size_t)d * 147456;
    const ushort_t* wod = wob + (size_t)d * 147456;
    const ushort_t* w1d = w1b + (size_t)d * 589824;
    const ushort_t* w2d = w2b + (size_t)d * 589824;

    dwconv_lpu<<<dim3(32, 12, 8), 256, 0, stream>>>(xin, lpu_w + d * C_ * 9,
                                                    lpu_b + d * C_, y1, tb1);
    gemm128<false, false, true, false><<<dim3(8, 3, 8), 256, 0, stream>>>(
        wqd, tb1, bq + d * C_, nullptr, nullptr, qt, C_, C_, HW_);
    offset_kernel<<<48, 256, 0, stream>>>(qt, odw + d * CG_ * 9, odb + d * CG_,
                                          olw + d * CG_, olb + d * CG_,
                                          opw + d * 2 * CG_, pos);
    sample_xst<<<dim3(64, 48), 256, 0, stream>>>(y1, pos, xst);
    gemm_kv<<<dim3(4, 12, 8), 256, 0, stream>>>(wkd, wvd, xst, bk + d * C_,
                                                bv + d * C_, ktb, vbn);
    attn_kernel<<<768, 256, 0, stream>>>(qt, ktb, vbn, pos,
                                         rpq + (size_t)d * HEADS_ * 4096, aot);
    gemm128<true, false, true, true><<<dim3(8, 3, 8), 256, 0, stream>>>(
        wod, aot, bo + d * C_, y1, x2, tb1, C_, C_, HW_);
    gemm128<false, true, false, false><<<dim3(8, 12, 8), 256, 0, stream>>>(
        w1d, tb1, b1 + d * D2_, nullptr, nullptr, h1b, D2_, C_, HW_);
    dwgelu_t<<<dim3(16, 48, 8), 256, 0, stream>>>(h1b, mdw + d * D2_ * 9,
                                                  mdb + d * D2_, h3t);
    gemm128<true, false, false, true><<<dim3(8, 3, 8), 256, 0, stream>>>(
        w2d, h3t, b2 + d * C_, x2, xnext, nullptr, C_, D2_, HW_);
  }
}

// Round 8
// 460.827 us; speedup vs baseline: 3.7828x; 1.0998x over previous
//
#include <hip/hip_runtime.h>
#include <hip/hip_bf16.h>
#include <math.h>

namespace {

constexpr int B_ = 8, C_ = 384, H_ = 32, W_ = 32, HW_ = 1024;
constexpr int HEADS_ = 12, G_ = 6, HC_ = 32, CG_ = 64, NS_ = 256, D2_ = 1536;
constexpr float SCALE_ = 0.17677669529663687f;  // 32^-0.5

using short8 = __attribute__((ext_vector_type(8))) short;
using f32x4 = __attribute__((ext_vector_type(4))) float;
using u32x4 = __attribute__((ext_vector_type(4))) unsigned;
typedef unsigned short ushort_t;

__device__ __forceinline__ float gelu_exact(float x) {
  return 0.5f * x * (1.f + erff(x * 0.70710678118654752f));
}
__device__ __forceinline__ ushort_t f2bf(float f) {
  unsigned u = __float_as_uint(f);
  u = (u + 0x7FFFu + ((u >> 16) & 1u)) >> 16;
  return (ushort_t)u;
}
__device__ __forceinline__ float bf2f(ushort_t s) {
  return __uint_as_float(((unsigned)s) << 16);
}
__device__ __forceinline__ float bflo(unsigned u) { return __uint_as_float(u << 16); }
__device__ __forceinline__ float bfhi(unsigned u) { return __uint_as_float(u & 0xFFFF0000u); }
__device__ __forceinline__ unsigned pack2(float a, float b) {
  return (unsigned)f2bf(a) | ((unsigned)f2bf(b) << 16);
}

typedef __attribute__((address_space(1))) const unsigned int gq_u32;
typedef __attribute__((address_space(3))) unsigned int lq_u32;
__device__ __forceinline__ void gload16(const ushort_t* g, ushort_t* l) {
  __builtin_amdgcn_global_load_lds((gq_u32*)g, (lq_u32*)l, 16, 0, 0);
}

// ---- weight fp32 -> bf16 (+ rpe quad-pack fused as trailing blocks)
__global__ __launch_bounds__(256) void wcvt_rpe(
    const float* __restrict__ s0, const float* __restrict__ s1,
    const float* __restrict__ s2, const float* __restrict__ s3,
    const float* __restrict__ s4, const float* __restrict__ s5,
    ushort_t* __restrict__ dst, const float* __restrict__ rpe,
    uint2* __restrict__ rpq) {
  int blk = blockIdx.x;
  if (blk < 13824) {
    long idx = (long)blk * 256 + threadIdx.x;
    long off = idx;
    const float* s;
    if (off < 294912) s = s0;
    else if ((off -= 294912) < 294912) s = s1;
    else if ((off -= 294912) < 294912) s = s2;
    else if ((off -= 294912) < 294912) s = s3;
    else if ((off -= 294912) < 1179648) s = s4;
    else { off -= 1179648; s = s5; }
    dst[idx] = f2bf(s[off]);
  } else {
    int hb = blk - 13824;  // 24 = 12 heads * 2 depths
    const float* rph = rpe + (size_t)hb * 3969;
    uint2* dq = rpq + (size_t)hb * 4096;
    for (int i = threadIdx.x; i < 4096; i += 256) {
      int y = i >> 6, x = i & 63;
      float v00 = 0.f, v01 = 0.f, v10 = 0.f, v11 = 0.f;
      if (y < 63) {
        if (x < 63) v00 = rph[y * 63 + x];
        if (x < 62) v01 = rph[y * 63 + x + 1];
      }
      if (y < 62) {
        if (x < 63) v10 = rph[(y + 1) * 63 + x];
        if (x < 62) v11 = rph[(y + 1) * 63 + x + 1];
      }
      dq[i] = make_uint2(pack2(v00, v01), pack2(v10, v11));
    }
  }
}

// ---- LPU: y = x + dwconv3x3(x), vectorized 4 px/thread.
__global__ __launch_bounds__(256) void dwconv_lpu(
    const float* __restrict__ x, const float* __restrict__ w,
    const float* __restrict__ bias, float* __restrict__ y,
    ushort_t* __restrict__ yt) {
  __shared__ __align__(16) float tile[32][33];
  int hp = blockIdx.x, c0 = blockIdx.y * 32, b = blockIdx.z;
  int t = threadIdx.x;
  int cl = t >> 3, g4 = t & 7;
  int c = c0 + cl;
  const float* img = x + ((size_t)b * C_ + c) * HW_;
  const float* wc = w + c * 9;
  float o0 = bias[c], o1 = o0, o2 = o0, o3 = o0;
#pragma unroll
  for (int ky = 0; ky < 3; ++ky) {
    int ih = hp + ky - 1;
    if ((unsigned)ih >= 32u) continue;
    const float* row = img + ih * 32 + g4 * 4;
    float4 m = *(const float4*)row;
    float v0 = (g4 > 0) ? row[-1] : 0.f;
    float v5 = (g4 < 7) ? row[4] : 0.f;
    float k0 = wc[ky * 3], k1 = wc[ky * 3 + 1], k2 = wc[ky * 3 + 2];
    o0 = fmaf(k0, v0, fmaf(k1, m.x, fmaf(k2, m.y, o0)));
    o1 = fmaf(k0, m.x, fmaf(k1, m.y, fmaf(k2, m.z, o1)));
    o2 = fmaf(k0, m.y, fmaf(k1, m.z, fmaf(k2, m.w, o2)));
    o3 = fmaf(k0, m.z, fmaf(k1, m.w, fmaf(k2, v5, o3)));
  }
  float4 ctr = *(const float4*)(img + hp * 32 + g4 * 4);
  o0 += ctr.x; o1 += ctr.y; o2 += ctr.z; o3 += ctr.w;
  *(float4*)(y + ((size_t)b * C_ + c) * HW_ + hp * 32 + g4 * 4) =
      make_float4(o0, o1, o2, o3);
  tile[cl][g4 * 4 + 0] = o0;
  tile[cl][g4 * 4 + 1] = o1;
  tile[cl][g4 * 4 + 2] = o2;
  tile[cl][g4 * 4 + 3] = o3;
  __syncthreads();
  int wl = t >> 3, cg = t & 7;
  unsigned p0 = pack2(tile[cg * 4 + 0][wl], tile[cg * 4 + 1][wl]);
  unsigned p1 = pack2(tile[cg * 4 + 2][wl], tile[cg * 4 + 3][wl]);
  unsigned* dst = (unsigned*)(yt + ((size_t)b * HW_ + hp * 32 + wl) * C_ + c0 + cg * 4);
  dst[0] = p0;
  dst[1] = p1;
}

// ---- MLP dw: h3t[b][hw][c] = bf16(gelu(h + dwconv(h)+bias)); 8 px/thread
__global__ __launch_bounds__(256) void dwgelu_t(
    const ushort_t* __restrict__ hin, const float* __restrict__ w,
    const float* __restrict__ bias, ushort_t* __restrict__ ht) {
  __shared__ __align__(16) float tile[2][32][33];
  int hp0 = blockIdx.x * 2, c0 = blockIdx.y * 32, b = blockIdx.z;
  int t = threadIdx.x;
  int cl = t >> 3, rw = (t >> 2) & 1, g8 = t & 3;
  int hp = hp0 + rw;
  int c = c0 + cl;
  const ushort_t* img = hin + ((size_t)b * D2_ + c) * HW_;
  const float* wc = w + c * 9;
  float o[8];
  float bi = bias[c];
#pragma unroll
  for (int j = 0; j < 8; ++j) o[j] = bi;
#pragma unroll
  for (int ky = 0; ky < 3; ++ky) {
    int ih = hp + ky - 1;
    if ((unsigned)ih >= 32u) continue;
    const ushort_t* row = img + ih * 32 + g8 * 8;
    uint4 u = *(const uint4*)row;
    float vv[10];
    vv[0] = (g8 > 0) ? bf2f(row[-1]) : 0.f;
    vv[1] = bflo(u.x); vv[2] = bfhi(u.x); vv[3] = bflo(u.y); vv[4] = bfhi(u.y);
    vv[5] = bflo(u.z); vv[6] = bfhi(u.z); vv[7] = bflo(u.w); vv[8] = bfhi(u.w);
    vv[9] = (g8 < 3) ? bf2f(row[8]) : 0.f;
    float k0 = wc[ky * 3], k1 = wc[ky * 3 + 1], k2 = wc[ky * 3 + 2];
#pragma unroll
    for (int j = 0; j < 8; ++j)
      o[j] = fmaf(k0, vv[j], fmaf(k1, vv[j + 1], fmaf(k2, vv[j + 2], o[j])));
  }
  {
    uint4 u = *(const uint4*)(img + hp * 32 + g8 * 8);
    float cv[8] = {bflo(u.x), bfhi(u.x), bflo(u.y), bfhi(u.y),
                   bflo(u.z), bfhi(u.z), bflo(u.w), bfhi(u.w)};
#pragma unroll
    for (int j = 0; j < 8; ++j) {
      o[j] += cv[j];
      tile[rw][cl][g8 * 8 + j] = gelu_exact(o[j]);
    }
  }
  __syncthreads();
  int wl = t >> 3, cg = t & 7;
#pragma unroll
  for (int rr = 0; rr < 2; ++rr) {
    unsigned p0 = pack2(tile[rr][cg * 4 + 0][wl], tile[rr][cg * 4 + 1][wl]);
    unsigned p1 = pack2(tile[rr][cg * 4 + 2][wl], tile[rr][cg * 4 + 3][wl]);
    unsigned* dst = (unsigned*)(ht + ((size_t)b * HW_ + (hp0 + rr) * 32 + wl) * D2_ + c0 + cg * 4);
    dst[0] = p0;
    dst[1] = p1;
  }
}

// ---- fused K+V projection, 64-tile, reg-prefetch pipeline.
__global__ __launch_bounds__(256) void gemm_kv(
    const ushort_t* __restrict__ Wk, const ushort_t* __restrict__ Wv,
    const ushort_t* __restrict__ Xt, const float* __restrict__ bk,
    const float* __restrict__ bv, ushort_t* __restrict__ ktb,
    ushort_t* __restrict__ vbn) {
  constexpr int K = C_, N = NS_, O = C_;
  struct __align__(16) SMem {
    union {
      struct { char a[8192]; char b[8192]; } st;
      float shuf[64 * 68];
    };
  };
  __shared__ SMem sm;
  int t = threadIdx.x;
  int lane = t & 63, wave = t >> 6;
  int wm = (wave >> 1) * 32, wn = (wave & 1) * 32;
  int bz = blockIdx.z;
  bool isK = blockIdx.y < 6;
  int o0 = (isK ? blockIdx.y : blockIdx.y - 6) * 64;
  int n0 = blockIdx.x * 64;
  const ushort_t* Wb = isK ? Wk : Wv;
  const float* bias = isK ? bk : bv;
  const ushort_t* Ag = Wb + (size_t)o0 * K;
  const ushort_t* Bg = Xt + ((size_t)bz * N + n0) * K;
  int sr = t >> 3, sc = t & 7;
  int swz = ((sc ^ (sr & 7)) << 4);
  f32x4 acc[2][2];
#pragma unroll
  for (int fi = 0; fi < 2; ++fi)
#pragma unroll
    for (int fj = 0; fj < 2; ++fj) acc[fi][fj] = f32x4{0.f, 0.f, 0.f, 0.f};
  int lrow = lane & 15, lk = lane >> 4;
  short8 a0 = *(const short8*)(Ag + (size_t)sr * K + sc * 8);
  short8 a1 = *(const short8*)(Ag + (size_t)(sr + 32) * K + sc * 8);
  short8 b0 = *(const short8*)(Bg + (size_t)sr * K + sc * 8);
  short8 b1 = *(const short8*)(Bg + (size_t)(sr + 32) * K + sc * 8);
  constexpr int NSTEP = K / 64;
#pragma unroll
  for (int s = 0; s < NSTEP; ++s) {
    if (s) __syncthreads();
    *(short8*)(sm.st.a + sr * 128 + swz) = a0;
    *(short8*)(sm.st.a + (sr + 32) * 128 + swz) = a1;
    *(short8*)(sm.st.b + sr * 128 + swz) = b0;
    *(short8*)(sm.st.b + (sr + 32) * 128 + swz) = b1;
    __syncthreads();
    if (s + 1 < NSTEP) {
      int k0 = (s + 1) * 64;
      a0 = *(const short8*)(Ag + (size_t)sr * K + k0 + sc * 8);
      a1 = *(const short8*)(Ag + (size_t)(sr + 32) * K + k0 + sc * 8);
      b0 = *(const short8*)(Bg + (size_t)sr * K + k0 + sc * 8);
      b1 = *(const short8*)(Bg + (size_t)(sr + 32) * K + k0 + sc * 8);
    }
#pragma unroll
    for (int kk = 0; kk < 2; ++kk) {
      short8 af[2], bfr[2];
#pragma unroll
      for (int fi = 0; fi < 2; ++fi) {
        int row = wm + fi * 16 + lrow;
        af[fi] = *(const short8*)(sm.st.a + row * 128 + (((kk * 4 + lk) ^ (row & 7)) << 4));
      }
#pragma unroll
      for (int fj = 0; fj < 2; ++fj) {
        int row = wn + fj * 16 + lrow;
        bfr[fj] = *(const short8*)(sm.st.b + row * 128 + (((kk * 4 + lk) ^ (row & 7)) << 4));
      }
#pragma unroll
      for (int fi = 0; fi < 2; ++fi)
#pragma unroll
        for (int fj = 0; fj < 2; ++fj)
          acc[fi][fj] = __builtin_amdgcn_mfma_f32_16x16x32_bf16(af[fi], bfr[fj], acc[fi][fj], 0, 0, 0);
    }
  }
  __syncthreads();
#pragma unroll
  for (int fi = 0; fi < 2; ++fi) {
#pragma unroll
    for (int r = 0; r < 4; ++r) {
      int ol = wm + fi * 16 + lk * 4 + r;
      float bi = bias[o0 + ol];
#pragma unroll
      for (int fj = 0; fj < 2; ++fj) {
        int nl = wn + fj * 16 + lrow;
        sm.shuf[ol * 68 + nl] = acc[fi][fj][r] + bi;
      }
    }
  }
  __syncthreads();
  if (isK) {
    int nl = t >> 2, og = (t & 3) * 16;
    unsigned pk[8];
#pragma unroll
    for (int i = 0; i < 8; ++i)
      pk[i] = pack2(sm.shuf[(og + 2 * i) * 68 + nl], sm.shuf[(og + 2 * i + 1) * 68 + nl]);
    unsigned* dst = (unsigned*)(ktb + ((size_t)bz * N + (n0 + nl)) * O + o0 + og);
    *(uint4*)(dst) = make_uint4(pk[0], pk[1], pk[2], pk[3]);
    *(uint4*)(dst + 4) = make_uint4(pk[4], pk[5], pk[6], pk[7]);
  } else {
    int ol = t >> 2, ng = (t & 3) * 16;
    unsigned pk[8];
#pragma unroll
    for (int i = 0; i < 8; ++i)
      pk[i] = pack2(sm.shuf[ol * 68 + ng + 2 * i], sm.shuf[ol * 68 + ng + 2 * i + 1]);
    unsigned* dst = (unsigned*)(vbn + ((size_t)bz * O + (o0 + ol)) * N + n0 + ng);
    *(uint4*)(dst) = make_uint4(pk[0], pk[1], pk[2], pk[3]);
    *(uint4*)(dst + 4) = make_uint4(pk[4], pk[5], pk[6], pk[7]);
  }
}

// ---- 128xBN x64 bf16 GEMM, double-buffered global_load_lds.
// BN=128: 4 waves as 2x2 of 64x64.  BN=64: 4 waves as 4x1 of 32x64.
template <int BN, bool F32, bool B16N, bool B16T, bool RES>
__global__ __launch_bounds__(256) void gemm128(
    const ushort_t* __restrict__ Wb, const ushort_t* __restrict__ Xt,
    const float* __restrict__ bias, const float* __restrict__ resid,
    float* __restrict__ Y, ushort_t* __restrict__ Yb, int O, int K, int N) {
  constexpr int MFW = (BN == 128) ? 4 : 2;
  __shared__ __align__(16) ushort_t sA[2][128 * 64];
  __shared__ __align__(16) ushort_t sB[2][BN * 64];
  int t = threadIdx.x;
  int l = t & 63, w = t >> 6;
  int o0 = blockIdx.y * 128, n0 = blockIdx.x * BN, bz = blockIdx.z;
  const ushort_t* Ag = Wb + (size_t)o0 * K;
  const ushort_t* Bg = Xt + ((size_t)bz * N + n0) * K;
  int lr8 = l >> 3;
  int scol = (l & 7) * 8;
  int lrow = l & 15, lg = l >> 4;
  int wm = (BN == 128) ? (w >> 1) * 64 : w * 32;
  int wn = (BN == 128) ? (w & 1) * 64 : 0;
  f32x4 acc[MFW][4];
#pragma unroll
  for (int fi = 0; fi < MFW; ++fi)
#pragma unroll
    for (int fj = 0; fj < 4; ++fj) acc[fi][fj] = f32x4{0.f, 0.f, 0.f, 0.f};
  auto stage = [&](int buf, int k0) {
#pragma unroll
    for (int i = 0; i < 4; ++i)
      gload16(Ag + (size_t)(w * 32 + i * 8 + lr8) * K + k0 + scol,
              sA[buf] + (w * 32 + i * 8) * 64);
    if constexpr (BN == 128) {
#pragma unroll
      for (int i = 0; i < 4; ++i)
        gload16(Bg + (size_t)(w * 32 + i * 8 + lr8) * K + k0 + scol,
                sB[buf] + (w * 32 + i * 8) * 64);
    } else {
#pragma unroll
      for (int i = 0; i < 2; ++i)
        gload16(Bg + (size_t)(w * 16 + i * 8 + lr8) * K + k0 + scol,
                sB[buf] + (w * 16 + i * 8) * 64);
    }
  };
  stage(0, 0);
  __syncthreads();
  int nstep = K >> 6;
  for (int s = 0; s < nstep; ++s) {
    int cur = s & 1;
    if (s + 1 < nstep) stage(cur ^ 1, (s + 1) * 64);
#pragma unroll
    for (int kk = 0; kk < 2; ++kk) {
      short8 af[MFW], bfr[4];
#pragma unroll
      for (int fi = 0; fi < MFW; ++fi)
        af[fi] = *(const short8*)(sA[cur] + (wm + fi * 16 + lrow) * 64 + kk * 32 + lg * 8);
#pragma unroll
      for (int fj = 0; fj < 4; ++fj)
        bfr[fj] = *(const short8*)(sB[cur] + (wn + fj * 16 + lrow) * 64 + kk * 32 + lg * 8);
#pragma unroll
      for (int fi = 0; fi < MFW; ++fi)
#pragma unroll
        for (int fj = 0; fj < 4; ++fj)
          acc[fi][fj] = __builtin_amdgcn_mfma_f32_16x16x32_bf16(af[fi], bfr[fj], acc[fi][fj], 0, 0, 0);
    }
    __syncthreads();
  }
#pragma unroll
  for (int fi = 0; fi < MFW; ++fi) {
    int ob = wm + fi * 16 + lg * 4;
    float bi[4];
#pragma unroll
    for (int r = 0; r < 4; ++r) bi[r] = bias[o0 + ob + r];
#pragma unroll
    for (int fj = 0; fj < 4; ++fj) {
      int n = n0 + wn + fj * 16 + lrow;
      float v[4];
#pragma unroll
      for (int r = 0; r < 4; ++r) {
        v[r] = acc[fi][fj][r] + bi[r];
        if (RES) v[r] += resid[((size_t)bz * O + ob + r + o0) * N + n];
        if (F32) Y[((size_t)bz * O + ob + r + o0) * N + n] = v[r];
        if (B16N) Yb[((size_t)bz * O + ob + r + o0) * N + n] = f2bf(v[r]);
      }
      if (B16T) {
        uint2 u;
        u.x = pack2(v[0], v[1]);
        u.y = pack2(v[2], v[3]);
        *(uint2*)&Yb[((size_t)bz * N + n) * O + o0 + ob] = u;
      }
    }
  }
}

// ---- offset branch: 4 threads per position (16 ch each), quad shfl-reduce LN.
// grid 192 = 48 bg * 4 position-quarters.
__global__ __launch_bounds__(256) void offset_kernel(
    const ushort_t* __restrict__ qt, const float* __restrict__ odw,
    const float* __restrict__ odb, const float* __restrict__ olw,
    const float* __restrict__ olb, const float* __restrict__ opw,
    float* __restrict__ pos) {
  int blk = blockIdx.x;
  int bg = blk >> 2, pb = blk & 3;
  int b = bg / G_, g = bg % G_;
  int t = threadIdx.x;
  int p = pb * 64 + (t >> 2);
  int q = t & 3;
  int c0 = q * 16;
  int hk = p >> 4, wk = p & 15;
  const ushort_t* qb = qt + (size_t)b * HW_ * C_ + g * CG_ + c0;
  float sv[16];
#pragma unroll
  for (int j = 0; j < 16; ++j) sv[j] = odb[c0 + j];
#pragma unroll
  for (int ky = 0; ky < 3; ++ky) {
    int ih = 2 * hk + ky - 1;
    if ((unsigned)ih >= 32u) continue;
#pragma unroll
    for (int kx = 0; kx < 3; ++kx) {
      int iw = 2 * wk + kx - 1;
      if ((unsigned)iw >= 32u) continue;
      const ushort_t* qp = qb + (size_t)(ih * 32 + iw) * C_;
      uint4 u0 = *(const uint4*)qp;
      uint4 u1 = *(const uint4*)(qp + 8);
      float vv[16] = {bflo(u0.x), bfhi(u0.x), bflo(u0.y), bfhi(u0.y),
                      bflo(u0.z), bfhi(u0.z), bflo(u0.w), bfhi(u0.w),
                      bflo(u1.x), bfhi(u1.x), bflo(u1.y), bfhi(u1.y),
                      bflo(u1.z), bfhi(u1.z), bflo(u1.w), bfhi(u1.w)};
      int tap = ky * 3 + kx;
#pragma unroll
      for (int j = 0; j < 16; ++j)
        sv[j] = fmaf(odw[(c0 + j) * 9 + tap], vv[j], sv[j]);
    }
  }
  float s1 = 0.f;
#pragma unroll
  for (int j = 0; j < 16; ++j) s1 += sv[j];
  s1 += __shfl_xor(s1, 1);
  s1 += __shfl_xor(s1, 2);
  float mu = s1 * (1.f / CG_);
  float vs = 0.f;
#pragma unroll
  for (int j = 0; j < 16; ++j) {
    float d = sv[j] - mu;
    vs = fmaf(d, d, vs);
  }
  vs += __shfl_xor(vs, 1);
  vs += __shfl_xor(vs, 2);
  float rs = rsqrtf(vs * (1.f / CG_) + 1e-5f);
  float dy = 0.f, dx = 0.f;
#pragma unroll
  for (int j = 0; j < 16; ++j) {
    int c = c0 + j;
    float tv = (sv[j] - mu) * rs * olw[c] + olb[c];
    float ge = gelu_exact(tv);
    dy = fmaf(opw[c], ge, dy);
    dx = fmaf(opw[CG_ + c], ge, dx);
  }
  dy += __shfl_xor(dy, 1);
  dy += __shfl_xor(dy, 2);
  dx += __shfl_xor(dx, 1);
  dx += __shfl_xor(dx, 2);
  if (q == 0) {
    float ry = (hk + 0.5f) * (2.f / 15.f) - 1.f;
    float rx = (wk + 0.5f) * (2.f / 15.f) - 1.f;
    pos[(size_t)bg * 512 + p * 2 + 0] = fminf(fmaxf(dy + ry, -1.f), 1.f);
    pos[(size_t)bg * 512 + p * 2 + 1] = fminf(fmaxf(dx + rx, -1.f), 1.f);
  }
}

// ---- fused deformable sampling + transpose: y1 fp32 -> xst bf16 [b][n][C]
__global__ __launch_bounds__(256) void sample_xst(
    const float* __restrict__ y1, const float* __restrict__ pos,
    ushort_t* __restrict__ xst) {
  int bg = blockIdx.y;
  int b = bg / G_, g = bg % G_;
  int t = threadIdx.x;
  int cg = t & 63, nl = t >> 6;
  int n = blockIdx.x * 4 + nl;
  float py = pos[(size_t)bg * 512 + 2 * n];
  float px = pos[(size_t)bg * 512 + 2 * n + 1];
  float gx = (px + 1.f) * 15.5f, gy = (py + 1.f) * 15.5f;
  float fx = floorf(gx), fy = floorf(gy);
  float wx = gx - fx, wy = gy - fy;
  int x0 = min(max((int)fx, 0), 31), y0 = min(max((int)fy, 0), 31);
  int x1 = min(x0 + 1, 31), y1i = min(y0 + 1, 31);
  const float* img = y1 + ((size_t)b * C_ + g * CG_ + cg) * HW_;
  float v00 = img[y0 * 32 + x0], v01 = img[y0 * 32 + x1];
  float v10 = img[y1i * 32 + x0], v11 = img[y1i * 32 + x1];
  float v = v00 * (1.f - wx) * (1.f - wy) + v01 * wx * (1.f - wy) +
            v10 * (1.f - wx) * wy + v11 * wx * wy;
  xst[((size_t)b * NS_ + n) * C_ + g * CG_ + cg] = f2bf(v);
}

// ---- MFMA flash attention; quad rpe table; defer-max (THR=8).
__global__ __launch_bounds__(256) void attn_kernel(
    const ushort_t* __restrict__ qt, const ushort_t* __restrict__ kt,
    const ushort_t* __restrict__ vbn, const float* __restrict__ pos,
    const uint2* __restrict__ rpq, ushort_t* __restrict__ aot) {
  __shared__ __align__(16) uint2 sRPQ[4096];
  __shared__ __align__(16) ushort_t sP[4][32 * 40];
  __shared__ unsigned sIB[256];
  __shared__ float sW2[512];
  int bid = blockIdx.x;
  int swzb = (bid & 7) * 96 + (bid >> 3);
  int qb = swzb & 7;
  int grp = swzb >> 3;
  int h = grp % HEADS_;
  int b = grp / HEADS_;
  int t = threadIdx.x;
  int l = t & 63, wv = t >> 6;
  int lrow = l & 15, lg = l >> 4;
  int bg = b * G_ + (h >> 1);
  {
    const ushort_t* src = (const ushort_t*)(rpq + (size_t)h * 4096);
    ushort_t* dstb = (ushort_t*)sRPQ;
#pragma unroll
    for (int i = 0; i < 8; ++i)
      gload16(src + i * 2048 + t * 8, dstb + i * 2048 + wv * 512);
  }
  {
    float py = pos[(size_t)bg * 512 + 2 * t];
    float px = pos[(size_t)bg * 512 + 2 * t + 1];
    float cy = 15.5f - 15.5f * py;
    float cx = 15.5f - 15.5f * px;
    float fy = floorf(cy), fx = floorf(cx);
    sIB[t] = (unsigned)((int)fy * 64 + (int)fx);
    sW2[2 * t] = cy - fy;
    sW2[2 * t + 1] = cx - fx;
  }
  __syncthreads();

  int m0 = qb * 128 + wv * 32;
  short8 qf[2];
  int aq[2];
#pragma unroll
  for (int f = 0; f < 2; ++f) {
    int m = m0 + f * 16 + lrow;
    qf[f] = *(const short8*)(qt + ((size_t)b * HW_ + m) * C_ + h * HC_ + lg * 8);
    aq[f] = (m >> 5) * 64 + (m & 31);
  }
  const ushort_t* kbase = kt + (size_t)b * NS_ * C_ + h * HC_;
  const ushort_t* vbase = vbn + ((size_t)b * C_ + h * HC_) * NS_;
  f32x4 oc[2][2];
#pragma unroll
  for (int f = 0; f < 2; ++f)
#pragma unroll
    for (int ct = 0; ct < 2; ++ct) oc[f][ct] = f32x4{0.f, 0.f, 0.f, 0.f};
  float mrun[2] = {-1e30f, -1e30f}, lrun[2] = {0.f, 0.f};
  ushort_t* sPw = sP[wv];

  for (int c = 0; c < 8; ++c) {
    f32x4 s[2][2];
    __builtin_amdgcn_s_setprio(1);
#pragma unroll
    for (int T = 0; T < 2; ++T) {
      short8 kf = *(const short8*)(kbase + (size_t)((c * 2 + T) * 16 + lrow) * C_ + lg * 8);
#pragma unroll
      for (int f = 0; f < 2; ++f)
        s[f][T] = __builtin_amdgcn_mfma_f32_16x16x32_bf16(kf, qf[f], f32x4{0.f, 0.f, 0.f, 0.f}, 0, 0, 0);
    }
    __builtin_amdgcn_s_setprio(0);
    u32x4 ibT[2];
    f32x4 wA[2], wB[2];
#pragma unroll
    for (int T = 0; T < 2; ++T) {
      int kbase2 = c * 32 + T * 16 + lg * 4;
      ibT[T] = *(const u32x4*)&sIB[kbase2];
      wA[T] = *(const f32x4*)&sW2[2 * kbase2];
      wB[T] = *(const f32x4*)&sW2[2 * kbase2 + 4];
    }
#pragma unroll
    for (int f = 0; f < 2; ++f)
#pragma unroll
      for (int T = 0; T < 2; ++T)
#pragma unroll
        for (int r = 0; r < 4; ++r) {
          int a = aq[f] + (int)ibT[T][r];
          float wy = (r < 2) ? wA[T][(r & 1) * 2] : wB[T][(r & 1) * 2];
          float wx = (r < 2) ? wA[T][(r & 1) * 2 + 1] : wB[T][(r & 1) * 2 + 1];
          uint2 qd = sRPQ[a];
          float b00 = bflo(qd.x), b01 = bfhi(qd.x);
          float b10 = bflo(qd.y), b11 = bfhi(qd.y);
          float r0 = b00 + wx * (b01 - b00);
          float r1 = b10 + wx * (b11 - b10);
          s[f][T][r] = s[f][T][r] * SCALE_ + r0 + wy * (r1 - r0);
        }
#pragma unroll
    for (int f = 0; f < 2; ++f) {
      float mx = s[f][0][0];
#pragma unroll
      for (int T = 0; T < 2; ++T)
#pragma unroll
        for (int r = 0; r < 4; ++r) mx = fmaxf(mx, s[f][T][r]);
      mx = fmaxf(mx, __shfl_xor(mx, 16));
      mx = fmaxf(mx, __shfl_xor(mx, 32));
      if (!__all(mx <= mrun[f] + 8.f)) {  // defer-max: rescale only on growth
        float newm = fmaxf(mrun[f], mx);
        float fac = __expf(mrun[f] - newm);
        mrun[f] = newm;
        lrun[f] *= fac;
#pragma unroll
        for (int ct = 0; ct < 2; ++ct)
#pragma unroll
          for (int r = 0; r < 4; ++r) oc[f][ct][r] *= fac;
      }
      float ps = 0.f;
#pragma unroll
      for (int T = 0; T < 2; ++T)
#pragma unroll
        for (int r = 0; r < 4; ++r) {
          float p = __expf(s[f][T][r] - mrun[f]);
          s[f][T][r] = p;
          ps += p;
        }
      ps += __shfl_xor(ps, 16);
      ps += __shfl_xor(ps, 32);
      lrun[f] += ps;
#pragma unroll
      for (int T = 0; T < 2; ++T) {
        uint2 u;
        u.x = pack2(s[f][T][0], s[f][T][1]);
        u.y = pack2(s[f][T][2], s[f][T][3]);
        *(uint2*)&sPw[(f * 16 + lrow) * 40 + T * 16 + lg * 4] = u;
      }
    }
    short8 pa[2];
#pragma unroll
    for (int f = 0; f < 2; ++f)
      pa[f] = *(const short8*)&sPw[(f * 16 + lrow) * 40 + lg * 8];
    __builtin_amdgcn_s_setprio(1);
#pragma unroll
    for (int ct = 0; ct < 2; ++ct) {
      short8 vf = *(const short8*)(vbase + (size_t)(ct * 16 + lrow) * NS_ + c * 32 + lg * 8);
#pragma unroll
      for (int f = 0; f < 2; ++f)
        oc[f][ct] = __builtin_amdgcn_mfma_f32_16x16x32_bf16(pa[f], vf, oc[f][ct], 0, 0, 0);
    }
    __builtin_amdgcn_s_setprio(0);
  }
#pragma unroll
  for (int f = 0; f < 2; ++f) {
    float inv = 1.f / lrun[f];
    float invq[4];
#pragma unroll
    for (int r = 0; r < 4; ++r) invq[r] = __shfl(inv, lg * 4 + r);
#pragma unroll
    for (int ct = 0; ct < 2; ++ct)
#pragma unroll
      for (int r = 0; r < 4; ++r) {
        int m = m0 + f * 16 + lg * 4 + r;
        aot[((size_t)b * HW_ + m) * C_ + h * HC_ + ct * 16 + lrow] =
            f2bf(oc[f][ct][r] * invq[r]);
      }
  }
}

}  // namespace

extern "C" void kernel_launch(void* const* d_in, const int* in_sizes, int n_in,
                              void* d_out, int out_size, void* d_ws,
                              size_t ws_size, hipStream_t stream) {
  const float* x_in = (const float*)d_in[0];
  const float* lpu_w = (const float*)d_in[1];
  const float* lpu_b = (const float*)d_in[2];
  const float* wq = (const float*)d_in[3];
  const float* bq = (const float*)d_in[4];
  const float* wk = (const float*)d_in[5];
  const float* bk = (const float*)d_in[6];
  const float* wv = (const float*)d_in[7];
  const float* bv = (const float*)d_in[8];
  const float* wo = (const float*)d_in[9];
  const float* bo = (const float*)d_in[10];
  const float* odw = (const float*)d_in[11];
  const float* odb = (const float*)d_in[12];
  const float* olw = (const float*)d_in[13];
  const float* olb = (const float*)d_in[14];
  const float* opw = (const float*)d_in[15];
  const float* rpe = (const float*)d_in[16];
  const float* w1 = (const float*)d_in[17];
  const float* b1 = (const float*)d_in[18];
  const float* mdw = (const float*)d_in[19];
  const float* mdb = (const float*)d_in[20];
  const float* w2 = (const float*)d_in[21];
  const float* b2 = (const float*)d_in[22];
  float* out = (float*)d_out;

  constexpr size_t XSZ = (size_t)B_ * C_ * HW_;
  constexpr size_t SSZ = (size_t)B_ * C_ * NS_;
  constexpr size_t HSZ = (size_t)B_ * D2_ * HW_;

  char* base = (char*)d_ws;
  auto alloc = [&](size_t bytes) {
    char* p = base;
    base += (bytes + 255) & ~(size_t)255;
    return p;
  };
  float* bufX = (float*)alloc(XSZ * 4);
  float* y1 = (float*)alloc(XSZ * 4);
  float* x2 = (float*)alloc(XSZ * 4);
  float* pos = (float*)alloc(48 * 512 * 4);
  ushort_t* qt = (ushort_t*)alloc(XSZ * 2);
  ushort_t* tb1 = (ushort_t*)alloc(XSZ * 2);
  ushort_t* aot = (ushort_t*)alloc(XSZ * 2);
  ushort_t* xst = (ushort_t*)alloc(SSZ * 2);
  ushort_t* ktb = (ushort_t*)alloc(SSZ * 2);
  ushort_t* vbn = (ushort_t*)alloc(SSZ * 2);
  ushort_t* h1b = (ushort_t*)alloc(HSZ * 2);
  ushort_t* h3t = (ushort_t*)alloc(HSZ * 2);
  ushort_t* wb = (ushort_t*)alloc((size_t)3538944 * 2);
  uint2* rpq = (uint2*)alloc((size_t)2 * HEADS_ * 4096 * 8);

  ushort_t* wqb = wb;
  ushort_t* wkb = wb + 294912;
  ushort_t* wvb = wb + 589824;
  ushort_t* wob = wb + 884736;
  ushort_t* w1b = wb + 1179648;
  ushort_t* w2b = wb + 2359296;

  wcvt_rpe<<<13824 + 24, 256, 0, stream>>>(wq, wk, wv, wo, w1, w2, wb, rpe, rpq);

  for (int d = 0; d < 2; ++d) {
    const float* xin = (d == 0) ? x_in : bufX;
    float* xnext = (d == 1) ? out : bufX;
    const ushort_t* wqd = wqb + (size_t)d * 147456;
    const ushort_t* wkd = wkb + (size_t)d * 147456;
    const ushort_t* wvd = wvb + (size_t)d * 147456;
    const ushort_t* wod = wob + (size_t)d * 147456;
    const ushort_t* w1d = w1b + (size_t)d * 589824;
    const ushort_t* w2d = w2b + (size_t)d * 589824;

    dwconv_lpu<<<dim3(32, 12, 8), 256, 0, stream>>>(xin, lpu_w + d * C_ * 9,
                                                    lpu_b + d * C_, y1, tb1);
    gemm128<64, false, false, true, false><<<dim3(16, 3, 8), 256, 0, stream>>>(
        wqd, tb1, bq + d * C_, nullptr, nullptr, qt, C_, C_, HW_);
    offset_kernel<<<192, 256, 0, stream>>>(qt, odw + d * CG_ * 9, odb + d * CG_,
                                           olw + d * CG_, olb + d * CG_,
                                           opw + d * 2 * CG_, pos);
    sample_xst<<<dim3(64, 48), 256, 0, stream>>>(y1, pos, xst);
    gemm_kv<<<dim3(4, 12, 8), 256, 0, stream>>>(wkd, wvd, xst, bk + d * C_,
                                                bv + d * C_, ktb, vbn);
    attn_kernel<<<768, 256, 0, stream>>>(qt, ktb, vbn, pos,
                                         rpq + (size_t)d * HEADS_ * 4096, aot);
    gemm128<64, true, false, true, true><<<dim3(16, 3, 8), 256, 0, stream>>>(
        wod, aot, bo + d * C_, y1, x2, tb1, C_, C_, HW_);
    gemm128<128, false, true, false, false><<<dim3(8, 12, 8), 256, 0, stream>>>(
        w1d, tb1, b1 + d * D2_, nullptr, nullptr, h1b, D2_, C_, HW_);
    dwgelu_t<<<dim3(16, 48, 8), 256, 0, stream>>>(h1b, mdw + d * D2_ * 9,
                                                  mdb + d * D2_, h3t);
    gemm128<64, true, false, false, true><<<dim3(16, 3, 8), 256, 0, stream>>>(
        w2d, h3t, b2 + d * C_, x2, xnext, nullptr, C_, D2_, HW_);
  }
}

// Round 9
// 432.640 us; speedup vs baseline: 4.0293x; 1.0652x over previous
//
#include <hip/hip_runtime.h>
#include <hip/hip_bf16.h>
#include <math.h>

namespace {

constexpr int B_ = 8, C_ = 384, H_ = 32, W_ = 32, HW_ = 1024;
constexpr int HEADS_ = 12, G_ = 6, HC_ = 32, CG_ = 64, NS_ = 256, D2_ = 1536;
constexpr float SCALE_ = 0.17677669529663687f;  // 32^-0.5

using short8 = __attribute__((ext_vector_type(8))) short;
using f32x4 = __attribute__((ext_vector_type(4))) float;
using u32x4 = __attribute__((ext_vector_type(4))) unsigned;
typedef unsigned short ushort_t;

__device__ __forceinline__ float gelu_exact(float x) {
  return 0.5f * x * (1.f + erff(x * 0.70710678118654752f));
}
__device__ __forceinline__ ushort_t f2bf(float f) {
  unsigned u = __float_as_uint(f);
  u = (u + 0x7FFFu + ((u >> 16) & 1u)) >> 16;
  return (ushort_t)u;
}
__device__ __forceinline__ float bf2f(ushort_t s) {
  return __uint_as_float(((unsigned)s) << 16);
}
__device__ __forceinline__ float bflo(unsigned u) { return __uint_as_float(u << 16); }
__device__ __forceinline__ float bfhi(unsigned u) { return __uint_as_float(u & 0xFFFF0000u); }
__device__ __forceinline__ unsigned pack2(float a, float b) {
  return (unsigned)f2bf(a) | ((unsigned)f2bf(b) << 16);
}

typedef __attribute__((address_space(1))) const unsigned int gq_u32;
typedef __attribute__((address_space(3))) unsigned int lq_u32;
__device__ __forceinline__ void gload16(const ushort_t* g, ushort_t* l) {
  __builtin_amdgcn_global_load_lds((gq_u32*)g, (lq_u32*)l, 16, 0, 0);
}

// ---- weight fp32 -> bf16 (+ rpe quad-pack fused as trailing blocks)
__global__ __launch_bounds__(256) void wcvt_rpe(
    const float* __restrict__ s0, const float* __restrict__ s1,
    const float* __restrict__ s2, const float* __restrict__ s3,
    const float* __restrict__ s4, const float* __restrict__ s5,
    ushort_t* __restrict__ dst, const float* __restrict__ rpe,
    uint2* __restrict__ rpq) {
  int blk = blockIdx.x;
  if (blk < 13824) {
    long idx = (long)blk * 256 + threadIdx.x;
    long off = idx;
    const float* s;
    if (off < 294912) s = s0;
    else if ((off -= 294912) < 294912) s = s1;
    else if ((off -= 294912) < 294912) s = s2;
    else if ((off -= 294912) < 294912) s = s3;
    else if ((off -= 294912) < 1179648) s = s4;
    else { off -= 1179648; s = s5; }
    dst[idx] = f2bf(s[off]);
  } else {
    int hb = blk - 13824;  // 24 = 12 heads * 2 depths
    const float* rph = rpe + (size_t)hb * 3969;
    uint2* dq = rpq + (size_t)hb * 4096;
    for (int i = threadIdx.x; i < 4096; i += 256) {
      int y = i >> 6, x = i & 63;
      float v00 = 0.f, v01 = 0.f, v10 = 0.f, v11 = 0.f;
      if (y < 63) {
        if (x < 63) v00 = rph[y * 63 + x];
        if (x < 62) v01 = rph[y * 63 + x + 1];
      }
      if (y < 62) {
        if (x < 63) v10 = rph[(y + 1) * 63 + x];
        if (x < 62) v11 = rph[(y + 1) * 63 + x + 1];
      }
      dq[i] = make_uint2(pack2(v00, v01), pack2(v10, v11));
    }
  }
}

// ---- LPU: y = x + dwconv3x3(x), vectorized 4 px/thread.
__global__ __launch_bounds__(256) void dwconv_lpu(
    const float* __restrict__ x, const float* __restrict__ w,
    const float* __restrict__ bias, float* __restrict__ y,
    ushort_t* __restrict__ yt) {
  __shared__ __align__(16) float tile[32][33];
  int hp = blockIdx.x, c0 = blockIdx.y * 32, b = blockIdx.z;
  int t = threadIdx.x;
  int cl = t >> 3, g4 = t & 7;
  int c = c0 + cl;
  const float* img = x + ((size_t)b * C_ + c) * HW_;
  const float* wc = w + c * 9;
  float o0 = bias[c], o1 = o0, o2 = o0, o3 = o0;
#pragma unroll
  for (int ky = 0; ky < 3; ++ky) {
    int ih = hp + ky - 1;
    if ((unsigned)ih >= 32u) continue;
    const float* row = img + ih * 32 + g4 * 4;
    float4 m = *(const float4*)row;
    float v0 = (g4 > 0) ? row[-1] : 0.f;
    float v5 = (g4 < 7) ? row[4] : 0.f;
    float k0 = wc[ky * 3], k1 = wc[ky * 3 + 1], k2 = wc[ky * 3 + 2];
    o0 = fmaf(k0, v0, fmaf(k1, m.x, fmaf(k2, m.y, o0)));
    o1 = fmaf(k0, m.x, fmaf(k1, m.y, fmaf(k2, m.z, o1)));
    o2 = fmaf(k0, m.y, fmaf(k1, m.z, fmaf(k2, m.w, o2)));
    o3 = fmaf(k0, m.z, fmaf(k1, m.w, fmaf(k2, v5, o3)));
  }
  float4 ctr = *(const float4*)(img + hp * 32 + g4 * 4);
  o0 += ctr.x; o1 += ctr.y; o2 += ctr.z; o3 += ctr.w;
  *(float4*)(y + ((size_t)b * C_ + c) * HW_ + hp * 32 + g4 * 4) =
      make_float4(o0, o1, o2, o3);
  tile[cl][g4 * 4 + 0] = o0;
  tile[cl][g4 * 4 + 1] = o1;
  tile[cl][g4 * 4 + 2] = o2;
  tile[cl][g4 * 4 + 3] = o3;
  __syncthreads();
  int wl = t >> 3, cg = t & 7;
  unsigned p0 = pack2(tile[cg * 4 + 0][wl], tile[cg * 4 + 1][wl]);
  unsigned p1 = pack2(tile[cg * 4 + 2][wl], tile[cg * 4 + 3][wl]);
  unsigned* dst = (unsigned*)(yt + ((size_t)b * HW_ + hp * 32 + wl) * C_ + c0 + cg * 4);
  dst[0] = p0;
  dst[1] = p1;
}

// ---- MLP dw: h3t[b][hw][c] = bf16(gelu(h + dwconv(h)+bias)); 8 px/thread
__global__ __launch_bounds__(256) void dwgelu_t(
    const ushort_t* __restrict__ hin, const float* __restrict__ w,
    const float* __restrict__ bias, ushort_t* __restrict__ ht) {
  __shared__ __align__(16) float tile[2][32][33];
  int hp0 = blockIdx.x * 2, c0 = blockIdx.y * 32, b = blockIdx.z;
  int t = threadIdx.x;
  int cl = t >> 3, rw = (t >> 2) & 1, g8 = t & 3;
  int hp = hp0 + rw;
  int c = c0 + cl;
  const ushort_t* img = hin + ((size_t)b * D2_ + c) * HW_;
  const float* wc = w + c * 9;
  float o[8];
  float bi = bias[c];
#pragma unroll
  for (int j = 0; j < 8; ++j) o[j] = bi;
#pragma unroll
  for (int ky = 0; ky < 3; ++ky) {
    int ih = hp + ky - 1;
    if ((unsigned)ih >= 32u) continue;
    const ushort_t* row = img + ih * 32 + g8 * 8;
    uint4 u = *(const uint4*)row;
    float vv[10];
    vv[0] = (g8 > 0) ? bf2f(row[-1]) : 0.f;
    vv[1] = bflo(u.x); vv[2] = bfhi(u.x); vv[3] = bflo(u.y); vv[4] = bfhi(u.y);
    vv[5] = bflo(u.z); vv[6] = bfhi(u.z); vv[7] = bflo(u.w); vv[8] = bfhi(u.w);
    vv[9] = (g8 < 3) ? bf2f(row[8]) : 0.f;
    float k0 = wc[ky * 3], k1 = wc[ky * 3 + 1], k2 = wc[ky * 3 + 2];
#pragma unroll
    for (int j = 0; j < 8; ++j)
      o[j] = fmaf(k0, vv[j], fmaf(k1, vv[j + 1], fmaf(k2, vv[j + 2], o[j])));
  }
  {
    uint4 u = *(const uint4*)(img + hp * 32 + g8 * 8);
    float cv[8] = {bflo(u.x), bfhi(u.x), bflo(u.y), bfhi(u.y),
                   bflo(u.z), bfhi(u.z), bflo(u.w), bfhi(u.w)};
#pragma unroll
    for (int j = 0; j < 8; ++j) {
      o[j] += cv[j];
      tile[rw][cl][g8 * 8 + j] = gelu_exact(o[j]);
    }
  }
  __syncthreads();
  int wl = t >> 3, cg = t & 7;
#pragma unroll
  for (int rr = 0; rr < 2; ++rr) {
    unsigned p0 = pack2(tile[rr][cg * 4 + 0][wl], tile[rr][cg * 4 + 1][wl]);
    unsigned p1 = pack2(tile[rr][cg * 4 + 2][wl], tile[rr][cg * 4 + 3][wl]);
    unsigned* dst = (unsigned*)(ht + ((size_t)b * HW_ + (hp0 + rr) * 32 + wl) * D2_ + c0 + cg * 4);
    dst[0] = p0;
    dst[1] = p1;
  }
}

// ---- fused K+V projection, 64-tile, reg-prefetch pipeline.
__global__ __launch_bounds__(256) void gemm_kv(
    const ushort_t* __restrict__ Wk, const ushort_t* __restrict__ Wv,
    const ushort_t* __restrict__ Xt, const float* __restrict__ bk,
    const float* __restrict__ bv, ushort_t* __restrict__ ktb,
    ushort_t* __restrict__ vbn) {
  constexpr int K = C_, N = NS_, O = C_;
  struct __align__(16) SMem {
    union {
      struct { char a[8192]; char b[8192]; } st;
      float shuf[64 * 68];
    };
  };
  __shared__ SMem sm;
  int t = threadIdx.x;
  int lane = t & 63, wave = t >> 6;
  int wm = (wave >> 1) * 32, wn = (wave & 1) * 32;
  int bz = blockIdx.z;
  bool isK = blockIdx.y < 6;
  int o0 = (isK ? blockIdx.y : blockIdx.y - 6) * 64;
  int n0 = blockIdx.x * 64;
  const ushort_t* Wb = isK ? Wk : Wv;
  const float* bias = isK ? bk : bv;
  const ushort_t* Ag = Wb + (size_t)o0 * K;
  const ushort_t* Bg = Xt + ((size_t)bz * N + n0) * K;
  int sr = t >> 3, sc = t & 7;
  int swz = ((sc ^ (sr & 7)) << 4);
  f32x4 acc[2][2];
#pragma unroll
  for (int fi = 0; fi < 2; ++fi)
#pragma unroll
    for (int fj = 0; fj < 2; ++fj) acc[fi][fj] = f32x4{0.f, 0.f, 0.f, 0.f};
  int lrow = lane & 15, lk = lane >> 4;
  short8 a0 = *(const short8*)(Ag + (size_t)sr * K + sc * 8);
  short8 a1 = *(const short8*)(Ag + (size_t)(sr + 32) * K + sc * 8);
  short8 b0 = *(const short8*)(Bg + (size_t)sr * K + sc * 8);
  short8 b1 = *(const short8*)(Bg + (size_t)(sr + 32) * K + sc * 8);
  constexpr int NSTEP = K / 64;
#pragma unroll
  for (int s = 0; s < NSTEP; ++s) {
    if (s) __syncthreads();
    *(short8*)(sm.st.a + sr * 128 + swz) = a0;
    *(short8*)(sm.st.a + (sr + 32) * 128 + swz) = a1;
    *(short8*)(sm.st.b + sr * 128 + swz) = b0;
    *(short8*)(sm.st.b + (sr + 32) * 128 + swz) = b1;
    __syncthreads();
    if (s + 1 < NSTEP) {
      int k0 = (s + 1) * 64;
      a0 = *(const short8*)(Ag + (size_t)sr * K + k0 + sc * 8);
      a1 = *(const short8*)(Ag + (size_t)(sr + 32) * K + k0 + sc * 8);
      b0 = *(const short8*)(Bg + (size_t)sr * K + k0 + sc * 8);
      b1 = *(const short8*)(Bg + (size_t)(sr + 32) * K + k0 + sc * 8);
    }
#pragma unroll
    for (int kk = 0; kk < 2; ++kk) {
      short8 af[2], bfr[2];
#pragma unroll
      for (int fi = 0; fi < 2; ++fi) {
        int row = wm + fi * 16 + lrow;
        af[fi] = *(const short8*)(sm.st.a + row * 128 + (((kk * 4 + lk) ^ (row & 7)) << 4));
      }
#pragma unroll
      for (int fj = 0; fj < 2; ++fj) {
        int row = wn + fj * 16 + lrow;
        bfr[fj] = *(const short8*)(sm.st.b + row * 128 + (((kk * 4 + lk) ^ (row & 7)) << 4));
      }
#pragma unroll
      for (int fi = 0; fi < 2; ++fi)
#pragma unroll
        for (int fj = 0; fj < 2; ++fj)
          acc[fi][fj] = __builtin_amdgcn_mfma_f32_16x16x32_bf16(af[fi], bfr[fj], acc[fi][fj], 0, 0, 0);
    }
  }
  __syncthreads();
#pragma unroll
  for (int fi = 0; fi < 2; ++fi) {
#pragma unroll
    for (int r = 0; r < 4; ++r) {
      int ol = wm + fi * 16 + lk * 4 + r;
      float bi = bias[o0 + ol];
#pragma unroll
      for (int fj = 0; fj < 2; ++fj) {
        int nl = wn + fj * 16 + lrow;
        sm.shuf[ol * 68 + nl] = acc[fi][fj][r] + bi;
      }
    }
  }
  __syncthreads();
  if (isK) {
    int nl = t >> 2, og = (t & 3) * 16;
    unsigned pk[8];
#pragma unroll
    for (int i = 0; i < 8; ++i)
      pk[i] = pack2(sm.shuf[(og + 2 * i) * 68 + nl], sm.shuf[(og + 2 * i + 1) * 68 + nl]);
    unsigned* dst = (unsigned*)(ktb + ((size_t)bz * N + (n0 + nl)) * O + o0 + og);
    *(uint4*)(dst) = make_uint4(pk[0], pk[1], pk[2], pk[3]);
    *(uint4*)(dst + 4) = make_uint4(pk[4], pk[5], pk[6], pk[7]);
  } else {
    int ol = t >> 2, ng = (t & 3) * 16;
    unsigned pk[8];
#pragma unroll
    for (int i = 0; i < 8; ++i)
      pk[i] = pack2(sm.shuf[ol * 68 + ng + 2 * i], sm.shuf[ol * 68 + ng + 2 * i + 1]);
    unsigned* dst = (unsigned*)(vbn + ((size_t)bz * O + (o0 + ol)) * N + n0 + ng);
    *(uint4*)(dst) = make_uint4(pk[0], pk[1], pk[2], pk[3]);
    *(uint4*)(dst + 4) = make_uint4(pk[4], pk[5], pk[6], pk[7]);
  }
}

// ---- 128xBN x64 bf16 GEMM, double-buffered global_load_lds + XOR swizzle.
// LDS dest stays linear (rule #21); the k-chunk is pre-swizzled on the GLOBAL
// source per lane (chunk = (l&7) ^ (row&7)) and the same XOR is applied on the
// ds_read side, so MFMA fragment reads are bank-conflict-free (T2/m173).
// BN=128: 4 waves as 2x2 of 64x64.  BN=64: 4 waves as 4x1 of 32x64.
template <int BN, bool F32, bool B16N, bool B16T, bool RES>
__global__ __launch_bounds__(256) void gemm128(
    const ushort_t* __restrict__ Wb, const ushort_t* __restrict__ Xt,
    const float* __restrict__ bias, const float* __restrict__ resid,
    float* __restrict__ Y, ushort_t* __restrict__ Yb, int O, int K, int N) {
  constexpr int MFW = (BN == 128) ? 4 : 2;
  __shared__ __align__(16) ushort_t sA[2][128 * 64];
  __shared__ __align__(16) ushort_t sB[2][BN * 64];
  int t = threadIdx.x;
  int l = t & 63, w = t >> 6;
  int o0 = blockIdx.y * 128, n0 = blockIdx.x * BN, bz = blockIdx.z;
  const ushort_t* Ag = Wb + (size_t)o0 * K;
  const ushort_t* Bg = Xt + ((size_t)bz * N + n0) * K;
  int lr8 = l >> 3;
  int scol = (((l & 7) ^ (lr8 & 7)) * 8);  // pre-swizzled global k-chunk
  int lrow = l & 15, lg = l >> 4;
  int wm = (BN == 128) ? (w >> 1) * 64 : w * 32;
  int wn = (BN == 128) ? (w & 1) * 64 : 0;
  f32x4 acc[MFW][4];
#pragma unroll
  for (int fi = 0; fi < MFW; ++fi)
#pragma unroll
    for (int fj = 0; fj < 4; ++fj) acc[fi][fj] = f32x4{0.f, 0.f, 0.f, 0.f};
  auto stage = [&](int buf, int k0) {
#pragma unroll
    for (int i = 0; i < 4; ++i)
      gload16(Ag + (size_t)(w * 32 + i * 8 + lr8) * K + k0 + scol,
              sA[buf] + (w * 32 + i * 8) * 64);
    if constexpr (BN == 128) {
#pragma unroll
      for (int i = 0; i < 4; ++i)
        gload16(Bg + (size_t)(w * 32 + i * 8 + lr8) * K + k0 + scol,
                sB[buf] + (w * 32 + i * 8) * 64);
    } else {
      // rows w*16 + i*8 + lr8; row&7 == lr8&7 so the same scol applies
#pragma unroll
      for (int i = 0; i < 2; ++i)
        gload16(Bg + (size_t)(w * 16 + i * 8 + lr8) * K + k0 + scol,
                sB[buf] + (w * 16 + i * 8) * 64);
    }
  };
  stage(0, 0);
  __syncthreads();
  int nstep = K >> 6;
  for (int s = 0; s < nstep; ++s) {
    int cur = s & 1;
    if (s + 1 < nstep) stage(cur ^ 1, (s + 1) * 64);
#pragma unroll
    for (int kk = 0; kk < 2; ++kk) {
      short8 af[MFW], bfr[4];
#pragma unroll
      for (int fi = 0; fi < MFW; ++fi) {
        int row = wm + fi * 16 + lrow;
        af[fi] = *(const short8*)(sA[cur] + row * 64 + (((kk * 4 + lg) ^ (row & 7)) << 3));
      }
#pragma unroll
      for (int fj = 0; fj < 4; ++fj) {
        int row = wn + fj * 16 + lrow;
        bfr[fj] = *(const short8*)(sB[cur] + row * 64 + (((kk * 4 + lg) ^ (row & 7)) << 3));
      }
#pragma unroll
      for (int fi = 0; fi < MFW; ++fi)
#pragma unroll
        for (int fj = 0; fj < 4; ++fj)
          acc[fi][fj] = __builtin_amdgcn_mfma_f32_16x16x32_bf16(af[fi], bfr[fj], acc[fi][fj], 0, 0, 0);
    }
    __syncthreads();
  }
#pragma unroll
  for (int fi = 0; fi < MFW; ++fi) {
    int ob = wm + fi * 16 + lg * 4;
    float bi[4];
#pragma unroll
    for (int r = 0; r < 4; ++r) bi[r] = bias[o0 + ob + r];
#pragma unroll
    for (int fj = 0; fj < 4; ++fj) {
      int n = n0 + wn + fj * 16 + lrow;
      float v[4];
#pragma unroll
      for (int r = 0; r < 4; ++r) {
        v[r] = acc[fi][fj][r] + bi[r];
        if (RES) v[r] += resid[((size_t)bz * O + ob + r + o0) * N + n];
        if (F32) Y[((size_t)bz * O + ob + r + o0) * N + n] = v[r];
        if (B16N) Yb[((size_t)bz * O + ob + r + o0) * N + n] = f2bf(v[r]);
      }
      if (B16T) {
        uint2 u;
        u.x = pack2(v[0], v[1]);
        u.y = pack2(v[2], v[3]);
        *(uint2*)&Yb[((size_t)bz * N + n) * O + o0 + ob] = u;
      }
    }
  }
}

// ---- offset branch: 4 threads per position (16 ch each), quad shfl-reduce LN.
__global__ __launch_bounds__(256) void offset_kernel(
    const ushort_t* __restrict__ qt, const float* __restrict__ odw,
    const float* __restrict__ odb, const float* __restrict__ olw,
    const float* __restrict__ olb, const float* __restrict__ opw,
    float* __restrict__ pos) {
  int blk = blockIdx.x;
  int bg = blk >> 2, pb = blk & 3;
  int b = bg / G_, g = bg % G_;
  int t = threadIdx.x;
  int p = pb * 64 + (t >> 2);
  int q = t & 3;
  int c0 = q * 16;
  int hk = p >> 4, wk = p & 15;
  const ushort_t* qb = qt + (size_t)b * HW_ * C_ + g * CG_ + c0;
  float sv[16];
#pragma unroll
  for (int j = 0; j < 16; ++j) sv[j] = odb[c0 + j];
#pragma unroll
  for (int ky = 0; ky < 3; ++ky) {
    int ih = 2 * hk + ky - 1;
    if ((unsigned)ih >= 32u) continue;
#pragma unroll
    for (int kx = 0; kx < 3; ++kx) {
      int iw = 2 * wk + kx - 1;
      if ((unsigned)iw >= 32u) continue;
      const ushort_t* qp = qb + (size_t)(ih * 32 + iw) * C_;
      uint4 u0 = *(const uint4*)qp;
      uint4 u1 = *(const uint4*)(qp + 8);
      float vv[16] = {bflo(u0.x), bfhi(u0.x), bflo(u0.y), bfhi(u0.y),
                      bflo(u0.z), bfhi(u0.z), bflo(u0.w), bfhi(u0.w),
                      bflo(u1.x), bfhi(u1.x), bflo(u1.y), bfhi(u1.y),
                      bflo(u1.z), bfhi(u1.z), bflo(u1.w), bfhi(u1.w)};
      int tap = ky * 3 + kx;
#pragma unroll
      for (int j = 0; j < 16; ++j)
        sv[j] = fmaf(odw[(c0 + j) * 9 + tap], vv[j], sv[j]);
    }
  }
  float s1 = 0.f;
#pragma unroll
  for (int j = 0; j < 16; ++j) s1 += sv[j];
  s1 += __shfl_xor(s1, 1);
  s1 += __shfl_xor(s1, 2);
  float mu = s1 * (1.f / CG_);
  float vs = 0.f;
#pragma unroll
  for (int j = 0; j < 16; ++j) {
    float d = sv[j] - mu;
    vs = fmaf(d, d, vs);
  }
  vs += __shfl_xor(vs, 1);
  vs += __shfl_xor(vs, 2);
  float rs = rsqrtf(vs * (1.f / CG_) + 1e-5f);
  float dy = 0.f, dx = 0.f;
#pragma unroll
  for (int j = 0; j < 16; ++j) {
    int c = c0 + j;
    float tv = (sv[j] - mu) * rs * olw[c] + olb[c];
    float ge = gelu_exact(tv);
    dy = fmaf(opw[c], ge, dy);
    dx = fmaf(opw[CG_ + c], ge, dx);
  }
  dy += __shfl_xor(dy, 1);
  dy += __shfl_xor(dy, 2);
  dx += __shfl_xor(dx, 1);
  dx += __shfl_xor(dx, 2);
  if (q == 0) {
    float ry = (hk + 0.5f) * (2.f / 15.f) - 1.f;
    float rx = (wk + 0.5f) * (2.f / 15.f) - 1.f;
    pos[(size_t)bg * 512 + p * 2 + 0] = fminf(fmaxf(dy + ry, -1.f), 1.f);
    pos[(size_t)bg * 512 + p * 2 + 1] = fminf(fmaxf(dx + rx, -1.f), 1.f);
  }
}

// ---- fused deformable sampling + transpose: y1 fp32 -> xst bf16 [b][n][C]
__global__ __launch_bounds__(256) void sample_xst(
    const float* __restrict__ y1, const float* __restrict__ pos,
    ushort_t* __restrict__ xst) {
  int bg = blockIdx.y;
  int b = bg / G_, g = bg % G_;
  int t = threadIdx.x;
  int cg = t & 63, nl = t >> 6;
  int n = blockIdx.x * 4 + nl;
  float py = pos[(size_t)bg * 512 + 2 * n];
  float px = pos[(size_t)bg * 512 + 2 * n + 1];
  float gx = (px + 1.f) * 15.5f, gy = (py + 1.f) * 15.5f;
  float fx = floorf(gx), fy = floorf(gy);
  float wx = gx - fx, wy = gy - fy;
  int x0 = min(max((int)fx, 0), 31), y0 = min(max((int)fy, 0), 31);
  int x1 = min(x0 + 1, 31), y1i = min(y0 + 1, 31);
  const float* img = y1 + ((size_t)b * C_ + g * CG_ + cg) * HW_;
  float v00 = img[y0 * 32 + x0], v01 = img[y0 * 32 + x1];
  float v10 = img[y1i * 32 + x0], v11 = img[y1i * 32 + x1];
  float v = v00 * (1.f - wx) * (1.f - wy) + v01 * wx * (1.f - wy) +
            v10 * (1.f - wx) * wy + v11 * wx * wy;
  xst[((size_t)b * NS_ + n) * C_ + g * CG_ + cg] = f2bf(v);
}

// ---- MFMA flash attention; quad rpe table; defer-max (THR=8).
__global__ __launch_bounds__(256) void attn_kernel(
    const ushort_t* __restrict__ qt, const ushort_t* __restrict__ kt,
    const ushort_t* __restrict__ vbn, const float* __restrict__ pos,
    const uint2* __restrict__ rpq, ushort_t* __restrict__ aot) {
  __shared__ __align__(16) uint2 sRPQ[4096];
  __shared__ __align__(16) ushort_t sP[4][32 * 40];
  __shared__ unsigned sIB[256];
  __shared__ float sW2[512];
  int bid = blockIdx.x;
  int swzb = (bid & 7) * 96 + (bid >> 3);
  int qb = swzb & 7;
  int grp = swzb >> 3;
  int h = grp % HEADS_;
  int b = grp / HEADS_;
  int t = threadIdx.x;
  int l = t & 63, wv = t >> 6;
  int lrow = l & 15, lg = l >> 4;
  int bg = b * G_ + (h >> 1);
  {
    const ushort_t* src = (const ushort_t*)(rpq + (size_t)h * 4096);
    ushort_t* dstb = (ushort_t*)sRPQ;
#pragma unroll
    for (int i = 0; i < 8; ++i)
      gload16(src + i * 2048 + t * 8, dstb + i * 2048 + wv * 512);
  }
  {
    float py = pos[(size_t)bg * 512 + 2 * t];
    float px = pos[(size_t)bg * 512 + 2 * t + 1];
    float cy = 15.5f - 15.5f * py;
    float cx = 15.5f - 15.5f * px;
    float fy = floorf(cy), fx = floorf(cx);
    sIB[t] = (unsigned)((int)fy * 64 + (int)fx);
    sW2[2 * t] = cy - fy;
    sW2[2 * t + 1] = cx - fx;
  }
  __syncthreads();

  int m0 = qb * 128 + wv * 32;
  short8 qf[2];
  int aq[2];
#pragma unroll
  for (int f = 0; f < 2; ++f) {
    int m = m0 + f * 16 + lrow;
    qf[f] = *(const short8*)(qt + ((size_t)b * HW_ + m) * C_ + h * HC_ + lg * 8);
    aq[f] = (m >> 5) * 64 + (m & 31);
  }
  const ushort_t* kbase = kt + (size_t)b * NS_ * C_ + h * HC_;
  const ushort_t* vbase = vbn + ((size_t)b * C_ + h * HC_) * NS_;
  f32x4 oc[2][2];
#pragma unroll
  for (int f = 0; f < 2; ++f)
#pragma unroll
    for (int ct = 0; ct < 2; ++ct) oc[f][ct] = f32x4{0.f, 0.f, 0.f, 0.f};
  float mrun[2] = {-1e30f, -1e30f}, lrun[2] = {0.f, 0.f};
  ushort_t* sPw = sP[wv];

  for (int c = 0; c < 8; ++c) {
    f32x4 s[2][2];
    __builtin_amdgcn_s_setprio(1);
#pragma unroll
    for (int T = 0; T < 2; ++T) {
      short8 kf = *(const short8*)(kbase + (size_t)((c * 2 + T) * 16 + lrow) * C_ + lg * 8);
#pragma unroll
      for (int f = 0; f < 2; ++f)
        s[f][T] = __builtin_amdgcn_mfma_f32_16x16x32_bf16(kf, qf[f], f32x4{0.f, 0.f, 0.f, 0.f}, 0, 0, 0);
    }
    __builtin_amdgcn_s_setprio(0);
    u32x4 ibT[2];
    f32x4 wA[2], wB[2];
#pragma unroll
    for (int T = 0; T < 2; ++T) {
      int kbase2 = c * 32 + T * 16 + lg * 4;
      ibT[T] = *(const u32x4*)&sIB[kbase2];
      wA[T] = *(const f32x4*)&sW2[2 * kbase2];
      wB[T] = *(const f32x4*)&sW2[2 * kbase2 + 4];
    }
#pragma unroll
    for (int f = 0; f < 2; ++f)
#pragma unroll
      for (int T = 0; T < 2; ++T)
#pragma unroll
        for (int r = 0; r < 4; ++r) {
          int a = aq[f] + (int)ibT[T][r];
          float wy = (r < 2) ? wA[T][(r & 1) * 2] : wB[T][(r & 1) * 2];
          float wx = (r < 2) ? wA[T][(r & 1) * 2 + 1] : wB[T][(r & 1) * 2 + 1];
          uint2 qd = sRPQ[a];
          float b00 = bflo(qd.x), b01 = bfhi(qd.x);
          float b10 = bflo(qd.y), b11 = bfhi(qd.y);
          float r0 = b00 + wx * (b01 - b00);
          float r1 = b10 + wx * (b11 - b10);
          s[f][T][r] = s[f][T][r] * SCALE_ + r0 + wy * (r1 - r0);
        }
#pragma unroll
    for (int f = 0; f < 2; ++f) {
      float mx = s[f][0][0];
#pragma unroll
      for (int T = 0; T < 2; ++T)
#pragma unroll
        for (int r = 0; r < 4; ++r) mx = fmaxf(mx, s[f][T][r]);
      mx = fmaxf(mx, __shfl_xor(mx, 16));
      mx = fmaxf(mx, __shfl_xor(mx, 32));
      if (!__all(mx <= mrun[f] + 8.f)) {  // defer-max: rescale only on growth
        float newm = fmaxf(mrun[f], mx);
        float fac = __expf(mrun[f] - newm);
        mrun[f] = newm;
        lrun[f] *= fac;
#pragma unroll
        for (int ct = 0; ct < 2; ++ct)
#pragma unroll
          for (int r = 0; r < 4; ++r) oc[f][ct][r] *= fac;
      }
      float ps = 0.f;
#pragma unroll
      for (int T = 0; T < 2; ++T)
#pragma unroll
        for (int r = 0; r < 4; ++r) {
          float p = __expf(s[f][T][r] - mrun[f]);
          s[f][T][r] = p;
          ps += p;
        }
      ps += __shfl_xor(ps, 16);
      ps += __shfl_xor(ps, 32);
      lrun[f] += ps;
#pragma unroll
      for (int T = 0; T < 2; ++T) {
        uint2 u;
        u.x = pack2(s[f][T][0], s[f][T][1]);
        u.y = pack2(s[f][T][2], s[f][T][3]);
        *(uint2*)&sPw[(f * 16 + lrow) * 40 + T * 16 + lg * 4] = u;
      }
    }
    short8 pa[2];
#pragma unroll
    for (int f = 0; f < 2; ++f)
      pa[f] = *(const short8*)&sPw[(f * 16 + lrow) * 40 + lg * 8];
    __builtin_amdgcn_s_setprio(1);
#pragma unroll
    for (int ct = 0; ct < 2; ++ct) {
      short8 vf = *(const short8*)(vbase + (size_t)(ct * 16 + lrow) * NS_ + c * 32 + lg * 8);
#pragma unroll
      for (int f = 0; f < 2; ++f)
        oc[f][ct] = __builtin_amdgcn_mfma_f32_16x16x32_bf16(pa[f], vf, oc[f][ct], 0, 0, 0);
    }
    __builtin_amdgcn_s_setprio(0);
  }
#pragma unroll
  for (int f = 0; f < 2; ++f) {
    float inv = 1.f / lrun[f];
    float invq[4];
#pragma unroll
    for (int r = 0; r < 4; ++r) invq[r] = __shfl(inv, lg * 4 + r);
#pragma unroll
    for (int ct = 0; ct < 2; ++ct)
#pragma unroll
      for (int r = 0; r < 4; ++r) {
        int m = m0 + f * 16 + lg * 4 + r;
        aot[((size_t)b * HW_ + m) * C_ + h * HC_ + ct * 16 + lrow] =
            f2bf(oc[f][ct][r] * invq[r]);
      }
  }
}

}  // namespace

extern "C" void kernel_launch(void* const* d_in, const int* in_sizes, int n_in,
                              void* d_out, int out_size, void* d_ws,
                              size_t ws_size, hipStream_t stream) {
  const float* x_in = (const float*)d_in[0];
  const float* lpu_w = (const float*)d_in[1];
  const float* lpu_b = (const float*)d_in[2];
  const float* wq = (const float*)d_in[3];
  const float* bq = (const float*)d_in[4];
  const float* wk = (const float*)d_in[5];
  const float* bk = (const float*)d_in[6];
  const float* wv = (const float*)d_in[7];
  const float* bv = (const float*)d_in[8];
  const float* wo = (const float*)d_in[9];
  const float* bo = (const float*)d_in[10];
  const float* odw = (const float*)d_in[11];
  const float* odb = (const float*)d_in[12];
  const float* olw = (const float*)d_in[13];
  const float* olb = (const float*)d_in[14];
  const float* opw = (const float*)d_in[15];
  const float* rpe = (const float*)d_in[16];
  const float* w1 = (const float*)d_in[17];
  const float* b1 = (const float*)d_in[18];
  const float* mdw = (const float*)d_in[19];
  const float* mdb = (const float*)d_in[20];
  const float* w2 = (const float*)d_in[21];
  const float* b2 = (const float*)d_in[22];
  float* out = (float*)d_out;

  constexpr size_t XSZ = (size_t)B_ * C_ * HW_;
  constexpr size_t SSZ = (size_t)B_ * C_ * NS_;
  constexpr size_t HSZ = (size_t)B_ * D2_ * HW_;

  char* base = (char*)d_ws;
  auto alloc = [&](size_t bytes) {
    char* p = base;
    base += (bytes + 255) & ~(size_t)255;
    return p;
  };
  float* bufX = (float*)alloc(XSZ * 4);
  float* y1 = (float*)alloc(XSZ * 4);
  float* x2 = (float*)alloc(XSZ * 4);
  float* pos = (float*)alloc(48 * 512 * 4);
  ushort_t* qt = (ushort_t*)alloc(XSZ * 2);
  ushort_t* tb1 = (ushort_t*)alloc(XSZ * 2);
  ushort_t* aot = (ushort_t*)alloc(XSZ * 2);
  ushort_t* xst = (ushort_t*)alloc(SSZ * 2);
  ushort_t* ktb = (ushort_t*)alloc(SSZ * 2);
  ushort_t* vbn = (ushort_t*)alloc(SSZ * 2);
  ushort_t* h1b = (ushort_t*)alloc(HSZ * 2);
  ushort_t* h3t = (ushort_t*)alloc(HSZ * 2);
  ushort_t* wb = (ushort_t*)alloc((size_t)3538944 * 2);
  uint2* rpq = (uint2*)alloc((size_t)2 * HEADS_ * 4096 * 8);

  ushort_t* wqb = wb;
  ushort_t* wkb = wb + 294912;
  ushort_t* wvb = wb + 589824;
  ushort_t* wob = wb + 884736;
  ushort_t* w1b = wb + 1179648;
  ushort_t* w2b = wb + 2359296;

  wcvt_rpe<<<13824 + 24, 256, 0, stream>>>(wq, wk, wv, wo, w1, w2, wb, rpe, rpq);

  for (int d = 0; d < 2; ++d) {
    const float* xin = (d == 0) ? x_in : bufX;
    float* xnext = (d == 1) ? out : bufX;
    const ushort_t* wqd = wqb + (size_t)d * 147456;
    const ushort_t* wkd = wkb + (size_t)d * 147456;
    const ushort_t* wvd = wvb + (size_t)d * 147456;
    const ushort_t* wod = wob + (size_t)d * 147456;
    const ushort_t* w1d = w1b + (size_t)d * 589824;
    const ushort_t* w2d = w2b + (size_t)d * 589824;

    dwconv_lpu<<<dim3(32, 12, 8), 256, 0, stream>>>(xin, lpu_w + d * C_ * 9,
                                                    lpu_b + d * C_, y1, tb1);
    gemm128<64, false, false, true, false><<<dim3(16, 3, 8), 256, 0, stream>>>(
        wqd, tb1, bq + d * C_, nullptr, nullptr, qt, C_, C_, HW_);
    offset_kernel<<<192, 256, 0, stream>>>(qt, odw + d * CG_ * 9, odb + d * CG_,
                                           olw + d * CG_, olb + d * CG_,
                                           opw + d * 2 * CG_, pos);
    sample_xst<<<dim3(64, 48), 256, 0, stream>>>(y1, pos, xst);
    gemm_kv<<<dim3(4, 12, 8), 256, 0, stream>>>(wkd, wvd, xst, bk + d * C_,
                                                bv + d * C_, ktb, vbn);
    attn_kernel<<<768, 256, 0, stream>>>(qt, ktb, vbn, pos,
                                         rpq + (size_t)d * HEADS_ * 4096, aot);
    gemm128<64, true, false, true, true><<<dim3(16, 3, 8), 256, 0, stream>>>(
        wod, aot, bo + d * C_, y1, x2, tb1, C_, C_, HW_);
    gemm128<128, false, true, false, false><<<dim3(8, 12, 8), 256, 0, stream>>>(
        w1d, tb1, b1 + d * D2_, nullptr, nullptr, h1b, D2_, C_, HW_);
    dwgelu_t<<<dim3(16, 48, 8), 256, 0, stream>>>(h1b, mdw + d * D2_ * 9,
                                                  mdb + d * D2_, h3t);
    gemm128<64, true, false, false, true><<<dim3(16, 3, 8), 256, 0, stream>>>(
        w2d, h3t, b2 + d * C_, x2, xnext, nullptr, C_, D2_, HW_);
  }
}

// Round 11
// 415.468 us; speedup vs baseline: 4.1958x; 1.0413x over previous
//
#include <hip/hip_runtime.h>
#include <hip/hip_bf16.h>
#include <math.h>

namespace {

constexpr int B_ = 8, C_ = 384, H_ = 32, W_ = 32, HW_ = 1024;
constexpr int HEADS_ = 12, G_ = 6, HC_ = 32, CG_ = 64, NS_ = 256, D2_ = 1536;
constexpr float SCALE_ = 0.17677669529663687f;  // 32^-0.5

using short8 = __attribute__((ext_vector_type(8))) short;
using f32x4 = __attribute__((ext_vector_type(4))) float;
using u32x4 = __attribute__((ext_vector_type(4))) unsigned;
typedef unsigned short ushort_t;

__device__ __forceinline__ float gelu_exact(float x) {
  return 0.5f * x * (1.f + erff(x * 0.70710678118654752f));
}
__device__ __forceinline__ ushort_t f2bf(float f) {
  unsigned u = __float_as_uint(f);
  u = (u + 0x7FFFu + ((u >> 16) & 1u)) >> 16;
  return (ushort_t)u;
}
__device__ __forceinline__ float bf2f(ushort_t s) {
  return __uint_as_float(((unsigned)s) << 16);
}
__device__ __forceinline__ float bflo(unsigned u) { return __uint_as_float(u << 16); }
__device__ __forceinline__ float bfhi(unsigned u) { return __uint_as_float(u & 0xFFFF0000u); }
__device__ __forceinline__ unsigned pack2(float a, float b) {
  return (unsigned)f2bf(a) | ((unsigned)f2bf(b) << 16);
}

typedef __attribute__((address_space(1))) const unsigned int gq_u32;
typedef __attribute__((address_space(3))) unsigned int lq_u32;
__device__ __forceinline__ void gload16(const ushort_t* g, ushort_t* l) {
  __builtin_amdgcn_global_load_lds((gq_u32*)g, (lq_u32*)l, 16, 0, 0);
}

// ---- weight fp32 -> bf16 (+ rpe row-pair pack fused as trailing blocks)
// rp2[d][h][y*64+x] = pack2(v(y,x), v(y,x+1)), zero-padded 64x64.
__global__ __launch_bounds__(256) void wcvt_rpe(
    const float* __restrict__ s0, const float* __restrict__ s1,
    const float* __restrict__ s2, const float* __restrict__ s3,
    const float* __restrict__ s4, const float* __restrict__ s5,
    ushort_t* __restrict__ dst, const float* __restrict__ rpe,
    unsigned* __restrict__ rp2) {
  int blk = blockIdx.x;
  if (blk < 13824) {
    long idx = (long)blk * 256 + threadIdx.x;
    long off = idx;
    const float* s;
    if (off < 294912) s = s0;
    else if ((off -= 294912) < 294912) s = s1;
    else if ((off -= 294912) < 294912) s = s2;
    else if ((off -= 294912) < 294912) s = s3;
    else if ((off -= 294912) < 1179648) s = s4;
    else { off -= 1179648; s = s5; }
    dst[idx] = f2bf(s[off]);
  } else {
    int hb = blk - 13824;  // 24 = 12 heads * 2 depths
    const float* rph = rpe + (size_t)hb * 3969;
    unsigned* dq = rp2 + (size_t)hb * 4096;
    for (int i = threadIdx.x; i < 4096; i += 256) {
      int y = i >> 6, x = i & 63;
      float v0 = 0.f, v1 = 0.f;
      if (y < 63) {
        if (x < 63) v0 = rph[y * 63 + x];
        if (x < 62) v1 = rph[y * 63 + x + 1];
      }
      dq[i] = pack2(v0, v1);
    }
  }
}

// ---- LPU: yb = bf16(x + dwconv3x3(x)) [b][c][hw]; yt = bf16T [b][hw][c].
// Input fp32 (depth 0) or bf16 [b][c][hw] (depth 1).
template <bool INF32>
__global__ __launch_bounds__(256) void dwconv_lpu(
    const void* __restrict__ xin, const float* __restrict__ w,
    const float* __restrict__ bias, ushort_t* __restrict__ yb,
    ushort_t* __restrict__ yt) {
  __shared__ __align__(16) float tile[32][33];
  int hp = blockIdx.x, c0 = blockIdx.y * 32, b = blockIdx.z;
  int t = threadIdx.x;
  int cl = t >> 3, g4 = t & 7;
  int c = c0 + cl;
  const float* wc = w + c * 9;
  float o0 = bias[c], o1 = o0, o2 = o0, o3 = o0;
  float m0, m1, m2, m3;
#pragma unroll
  for (int ky = 0; ky < 3; ++ky) {
    int ih = hp + ky - 1;
    if ((unsigned)ih >= 32u) continue;
    float r0, r1, r2, r3, v0, v5;
    if (INF32) {
      const float* img = (const float*)xin + ((size_t)b * C_ + c) * HW_;
      const float* row = img + ih * 32 + g4 * 4;
      float4 m = *(const float4*)row;
      r0 = m.x; r1 = m.y; r2 = m.z; r3 = m.w;
      v0 = (g4 > 0) ? row[-1] : 0.f;
      v5 = (g4 < 7) ? row[4] : 0.f;
    } else {
      const ushort_t* img = (const ushort_t*)xin + ((size_t)b * C_ + c) * HW_;
      const ushort_t* row = img + ih * 32 + g4 * 4;
      uint2 u = *(const uint2*)row;
      r0 = bflo(u.x); r1 = bfhi(u.x); r2 = bflo(u.y); r3 = bfhi(u.y);
      v0 = (g4 > 0) ? bf2f(row[-1]) : 0.f;
      v5 = (g4 < 7) ? bf2f(row[4]) : 0.f;
    }
    float k0 = wc[ky * 3], k1 = wc[ky * 3 + 1], k2 = wc[ky * 3 + 2];
    o0 = fmaf(k0, v0, fmaf(k1, r0, fmaf(k2, r1, o0)));
    o1 = fmaf(k0, r0, fmaf(k1, r1, fmaf(k2, r2, o1)));
    o2 = fmaf(k0, r1, fmaf(k1, r2, fmaf(k2, r3, o2)));
    o3 = fmaf(k0, r2, fmaf(k1, r3, fmaf(k2, v5, o3)));
    if (ky == 1) { m0 = r0; m1 = r1; m2 = r2; m3 = r3; }
  }
  // center row (ky==1, ih==hp) always valid
  o0 += m0; o1 += m1; o2 += m2; o3 += m3;
  uint2 pk;
  pk.x = pack2(o0, o1);
  pk.y = pack2(o2, o3);
  *(uint2*)(yb + ((size_t)b * C_ + c) * HW_ + hp * 32 + g4 * 4) = pk;
  tile[cl][g4 * 4 + 0] = o0;
  tile[cl][g4 * 4 + 1] = o1;
  tile[cl][g4 * 4 + 2] = o2;
  tile[cl][g4 * 4 + 3] = o3;
  __syncthreads();
  int wl = t >> 3, cg = t & 7;
  unsigned p0 = pack2(tile[cg * 4 + 0][wl], tile[cg * 4 + 1][wl]);
  unsigned p1 = pack2(tile[cg * 4 + 2][wl], tile[cg * 4 + 3][wl]);
  unsigned* dst = (unsigned*)(yt + ((size_t)b * HW_ + hp * 32 + wl) * C_ + c0 + cg * 4);
  dst[0] = p0;
  dst[1] = p1;
}

// ---- MLP dw: h3t[b][hw][c] = bf16(gelu(h + dwconv(h)+bias)); 8 px/thread
__global__ __launch_bounds__(256) void dwgelu_t(
    const ushort_t* __restrict__ hin, const float* __restrict__ w,
    const float* __restrict__ bias, ushort_t* __restrict__ ht) {
  __shared__ __align__(16) float tile[2][32][33];
  int hp0 = blockIdx.x * 2, c0 = blockIdx.y * 32, b = blockIdx.z;
  int t = threadIdx.x;
  int cl = t >> 3, rw = (t >> 2) & 1, g8 = t & 3;
  int hp = hp0 + rw;
  int c = c0 + cl;
  const ushort_t* img = hin + ((size_t)b * D2_ + c) * HW_;
  const float* wc = w + c * 9;
  float o[8];
  float bi = bias[c];
#pragma unroll
  for (int j = 0; j < 8; ++j) o[j] = bi;
#pragma unroll
  for (int ky = 0; ky < 3; ++ky) {
    int ih = hp + ky - 1;
    if ((unsigned)ih >= 32u) continue;
    const ushort_t* row = img + ih * 32 + g8 * 8;
    uint4 u = *(const uint4*)row;
    float vv[10];
    vv[0] = (g8 > 0) ? bf2f(row[-1]) : 0.f;
    vv[1] = bflo(u.x); vv[2] = bfhi(u.x); vv[3] = bflo(u.y); vv[4] = bfhi(u.y);
    vv[5] = bflo(u.z); vv[6] = bfhi(u.z); vv[7] = bflo(u.w); vv[8] = bfhi(u.w);
    vv[9] = (g8 < 3) ? bf2f(row[8]) : 0.f;
    float k0 = wc[ky * 3], k1 = wc[ky * 3 + 1], k2 = wc[ky * 3 + 2];
#pragma unroll
    for (int j = 0; j < 8; ++j)
      o[j] = fmaf(k0, vv[j], fmaf(k1, vv[j + 1], fmaf(k2, vv[j + 2], o[j])));
  }
  {
    uint4 u = *(const uint4*)(img + hp * 32 + g8 * 8);
    float cv[8] = {bflo(u.x), bfhi(u.x), bflo(u.y), bfhi(u.y),
                   bflo(u.z), bfhi(u.z), bflo(u.w), bfhi(u.w)};
#pragma unroll
    for (int j = 0; j < 8; ++j) {
      o[j] += cv[j];
      tile[rw][cl][g8 * 8 + j] = gelu_exact(o[j]);
    }
  }
  __syncthreads();
  int wl = t >> 3, cg = t & 7;
#pragma unroll
  for (int rr = 0; rr < 2; ++rr) {
    unsigned p0 = pack2(tile[rr][cg * 4 + 0][wl], tile[rr][cg * 4 + 1][wl]);
    unsigned p1 = pack2(tile[rr][cg * 4 + 2][wl], tile[rr][cg * 4 + 3][wl]);
    unsigned* dst = (unsigned*)(ht + ((size_t)b * HW_ + (hp0 + rr) * 32 + wl) * D2_ + c0 + cg * 4);
    dst[0] = p0;
    dst[1] = p1;
  }
}

// ---- fused K+V projection, 64-tile, reg-prefetch pipeline.
__global__ __launch_bounds__(256) void gemm_kv(
    const ushort_t* __restrict__ Wk, const ushort_t* __restrict__ Wv,
    const ushort_t* __restrict__ Xt, const float* __restrict__ bk,
    const float* __restrict__ bv, ushort_t* __restrict__ ktb,
    ushort_t* __restrict__ vbn) {
  constexpr int K = C_, N = NS_, O = C_;
  struct __align__(16) SMem {
    union {
      struct { char a[8192]; char b[8192]; } st;
      float shuf[64 * 68];
    };
  };
  __shared__ SMem sm;
  int t = threadIdx.x;
  int lane = t & 63, wave = t >> 6;
  int wm = (wave >> 1) * 32, wn = (wave & 1) * 32;
  int bz = blockIdx.z;
  bool isK = blockIdx.y < 6;
  int o0 = (isK ? blockIdx.y : blockIdx.y - 6) * 64;
  int n0 = blockIdx.x * 64;
  const ushort_t* Wb = isK ? Wk : Wv;
  const float* bias = isK ? bk : bv;
  const ushort_t* Ag = Wb + (size_t)o0 * K;
  const ushort_t* Bg = Xt + ((size_t)bz * N + n0) * K;
  int sr = t >> 3, sc = t & 7;
  int swz = ((sc ^ (sr & 7)) << 4);
  f32x4 acc[2][2];
#pragma unroll
  for (int fi = 0; fi < 2; ++fi)
#pragma unroll
    for (int fj = 0; fj < 2; ++fj) acc[fi][fj] = f32x4{0.f, 0.f, 0.f, 0.f};
  int lrow = lane & 15, lk = lane >> 4;
  short8 a0 = *(const short8*)(Ag + (size_t)sr * K + sc * 8);
  short8 a1 = *(const short8*)(Ag + (size_t)(sr + 32) * K + sc * 8);
  short8 b0 = *(const short8*)(Bg + (size_t)sr * K + sc * 8);
  short8 b1 = *(const short8*)(Bg + (size_t)(sr + 32) * K + sc * 8);
  constexpr int NSTEP = K / 64;
#pragma unroll
  for (int s = 0; s < NSTEP; ++s) {
    if (s) __syncthreads();
    *(short8*)(sm.st.a + sr * 128 + swz) = a0;
    *(short8*)(sm.st.a + (sr + 32) * 128 + swz) = a1;
    *(short8*)(sm.st.b + sr * 128 + swz) = b0;
    *(short8*)(sm.st.b + (sr + 32) * 128 + swz) = b1;
    __syncthreads();
    if (s + 1 < NSTEP) {
      int k0 = (s + 1) * 64;
      a0 = *(const short8*)(Ag + (size_t)sr * K + k0 + sc * 8);
      a1 = *(const short8*)(Ag + (size_t)(sr + 32) * K + k0 + sc * 8);
      b0 = *(const short8*)(Bg + (size_t)sr * K + k0 + sc * 8);
      b1 = *(const short8*)(Bg + (size_t)(sr + 32) * K + k0 + sc * 8);
    }
#pragma unroll
    for (int kk = 0; kk < 2; ++kk) {
      short8 af[2], bfr[2];
#pragma unroll
      for (int fi = 0; fi < 2; ++fi) {
        int row = wm + fi * 16 + lrow;
        af[fi] = *(const short8*)(sm.st.a + row * 128 + (((kk * 4 + lk) ^ (row & 7)) << 4));
      }
#pragma unroll
      for (int fj = 0; fj < 2; ++fj) {
        int row = wn + fj * 16 + lrow;
        bfr[fj] = *(const short8*)(sm.st.b + row * 128 + (((kk * 4 + lk) ^ (row & 7)) << 4));
      }
#pragma unroll
      for (int fi = 0; fi < 2; ++fi)
#pragma unroll
        for (int fj = 0; fj < 2; ++fj)
          acc[fi][fj] = __builtin_amdgcn_mfma_f32_16x16x32_bf16(af[fi], bfr[fj], acc[fi][fj], 0, 0, 0);
    }
  }
  __syncthreads();
#pragma unroll
  for (int fi = 0; fi < 2; ++fi) {
#pragma unroll
    for (int r = 0; r < 4; ++r) {
      int ol = wm + fi * 16 + lk * 4 + r;
      float bi = bias[o0 + ol];
#pragma unroll
      for (int fj = 0; fj < 2; ++fj) {
        int nl = wn + fj * 16 + lrow;
        sm.shuf[ol * 68 + nl] = acc[fi][fj][r] + bi;
      }
    }
  }
  __syncthreads();
  if (isK) {
    int nl = t >> 2, og = (t & 3) * 16;
    unsigned pk[8];
#pragma unroll
    for (int i = 0; i < 8; ++i)
      pk[i] = pack2(sm.shuf[(og + 2 * i) * 68 + nl], sm.shuf[(og + 2 * i + 1) * 68 + nl]);
    unsigned* dst = (unsigned*)(ktb + ((size_t)bz * N + (n0 + nl)) * O + o0 + og);
    *(uint4*)(dst) = make_uint4(pk[0], pk[1], pk[2], pk[3]);
    *(uint4*)(dst + 4) = make_uint4(pk[4], pk[5], pk[6], pk[7]);
  } else {
    int ol = t >> 2, ng = (t & 3) * 16;
    unsigned pk[8];
#pragma unroll
    for (int i = 0; i < 8; ++i)
      pk[i] = pack2(sm.shuf[ol * 68 + ng + 2 * i], sm.shuf[ol * 68 + ng + 2 * i + 1]);
    unsigned* dst = (unsigned*)(vbn + ((size_t)bz * O + (o0 + ol)) * N + n0 + ng);
    *(uint4*)(dst) = make_uint4(pk[0], pk[1], pk[2], pk[3]);
    *(uint4*)(dst + 4) = make_uint4(pk[4], pk[5], pk[6], pk[7]);
  }
}

// ---- 128xBN x64 bf16 GEMM, double-buffered global_load_lds + XOR swizzle.
// Outputs: F32 -> Y fp32 [b][O][N]; B16N -> Yn bf16 [b][O][N]; B16T -> Yb bf16
// [b][N][O].  RES: += bf16 resid [b][O][N].
template <int BN, bool F32, bool B16N, bool B16T, bool RES>
__global__ __launch_bounds__(256) void gemm128(
    const ushort_t* __restrict__ Wb, const ushort_t* __restrict__ Xt,
    const float* __restrict__ bias, const ushort_t* __restrict__ residb,
    float* __restrict__ Y, ushort_t* __restrict__ Yn, ushort_t* __restrict__ Yb,
    int O, int K, int N) {
  constexpr int MFW = (BN == 128) ? 4 : 2;
  __shared__ __align__(16) ushort_t sA[2][128 * 64];
  __shared__ __align__(16) ushort_t sB[2][BN * 64];
  int t = threadIdx.x;
  int l = t & 63, w = t >> 6;
  int o0 = blockIdx.y * 128, n0 = blockIdx.x * BN, bz = blockIdx.z;
  const ushort_t* Ag = Wb + (size_t)o0 * K;
  const ushort_t* Bg = Xt + ((size_t)bz * N + n0) * K;
  int lr8 = l >> 3;
  int scol = (((l & 7) ^ (lr8 & 7)) * 8);  // pre-swizzled global k-chunk
  int lrow = l & 15, lg = l >> 4;
  int wm = (BN == 128) ? (w >> 1) * 64 : w * 32;
  int wn = (BN == 128) ? (w & 1) * 64 : 0;
  f32x4 acc[MFW][4];
#pragma unroll
  for (int fi = 0; fi < MFW; ++fi)
#pragma unroll
    for (int fj = 0; fj < 4; ++fj) acc[fi][fj] = f32x4{0.f, 0.f, 0.f, 0.f};
  auto stage = [&](int buf, int k0) {
#pragma unroll
    for (int i = 0; i < 4; ++i)
      gload16(Ag + (size_t)(w * 32 + i * 8 + lr8) * K + k0 + scol,
              sA[buf] + (w * 32 + i * 8) * 64);
    if constexpr (BN == 128) {
#pragma unroll
      for (int i = 0; i < 4; ++i)
        gload16(Bg + (size_t)(w * 32 + i * 8 + lr8) * K + k0 + scol,
                sB[buf] + (w * 32 + i * 8) * 64);
    } else {
#pragma unroll
      for (int i = 0; i < 2; ++i)
        gload16(Bg + (size_t)(w * 16 + i * 8 + lr8) * K + k0 + scol,
                sB[buf] + (w * 16 + i * 8) * 64);
    }
  };
  stage(0, 0);
  __syncthreads();
  int nstep = K >> 6;
  for (int s = 0; s < nstep; ++s) {
    int cur = s & 1;
    if (s + 1 < nstep) stage(cur ^ 1, (s + 1) * 64);
#pragma unroll
    for (int kk = 0; kk < 2; ++kk) {
      short8 af[MFW], bfr[4];
#pragma unroll
      for (int fi = 0; fi < MFW; ++fi) {
        int row = wm + fi * 16 + lrow;
        af[fi] = *(const short8*)(sA[cur] + row * 64 + (((kk * 4 + lg) ^ (row & 7)) << 3));
      }
#pragma unroll
      for (int fj = 0; fj < 4; ++fj) {
        int row = wn + fj * 16 + lrow;
        bfr[fj] = *(const short8*)(sB[cur] + row * 64 + (((kk * 4 + lg) ^ (row & 7)) << 3));
      }
#pragma unroll
      for (int fi = 0; fi < MFW; ++fi)
#pragma unroll
        for (int fj = 0; fj < 4; ++fj)
          acc[fi][fj] = __builtin_amdgcn_mfma_f32_16x16x32_bf16(af[fi], bfr[fj], acc[fi][fj], 0, 0, 0);
    }
    __syncthreads();
  }
#pragma unroll
  for (int fi = 0; fi < MFW; ++fi) {
    int ob = wm + fi * 16 + lg * 4;
    float bi[4];
#pragma unroll
    for (int r = 0; r < 4; ++r) bi[r] = bias[o0 + ob + r];
#pragma unroll
    for (int fj = 0; fj < 4; ++fj) {
      int n = n0 + wn + fj * 16 + lrow;
      float v[4];
#pragma unroll
      for (int r = 0; r < 4; ++r) {
        v[r] = acc[fi][fj][r] + bi[r];
        if (RES) v[r] += bf2f(residb[((size_t)bz * O + ob + r + o0) * N + n]);
        if (F32) Y[((size_t)bz * O + ob + r + o0) * N + n] = v[r];
        if (B16N) Yn[((size_t)bz * O + ob + r + o0) * N + n] = f2bf(v[r]);
      }
      if (B16T) {
        uint2 u;
        u.x = pack2(v[0], v[1]);
        u.y = pack2(v[2], v[3]);
        *(uint2*)&Yb[((size_t)bz * N + n) * O + o0 + ob] = u;
      }
    }
  }
}

// ---- offset branch: 4 threads per position (16 ch each), quad shfl-reduce LN.
__global__ __launch_bounds__(256) void offset_kernel(
    const ushort_t* __restrict__ qt, const float* __restrict__ odw,
    const float* __restrict__ odb, const float* __restrict__ olw,
    const float* __restrict__ olb, const float* __restrict__ opw,
    float* __restrict__ pos) {
  int blk = blockIdx.x;
  int bg = blk >> 2, pb = blk & 3;
  int b = bg / G_, g = bg % G_;
  int t = threadIdx.x;
  int p = pb * 64 + (t >> 2);
  int q = t & 3;
  int c0 = q * 16;
  int hk = p >> 4, wk = p & 15;
  const ushort_t* qb = qt + (size_t)b * HW_ * C_ + g * CG_ + c0;
  float sv[16];
#pragma unroll
  for (int j = 0; j < 16; ++j) sv[j] = odb[c0 + j];
#pragma unroll
  for (int ky = 0; ky < 3; ++ky) {
    int ih = 2 * hk + ky - 1;
    if ((unsigned)ih >= 32u) continue;
#pragma unroll
    for (int kx = 0; kx < 3; ++kx) {
      int iw = 2 * wk + kx - 1;
      if ((unsigned)iw >= 32u) continue;
      const ushort_t* qp = qb + (size_t)(ih * 32 + iw) * C_;
      uint4 u0 = *(const uint4*)qp;
      uint4 u1 = *(const uint4*)(qp + 8);
      float vv[16] = {bflo(u0.x), bfhi(u0.x), bflo(u0.y), bfhi(u0.y),
                      bflo(u0.z), bfhi(u0.z), bflo(u0.w), bfhi(u0.w),
                      bflo(u1.x), bfhi(u1.x), bflo(u1.y), bfhi(u1.y),
                      bflo(u1.z), bfhi(u1.z), bflo(u1.w), bfhi(u1.w)};
      int tap = ky * 3 + kx;
#pragma unroll
      for (int j = 0; j < 16; ++j)
        sv[j] = fmaf(odw[(c0 + j) * 9 + tap], vv[j], sv[j]);
    }
  }
  float s1 = 0.f;
#pragma unroll
  for (int j = 0; j < 16; ++j) s1 += sv[j];
  s1 += __shfl_xor(s1, 1);
  s1 += __shfl_xor(s1, 2);
  float mu = s1 * (1.f / CG_);
  float vs = 0.f;
#pragma unroll
  for (int j = 0; j < 16; ++j) {
    float d = sv[j] - mu;
    vs = fmaf(d, d, vs);
  }
  vs += __shfl_xor(vs, 1);
  vs += __shfl_xor(vs, 2);
  float rs = rsqrtf(vs * (1.f / CG_) + 1e-5f);
  float dy = 0.f, dx = 0.f;
#pragma unroll
  for (int j = 0; j < 16; ++j) {
    int c = c0 + j;
    float tv = (sv[j] - mu) * rs * olw[c] + olb[c];
    float ge = gelu_exact(tv);
    dy = fmaf(opw[c], ge, dy);
    dx = fmaf(opw[CG_ + c], ge, dx);
  }
  dy += __shfl_xor(dy, 1);
  dy += __shfl_xor(dy, 2);
  dx += __shfl_xor(dx, 1);
  dx += __shfl_xor(dx, 2);
  if (q == 0) {
    float ry = (hk + 0.5f) * (2.f / 15.f) - 1.f;
    float rx = (wk + 0.5f) * (2.f / 15.f) - 1.f;
    pos[(size_t)bg * 512 + p * 2 + 0] = fminf(fmaxf(dy + ry, -1.f), 1.f);
    pos[(size_t)bg * 512 + p * 2 + 1] = fminf(fmaxf(dx + rx, -1.f), 1.f);
  }
}

// ---- fused deformable sampling + transpose: y1b bf16 [b][c][hw] -> xst bf16 [b][n][C]
__global__ __launch_bounds__(256) void sample_xst(
    const ushort_t* __restrict__ y1b, const float* __restrict__ pos,
    ushort_t* __restrict__ xst) {
  int bg = blockIdx.y;
  int b = bg / G_, g = bg % G_;
  int t = threadIdx.x;
  int cg = t & 63, nl = t >> 6;
  int n = blockIdx.x * 4 + nl;
  float py = pos[(size_t)bg * 512 + 2 * n];
  float px = pos[(size_t)bg * 512 + 2 * n + 1];
  float gx = (px + 1.f) * 15.5f, gy = (py + 1.f) * 15.5f;
  float fx = floorf(gx), fy = floorf(gy);
  float wx = gx - fx, wy = gy - fy;
  int x0 = min(max((int)fx, 0), 31), y0 = min(max((int)fy, 0), 31);
  int x1 = min(x0 + 1, 31), y1i = min(y0 + 1, 31);
  const ushort_t* img = y1b + ((size_t)b * C_ + g * CG_ + cg) * HW_;
  float v00 = bf2f(img[y0 * 32 + x0]), v01 = bf2f(img[y0 * 32 + x1]);
  float v10 = bf2f(img[y1i * 32 + x0]), v11 = bf2f(img[y1i * 32 + x1]);
  float v = v00 * (1.f - wx) * (1.f - wy) + v01 * wx * (1.f - wy) +
            v10 * (1.f - wx) * wy + v11 * wx * wy;
  xst[((size_t)b * NS_ + n) * C_ + g * CG_ + cg] = f2bf(v);
}

// ---- MFMA flash attention; row-pair rpe table (16 KB); defer-max (THR=8).
__global__ __launch_bounds__(256) void attn_kernel(
    const ushort_t* __restrict__ qt, const ushort_t* __restrict__ kt,
    const ushort_t* __restrict__ vbn, const float* __restrict__ pos,
    const unsigned* __restrict__ rp2, ushort_t* __restrict__ aot) {
  __shared__ __align__(16) unsigned sRP2[4096];      // 16 KB row-pair table
  __shared__ __align__(16) ushort_t sP[4][32 * 40];  // 10 KB P bounce
  __shared__ unsigned sIB[256];
  __shared__ float sW2[512];
  int bid = blockIdx.x;
  int swzb = (bid & 7) * 96 + (bid >> 3);
  int qb = swzb & 7;
  int grp = swzb >> 3;
  int h = grp % HEADS_;
  int b = grp / HEADS_;
  int t = threadIdx.x;
  int l = t & 63, wv = t >> 6;
  int lrow = l & 15, lg = l >> 4;
  int bg = b * G_ + (h >> 1);
  {
    const ushort_t* src = (const ushort_t*)(rp2 + (size_t)h * 4096);
    ushort_t* dstb = (ushort_t*)sRP2;
#pragma unroll
    for (int i = 0; i < 4; ++i)
      gload16(src + i * 2048 + t * 8, dstb + i * 2048 + wv * 512);
  }
  {
    float py = pos[(size_t)bg * 512 + 2 * t];
    float px = pos[(size_t)bg * 512 + 2 * t + 1];
    float cy = 15.5f - 15.5f * py;
    float cx = 15.5f - 15.5f * px;
    float fy = floorf(cy), fx = floorf(cx);
    sIB[t] = (unsigned)((int)fy * 64 + (int)fx);
    sW2[2 * t] = cy - fy;
    sW2[2 * t + 1] = cx - fx;
  }
  __syncthreads();

  int m0 = qb * 128 + wv * 32;
  short8 qf[2];
  int aq[2];
#pragma unroll
  for (int f = 0; f < 2; ++f) {
    int m = m0 + f * 16 + lrow;
    qf[f] = *(const short8*)(qt + ((size_t)b * HW_ + m) * C_ + h * HC_ + lg * 8);
    aq[f] = (m >> 5) * 64 + (m & 31);
  }
  const ushort_t* kbase = kt + (size_t)b * NS_ * C_ + h * HC_;
  const ushort_t* vbase = vbn + ((size_t)b * C_ + h * HC_) * NS_;
  f32x4 oc[2][2];
#pragma unroll
  for (int f = 0; f < 2; ++f)
#pragma unroll
    for (int ct = 0; ct < 2; ++ct) oc[f][ct] = f32x4{0.f, 0.f, 0.f, 0.f};
  float mrun[2] = {-1e30f, -1e30f}, lrun[2] = {0.f, 0.f};
  ushort_t* sPw = sP[wv];

  for (int c = 0; c < 8; ++c) {
    f32x4 s[2][2];
    __builtin_amdgcn_s_setprio(1);
#pragma unroll
    for (int T = 0; T < 2; ++T) {
      short8 kf = *(const short8*)(kbase + (size_t)((c * 2 + T) * 16 + lrow) * C_ + lg * 8);
#pragma unroll
      for (int f = 0; f < 2; ++f)
        s[f][T] = __builtin_amdgcn_mfma_f32_16x16x32_bf16(kf, qf[f], f32x4{0.f, 0.f, 0.f, 0.f}, 0, 0, 0);
    }
    __builtin_amdgcn_s_setprio(0);
    u32x4 ibT[2];
    f32x4 wA[2], wB[2];
#pragma unroll
    for (int T = 0; T < 2; ++T) {
      int kbase2 = c * 32 + T * 16 + lg * 4;
      ibT[T] = *(const u32x4*)&sIB[kbase2];
      wA[T] = *(const f32x4*)&sW2[2 * kbase2];
      wB[T] = *(const f32x4*)&sW2[2 * kbase2 + 4];
    }
#pragma unroll
    for (int f = 0; f < 2; ++f)
#pragma unroll
      for (int T = 0; T < 2; ++T)
#pragma unroll
        for (int r = 0; r < 4; ++r) {
          int a = aq[f] + (int)ibT[T][r];
          float wy = (r < 2) ? wA[T][(r & 1) * 2] : wB[T][(r & 1) * 2];
          float wx = (r < 2) ? wA[T][(r & 1) * 2 + 1] : wB[T][(r & 1) * 2 + 1];
          unsigned top = sRP2[a];
          unsigned bot = sRP2[a + 64];
          float b00 = bflo(top), b01 = bfhi(top);
          float b10 = bflo(bot), b11 = bfhi(bot);
          float r0 = b00 + wx * (b01 - b00);
          float r1 = b10 + wx * (b11 - b10);
          s[f][T][r] = s[f][T][r] * SCALE_ + r0 + wy * (r1 - r0);
        }
#pragma unroll
    for (int f = 0; f < 2; ++f) {
      float mx = s[f][0][0];
#pragma unroll
      for (int T = 0; T < 2; ++T)
#pragma unroll
        for (int r = 0; r < 4; ++r) mx = fmaxf(mx, s[f][T][r]);
      mx = fmaxf(mx, __shfl_xor(mx, 16));
      mx = fmaxf(mx, __shfl_xor(mx, 32));
      if (!__all(mx <= mrun[f] + 8.f)) {  // defer-max: rescale only on growth
        float newm = fmaxf(mrun[f], mx);
        float fac = __expf(mrun[f] - newm);
        mrun[f] = newm;
        lrun[f] *= fac;
#pragma unroll
        for (int ct = 0; ct < 2; ++ct)
#pragma unroll
          for (int r = 0; r < 4; ++r) oc[f][ct][r] *= fac;
      }
      float ps = 0.f;
#pragma unroll
      for (int T = 0; T < 2; ++T)
#pragma unroll
        for (int r = 0; r < 4; ++r) {
          float p = __expf(s[f][T][r] - mrun[f]);
          s[f][T][r] = p;
          ps += p;
        }
      ps += __shfl_xor(ps, 16);
      ps += __shfl_xor(ps, 32);
      lrun[f] += ps;
#pragma unroll
      for (int T = 0; T < 2; ++T) {
        uint2 u;
        u.x = pack2(s[f][T][0], s[f][T][1]);
        u.y = pack2(s[f][T][2], s[f][T][3]);
        *(uint2*)&sPw[(f * 16 + lrow) * 40 + T * 16 + lg * 4] = u;
      }
    }
    short8 pa[2];
#pragma unroll
    for (int f = 0; f < 2; ++f)
      pa[f] = *(const short8*)&sPw[(f * 16 + lrow) * 40 + lg * 8];
    __builtin_amdgcn_s_setprio(1);
#pragma unroll
    for (int ct = 0; ct < 2; ++ct) {
      short8 vf = *(const short8*)(vbase + (size_t)(ct * 16 + lrow) * NS_ + c * 32 + lg * 8);
#pragma unroll
      for (int f = 0; f < 2; ++f)
        oc[f][ct] = __builtin_amdgcn_mfma_f32_16x16x32_bf16(pa[f], vf, oc[f][ct], 0, 0, 0);
    }
    __builtin_amdgcn_s_setprio(0);
  }
#pragma unroll
  for (int f = 0; f < 2; ++f) {
    float inv = 1.f / lrun[f];
    float invq[4];
#pragma unroll
    for (int r = 0; r < 4; ++r) invq[r] = __shfl(inv, lg * 4 + r);
#pragma unroll
    for (int ct = 0; ct < 2; ++ct)
#pragma unroll
      for (int r = 0; r < 4; ++r) {
        int m = m0 + f * 16 + lg * 4 + r;
        aot[((size_t)b * HW_ + m) * C_ + h * HC_ + ct * 16 + lrow] =
            f2bf(oc[f][ct][r] * invq[r]);
      }
  }
}

}  // namespace

extern "C" void kernel_launch(void* const* d_in, const int* in_sizes, int n_in,
                              void* d_out, int out_size, void* d_ws,
                              size_t ws_size, hipStream_t stream) {
  const float* x_in = (const float*)d_in[0];
  const float* lpu_w = (const float*)d_in[1];
  const float* lpu_b = (const float*)d_in[2];
  const float* wq = (const float*)d_in[3];
  const float* bq = (const float*)d_in[4];
  const float* wk = (const float*)d_in[5];
  const float* bk = (const float*)d_in[6];
  const float* wv = (const float*)d_in[7];
  const float* bv = (const float*)d_in[8];
  const float* wo = (const float*)d_in[9];
  const float* bo = (const float*)d_in[10];
  const float* odw = (const float*)d_in[11];
  const float* odb = (const float*)d_in[12];
  const float* olw = (const float*)d_in[13];
  const float* olb = (const float*)d_in[14];
  const float* opw = (const float*)d_in[15];
  const float* rpe = (const float*)d_in[16];
  const float* w1 = (const float*)d_in[17];
  const float* b1 = (const float*)d_in[18];
  const float* mdw = (const float*)d_in[19];
  const float* mdb = (const float*)d_in[20];
  const float* w2 = (const float*)d_in[21];
  const float* b2 = (const float*)d_in[22];
  float* out = (float*)d_out;

  constexpr size_t XSZ = (size_t)B_ * C_ * HW_;
  constexpr size_t SSZ = (size_t)B_ * C_ * NS_;
  constexpr size_t HSZ = (size_t)B_ * D2_ * HW_;

  char* base = (char*)d_ws;
  auto alloc = [&](size_t bytes) {
    char* p = base;
    base += (bytes + 255) & ~(size_t)255;
    return p;
  };
  ushort_t* bufXb = (ushort_t*)alloc(XSZ * 2);  // bf16 residual stream x
  ushort_t* y1b = (ushort_t*)alloc(XSZ * 2);    // bf16 y1 [b][c][hw]
  ushort_t* x2b = (ushort_t*)alloc(XSZ * 2);    // bf16 x2 [b][c][hw]
  float* pos = (float*)alloc(48 * 512 * 4);
  ushort_t* qt = (ushort_t*)alloc(XSZ * 2);
  ushort_t* tb1 = (ushort_t*)alloc(XSZ * 2);
  ushort_t* aot = (ushort_t*)alloc(XSZ * 2);
  ushort_t* xst = (ushort_t*)alloc(SSZ * 2);
  ushort_t* ktb = (ushort_t*)alloc(SSZ * 2);
  ushort_t* vbn = (ushort_t*)alloc(SSZ * 2);
  ushort_t* h1b = (ushort_t*)alloc(HSZ * 2);
  ushort_t* h3t = (ushort_t*)alloc(HSZ * 2);
  ushort_t* wb = (ushort_t*)alloc((size_t)3538944 * 2);
  unsigned* rp2 = (unsigned*)alloc((size_t)2 * HEADS_ * 4096 * 4);

  ushort_t* wqb = wb;
  ushort_t* wkb = wb + 294912;
  ushort_t* wvb = wb + 589824;
  ushort_t* wob = wb + 884736;
  ushort_t* w1b = wb + 1179648;
  ushort_t* w2b = wb + 2359296;

  wcvt_rpe<<<13824 + 24, 256, 0, stream>>>(wq, wk, wv, wo, w1, w2, wb, rpe, rp2);

  for (int d = 0; d < 2; ++d) {
    const ushort_t* wqd = wqb + (size_t)d * 147456;
    const ushort_t* wkd = wkb + (size_t)d * 147456;
    const ushort_t* wvd = wvb + (size_t)d * 147456;
    const ushort_t* wod = wob + (size_t)d * 147456;
    const ushort_t* w1d = w1b + (size_t)d * 589824;
    const ushort_t* w2d = w2b + (size_t)d * 589824;

    if (d == 0)
      dwconv_lpu<true><<<dim3(32, 12, 8), 256, 0, stream>>>(
          x_in, lpu_w + d * C_ * 9, lpu_b + d * C_, y1b, tb1);
    else
      dwconv_lpu<false><<<dim3(32, 12, 8), 256, 0, stream>>>(
          bufXb, lpu_w + d * C_ * 9, lpu_b + d * C_, y1b, tb1);
    // q = Wq @ y1 (bf16T)
    gemm128<64, false, false, true, false><<<dim3(16, 3, 8), 256, 0, stream>>>(
        wqd, tb1, bq + d * C_, nullptr, nullptr, nullptr, qt, C_, C_, HW_);
    offset_kernel<<<192, 256, 0, stream>>>(qt, odw + d * CG_ * 9, odb + d * CG_,
                                           olw + d * CG_, olb + d * CG_,
                                           opw + d * 2 * CG_, pos);
    sample_xst<<<dim3(64, 48), 256, 0, stream>>>(y1b, pos, xst);
    gemm_kv<<<dim3(4, 12, 8), 256, 0, stream>>>(wkd, wvd, xst, bk + d * C_,
                                                bv + d * C_, ktb, vbn);
    attn_kernel<<<768, 256, 0, stream>>>(qt, ktb, vbn, pos,
                                         rp2 + (size_t)d * HEADS_ * 4096, aot);
    // x2 = y1 + Wo @ ao : bf16 x2b + bf16T tb1
    gemm128<64, false, true, true, true><<<dim3(16, 3, 8), 256, 0, stream>>>(
        wod, aot, bo + d * C_, y1b, nullptr, x2b, tb1, C_, C_, HW_);
    // mlp1: h1b bf16N [b][D2][hw]
    gemm128<128, false, true, false, false><<<dim3(8, 12, 8), 256, 0, stream>>>(
        w1d, tb1, b1 + d * D2_, nullptr, nullptr, h1b, nullptr, D2_, C_, HW_);
    dwgelu_t<<<dim3(16, 48, 8), 256, 0, stream>>>(h1b, mdw + d * D2_ * 9,
                                                  mdb + d * D2_, h3t);
    // mlp2: xnext = x2 + W2 @ h3  (d=0 -> bf16 bufXb; d=1 -> fp32 out)
    if (d == 0)
      gemm128<64, false, true, false, true><<<dim3(16, 3, 8), 256, 0, stream>>>(
          w2d, h3t, b2 + d * C_, x2b, nullptr, bufXb, nullptr, C_, D2_, HW_);
    else
      gemm128<64, true, false, false, true><<<dim3(16, 3, 8), 256, 0, stream>>>(
          w2d, h3t, b2 + d * C_, x2b, out, nullptr, nullptr, C_, D2_, HW_);
  }
}